// Round 1
// baseline (7342.341 us; speedup 1.0000x reference)
//
#include <hip/hip_runtime.h>
#include <cfloat>
#include <cstdint>

// Problem constants
#define BB      16      // batch
#define TT      512     // seq
#define DD      512     // d_model
#define HH      8       // heads
#define DHH     64      // head dim
#define FFD     2048    // ff dim
#define BHH     128     // BB*HH
#define NHASH   4
#define NCHUNK  8       // NHASH * N_BUCKETS
#define CHUNKSZ 256
#define NLAYER  4

// ---------------------------------------------------------------------------
// Embedding: h = x @ emb_w + emb_b + pos ; write to both x1 and x2
// grid = B*T blocks, 256 threads
__global__ __launch_bounds__(256)
void embed_kernel(const float* __restrict__ x, const float* __restrict__ ew,
                  const float* __restrict__ eb, const float* __restrict__ pos,
                  float* __restrict__ x1, float* __restrict__ x2)
{
    const int row = blockIdx.x;          // b*T + t
    const int t = row & (TT - 1);
    __shared__ float xr[32];
    if (threadIdx.x < 32) xr[threadIdx.x] = x[row * 32 + threadIdx.x];
    __syncthreads();
    for (int d = threadIdx.x; d < DD; d += 256) {
        float s = eb[d] + pos[t * DD + d];
        #pragma unroll
        for (int k = 0; k < 32; ++k) s = fmaf(xr[k], ew[k * DD + d], s);
        x1[(size_t)row * DD + d] = s;
        x2[(size_t)row * DD + d] = s;
    }
}

// ---------------------------------------------------------------------------
// LayerNorm over last dim (512). 4 rows per 256-thread block (wave per row).
__global__ __launch_bounds__(256)
void ln_kernel(const float* __restrict__ in, const float* __restrict__ g,
               const float* __restrict__ bta, float* __restrict__ out)
{
    const int row = blockIdx.x * 4 + (threadIdx.x >> 6);
    const int lane = threadIdx.x & 63;
    const float* r = in + (size_t)row * DD;
    float vals[8];
    float s = 0.0f;
    #pragma unroll
    for (int i = 0; i < 8; ++i) { vals[i] = r[i * 64 + lane]; s += vals[i]; }
    #pragma unroll
    for (int o = 1; o < 64; o <<= 1) s += __shfl_xor(s, o);
    const float mean = s * (1.0f / 512.0f);
    float vs = 0.0f;
    #pragma unroll
    for (int i = 0; i < 8; ++i) { float d = vals[i] - mean; vs += d * d; }
    #pragma unroll
    for (int o = 1; o < 64; o <<= 1) vs += __shfl_xor(vs, o);
    const float rstd = rsqrtf(vs * (1.0f / 512.0f) + 1e-5f);
    float* orow = out + (size_t)row * DD;
    #pragma unroll
    for (int i = 0; i < 8; ++i) {
        const int d = i * 64 + lane;
        orow[d] = (vals[i] - mean) * rstd * g[d] + bta[d];
    }
}

// ---------------------------------------------------------------------------
// f32 GEMM: C = A(MxK) @ W(KxN) [+bias] [gelu] [+addsrc], tiles 64x64x16,
// 256 threads, 4x4 per thread.
__device__ __forceinline__ float gelu1(float v) {
    return 0.5f * v * (1.0f + erff(v * 0.70710678118654752440f));
}

template<bool GELU, bool ADD, bool BIAS>
__global__ __launch_bounds__(256)
void gemm_f32(const float* __restrict__ A, const float* __restrict__ W,
              const float* __restrict__ bias, const float* __restrict__ addsrc,
              float* __restrict__ C, int M, int N, int K)
{
    __shared__ float As[16][68];
    __shared__ float Ws[16][68];
    const int tid = threadIdx.x;
    const int m0 = blockIdx.x * 64;
    const int n0 = blockIdx.y * 64;
    const int tm = tid >> 4;        // 0..15
    const int tn = tid & 15;        // 0..15
    const int lam = tid >> 2;       // 0..63 (A row)
    const int lak = (tid & 3) * 4;  // A k start
    const int lwk = tid >> 4;       // 0..15 (W k row)
    const int lwn = (tid & 15) * 4; // W n start
    const float* Ap = A + (size_t)(m0 + lam) * K + lak;
    const float* Wp = W + (size_t)lwk * N + n0 + lwn;
    float c[4][4] = {};
    for (int k0 = 0; k0 < K; k0 += 16) {
        const float4 av = *reinterpret_cast<const float4*>(Ap);
        const float4 wv = *reinterpret_cast<const float4*>(Wp);
        __syncthreads();
        As[lak + 0][lam] = av.x;
        As[lak + 1][lam] = av.y;
        As[lak + 2][lam] = av.z;
        As[lak + 3][lam] = av.w;
        *reinterpret_cast<float4*>(&Ws[lwk][lwn]) = wv;
        __syncthreads();
        #pragma unroll
        for (int kk = 0; kk < 16; ++kk) {
            const float4 a = *reinterpret_cast<const float4*>(&As[kk][tm * 4]);
            const float4 w = *reinterpret_cast<const float4*>(&Ws[kk][tn * 4]);
            const float avr[4] = {a.x, a.y, a.z, a.w};
            const float wvr[4] = {w.x, w.y, w.z, w.w};
            #pragma unroll
            for (int i = 0; i < 4; ++i)
                #pragma unroll
                for (int j = 0; j < 4; ++j)
                    c[i][j] = fmaf(avr[i], wvr[j], c[i][j]);
        }
        Ap += 16;
        Wp += (size_t)16 * N;
    }
    #pragma unroll
    for (int i = 0; i < 4; ++i) {
        const int row = m0 + tm * 4 + i;
        const int col = n0 + tn * 4;
        float4 r = make_float4(c[i][0], c[i][1], c[i][2], c[i][3]);
        if constexpr (BIAS) {
            r.x += bias[col]; r.y += bias[col + 1];
            r.z += bias[col + 2]; r.w += bias[col + 3];
        }
        if constexpr (GELU) {
            r.x = gelu1(r.x); r.y = gelu1(r.y); r.z = gelu1(r.z); r.w = gelu1(r.w);
        }
        if constexpr (ADD) {
            const float4 a4 = *reinterpret_cast<const float4*>(&addsrc[(size_t)row * N + col]);
            r.x += a4.x; r.y += a4.y; r.z += a4.z; r.w += a4.w;
        }
        *reinterpret_cast<float4*>(&C[(size_t)row * N + col]) = r;
    }
}

// ---------------------------------------------------------------------------
// Per (bh,t) key-row inverse norms: rinv = 1/max(||qk_row||, 1e-12)
// 16 lanes per row, 16 rows per 256-thread block.
__global__ __launch_bounds__(256)
void rownorm_kernel(const float* __restrict__ qk, float* __restrict__ rinv)
{
    const int g = blockIdx.x * 16 + (threadIdx.x >> 4);  // bh*T + t
    const int li = threadIdx.x & 15;
    const int bh = g >> 9, t = g & 511;
    const int b = bh >> 3, head = bh & 7;
    const float4* row = reinterpret_cast<const float4*>(
        qk + ((size_t)(b * TT + t)) * DD + head * DHH);
    const float4 xv = row[li];
    float ss = xv.x * xv.x + xv.y * xv.y + xv.z * xv.z + xv.w * xv.w;
    ss += __shfl_xor(ss, 1); ss += __shfl_xor(ss, 2);
    ss += __shfl_xor(ss, 4); ss += __shfl_xor(ss, 8);
    if (li == 0) rinv[g] = 1.0f / fmaxf(sqrtf(ss), 1e-12f);
}

// ---------------------------------------------------------------------------
// Bucket assignment + stable partition (the whole "LSH sort" for N_BUCKETS=2).
// grid (NHASH, BHH), 512 threads (one per token).
__global__ __launch_bounds__(512)
void bucket_sort_kernel(const float* __restrict__ qk, const float* __restrict__ rot,
                        int* __restrict__ st)
{
    const int h = blockIdx.x, bh = blockIdx.y;
    const int b = bh >> 3, head = bh & 7;
    const int t = threadIdx.x;
    __shared__ float rc[64];
    __shared__ int zcnt[8];
    if (t < 64) rc[t] = rot[t * NHASH + h];   // rot[f][h][0]
    __syncthreads();
    const float4* row = reinterpret_cast<const float4*>(
        qk + ((size_t)(b * TT + t)) * DD + head * DHH);
    float r = 0.0f;
    #pragma unroll
    for (int u = 0; u < 16; ++u) {
        const float4 q4 = row[u];
        r += q4.x * rc[u * 4] + q4.y * rc[u * 4 + 1]
           + q4.z * rc[u * 4 + 2] + q4.w * rc[u * 4 + 3];
    }
    // argmax([r,-r]) : tie (r==0) -> 0
    const int bit = (r < 0.0f) ? 1 : 0;
    const int wid = t >> 6, lane = t & 63;
    const unsigned long long zm = __ballot(bit == 0);
    if (lane == 0) zcnt[wid] = __popcll(zm);
    __syncthreads();
    int zoff = 0, Z = 0;
    #pragma unroll
    for (int w = 0; w < 8; ++w) { const int cn = zcnt[w]; if (w < wid) zoff += cn; Z += cn; }
    const int zpre = __popcll(zm & ((1ull << lane) - 1ull));
    const int dst = (bit == 0) ? (zoff + zpre)
                               : (Z + (wid * 64 - zoff) + (lane - zpre));
    st[((size_t)bh * NHASH + h) * TT + dst] = t;
}

// ---------------------------------------------------------------------------
// LSH chunked attention. grid (NCHUNK, BHH), 256 threads; thread = one query.
// Keys = own chunk (256) + previous chunk circular over global chunk idx (256).
__global__ __launch_bounds__(256)
void lsh_attn_kernel(const float* __restrict__ qk, const float* __restrict__ v,
                     const float* __restrict__ rinv, const int* __restrict__ st,
                     float* __restrict__ o_hash, float* __restrict__ lse_hash)
{
    const int cc = blockIdx.x;       // global chunk 0..7
    const int bh = blockIdx.y;
    const int b = bh >> 3, head = bh & 7;
    const int h = cc >> 1, c = cc & 1;
    const int pcc = (cc + 7) & 7;
    const int hp = pcc >> 1, cp = pcc & 1;
    const int tid = threadIdx.x;
    const int* stb = st + (size_t)bh * (NHASH * TT);

    __shared__ float4 ks[64][16];
    __shared__ float4 vs[64][16];
    __shared__ int    kts[64];

    const int q_t = stb[h * TT + c * CHUNKSZ + tid];
    const float4* qrow = reinterpret_cast<const float4*>(
        qk + ((size_t)(b * TT + q_t)) * DD + head * DHH);
    float4 q4[16];
    #pragma unroll
    for (int u = 0; u < 16; ++u) q4[u] = qrow[u];
    float4 acc[16];
    #pragma unroll
    for (int u = 0; u < 16; ++u) acc[u] = make_float4(0.f, 0.f, 0.f, 0.f);
    float m = -FLT_MAX, l = 0.0f;

    const int jr = tid >> 2;   // key row this thread loads
    const int jc = tid & 3;    // quarter of the row

    for (int kt = 0; kt < 8; ++kt) {
        const int kj = kt * 64 + jr;
        const int k_t = (kj < CHUNKSZ) ? stb[h * TT + c * CHUNKSZ + kj]
                                       : stb[hp * TT + cp * CHUNKSZ + (kj - CHUNKSZ)];
        const float rv = rinv[bh * TT + k_t];
        const float4* krow = reinterpret_cast<const float4*>(
            qk + ((size_t)(b * TT + k_t)) * DD + head * DHH);
        const float4* vrow = reinterpret_cast<const float4*>(
            v + ((size_t)(b * TT + k_t)) * DD + head * DHH);
        __syncthreads();     // previous tile fully consumed
        #pragma unroll
        for (int u = 0; u < 4; ++u) {
            float4 kv = krow[jc * 4 + u];
            kv.x *= rv; kv.y *= rv; kv.z *= rv; kv.w *= rv;
            ks[jr][jc * 4 + u] = kv;
            vs[jr][jc * 4 + u] = vrow[jc * 4 + u];
        }
        if (jc == 0) kts[jr] = k_t;
        __syncthreads();

        for (int j = 0; j < 64; ++j) {
            float s = 0.0f;
            #pragma unroll
            for (int u = 0; u < 16; ++u) {
                const float4 kv = ks[j][u];
                s += q4[u].x * kv.x + q4[u].y * kv.y + q4[u].z * kv.z + q4[u].w * kv.w;
            }
            s *= 0.125f;   // d^-0.5, d=64
            const int ktj = kts[j];
            s = (q_t < ktj) ? -FLT_MAX : ((q_t == ktj) ? -5.0e4f : s);
            const float nm = fmaxf(m, s);
            const float corr = __expf(m - nm);
            const float p = __expf(s - nm);
            l = l * corr + p;
            #pragma unroll
            for (int u = 0; u < 16; ++u) {
                const float4 vv = vs[j][u];
                acc[u].x = acc[u].x * corr + p * vv.x;
                acc[u].y = acc[u].y * corr + p * vv.y;
                acc[u].z = acc[u].z * corr + p * vv.z;
                acc[u].w = acc[u].w * corr + p * vv.w;
            }
            m = nm;
        }
    }
    const float invl = 1.0f / l;
    const float lse = m + __logf(l);
    float* orow = o_hash + ((size_t)((bh * NHASH + h) * TT + q_t)) * DHH;
    #pragma unroll
    for (int u = 0; u < 16; ++u) {
        float4 o = acc[u];
        o.x *= invl; o.y *= invl; o.z *= invl; o.w *= invl;
        reinterpret_cast<float4*>(orow)[u] = o;
    }
    lse_hash[(size_t)(bh * NHASH + h) * TT + q_t] = lse;
}

// ---------------------------------------------------------------------------
// Combine hash rounds: out = sum_h o_h * softmax_h(lse_h); write merged (B,T,D)
__global__ __launch_bounds__(256)
void combine_kernel(const float* __restrict__ o_hash, const float* __restrict__ lse_hash,
                    float* __restrict__ am)
{
    const int idx = blockIdx.x * 4 + (threadIdx.x >> 6);   // bh*T + t
    const int lane = threadIdx.x & 63;
    const int bh = idx >> 9, t = idx & 511;
    const int b = bh >> 3, head = bh & 7;
    const float ls0 = lse_hash[(size_t)(bh * NHASH + 0) * TT + t];
    const float ls1 = lse_hash[(size_t)(bh * NHASH + 1) * TT + t];
    const float ls2 = lse_hash[(size_t)(bh * NHASH + 2) * TT + t];
    const float ls3 = lse_hash[(size_t)(bh * NHASH + 3) * TT + t];
    const float M = fmaxf(fmaxf(ls0, ls1), fmaxf(ls2, ls3));
    const float e0 = __expf(ls0 - M), e1 = __expf(ls1 - M);
    const float e2 = __expf(ls2 - M), e3 = __expf(ls3 - M);
    const float inv = 1.0f / (e0 + e1 + e2 + e3);
    const float o =
        (e0 * o_hash[((size_t)((bh * NHASH + 0) * TT + t)) * DHH + lane] +
         e1 * o_hash[((size_t)((bh * NHASH + 1) * TT + t)) * DHH + lane] +
         e2 * o_hash[((size_t)((bh * NHASH + 2) * TT + t)) * DHH + lane] +
         e3 * o_hash[((size_t)((bh * NHASH + 3) * TT + t)) * DHH + lane]) * inv;
    am[((size_t)(b * TT + t)) * DD + head * DHH + lane] = o;
}

// ---------------------------------------------------------------------------
// Final head: only last token per batch. 16 blocks x 256 threads.
__device__ __forceinline__ float block_sum256(float v, volatile float* red)
{
    const int lane = threadIdx.x & 63, wid = threadIdx.x >> 6;
    #pragma unroll
    for (int o = 1; o < 64; o <<= 1) v += __shfl_xor(v, o);
    __syncthreads();
    if (lane == 0) red[wid] = v;
    __syncthreads();
    return red[0] + red[1] + red[2] + red[3];
}

__global__ __launch_bounds__(256)
void head_kernel(const float* __restrict__ x1, const float* __restrict__ x2,
                 const float* __restrict__ lnfg, const float* __restrict__ lnfb,
                 const float* __restrict__ hw1, const float* __restrict__ hb1,
                 const float* __restrict__ hlng, const float* __restrict__ hlnb,
                 const float* __restrict__ hw2, const float* __restrict__ hb2,
                 float* __restrict__ out)
{
    __shared__ float nrow[512];
    __shared__ float red[4];
    const int b = blockIdx.x, tid = threadIdx.x;
    const size_t roff = ((size_t)b * TT + (TT - 1)) * DD;
    const float v0 = 0.5f * (x1[roff + tid] + x2[roff + tid]);
    const float v1 = 0.5f * (x1[roff + 256 + tid] + x2[roff + 256 + tid]);
    const float mean = block_sum256(v0 + v1, red) * (1.0f / 512.0f);
    const float d0 = v0 - mean, d1 = v1 - mean;
    const float var = block_sum256(d0 * d0 + d1 * d1, red) * (1.0f / 512.0f);
    const float rstd = rsqrtf(var + 1e-5f);
    nrow[tid]       = d0 * rstd * lnfg[tid] + lnfb[tid];
    nrow[tid + 256] = d1 * rstd * lnfg[tid + 256] + lnfb[tid + 256];
    __syncthreads();
    float a = hb1[tid];
    for (int k = 0; k < 512; ++k) a = fmaf(nrow[k], hw1[(size_t)k * 256 + tid], a);
    const float m2 = block_sum256(a, red) * (1.0f / 256.0f);
    const float dd = a - m2;
    const float var2 = block_sum256(dd * dd, red) * (1.0f / 256.0f);
    float y = dd * rsqrtf(var2 + 1e-5f) * hlng[tid] + hlnb[tid];
    y = fmaxf(y, 0.0f);
    const float osum = block_sum256(y * hw2[tid], red);
    if (tid == 0) out[b] = osum + hb2[0];
}

// ---------------------------------------------------------------------------
extern "C" void kernel_launch(void* const* d_in, const int* in_sizes, int n_in,
                              void* d_out, int out_size, void* d_ws, size_t ws_size,
                              hipStream_t stream)
{
    (void)in_sizes; (void)n_in; (void)out_size; (void)ws_size;
    const float* x    = (const float*)d_in[0];
    const float* embw = (const float*)d_in[1];
    const float* embb = (const float*)d_in[2];
    const float* pos  = (const float*)d_in[3];
    const float* ln1g = (const float*)d_in[4];
    const float* ln1b = (const float*)d_in[5];
    const float* wqk  = (const float*)d_in[6];
    const float* wv   = (const float*)d_in[7];
    const float* wo   = (const float*)d_in[8];
    const float* wob  = (const float*)d_in[9];
    const float* ln2g = (const float*)d_in[10];
    const float* ln2b = (const float*)d_in[11];
    const float* ffw1 = (const float*)d_in[12];
    const float* ffb1 = (const float*)d_in[13];
    const float* ffw2 = (const float*)d_in[14];
    const float* ffb2 = (const float*)d_in[15];
    const float* rot  = (const float*)d_in[16];
    const float* lnfg = (const float*)d_in[17];
    const float* lnfb = (const float*)d_in[18];
    const float* hw1  = (const float*)d_in[19];
    const float* hb1  = (const float*)d_in[20];
    const float* hlng = (const float*)d_in[21];
    const float* hlnb = (const float*)d_in[22];
    const float* hw2  = (const float*)d_in[23];
    const float* hb2  = (const float*)d_in[24];
    float* out = (float*)d_out;

    // workspace layout (floats)
    const size_t SZ_BTD = (size_t)BB * TT * DD;        // 4,194,304
    float* x1b   = (float*)d_ws;
    float* x2b   = x1b + SZ_BTD;
    float* xnb   = x2b + SZ_BTD;
    float* qkb   = xnb + SZ_BTD;
    float* vb    = qkb + SZ_BTD;                       // also attn-merged
    float* ohash = vb + SZ_BTD;                        // 16,777,216 ; also ff_mid
    float* lseb  = ohash + (size_t)BHH * NHASH * TT * DHH;
    float* rinvb = lseb + (size_t)BHH * NHASH * TT;
    int*   stb   = (int*)(rinvb + (size_t)BHH * TT);

    embed_kernel<<<BB * TT, 256, 0, stream>>>(x, embw, embb, pos, x1b, x2b);

    for (int L = 0; L < NLAYER; ++L) {
        const size_t wOff  = (size_t)L * DD * DD;
        const size_t f1Off = (size_t)L * DD * FFD;
        const size_t f2Off = (size_t)L * FFD * DD;

        // x1 += attn(ln(x2))
        ln_kernel<<<2048, 256, 0, stream>>>(x2b, ln1g + L * DD, ln1b + L * DD, xnb);
        gemm_f32<false, false, false><<<dim3(128, 8), 256, 0, stream>>>(
            xnb, wqk + wOff, nullptr, nullptr, qkb, BB * TT, DD, DD);
        gemm_f32<false, false, false><<<dim3(128, 8), 256, 0, stream>>>(
            xnb, wv + wOff, nullptr, nullptr, vb, BB * TT, DD, DD);
        rownorm_kernel<<<4096, 256, 0, stream>>>(qkb, rinvb);
        bucket_sort_kernel<<<dim3(NHASH, BHH), 512, 0, stream>>>(
            qkb, rot + (size_t)L * DHH * NHASH, stb);
        lsh_attn_kernel<<<dim3(NCHUNK, BHH), 256, 0, stream>>>(
            qkb, vb, rinvb, stb, ohash, lseb);
        combine_kernel<<<16384, 256, 0, stream>>>(ohash, lseb, vb); // vb = merged attn
        gemm_f32<false, true, true><<<dim3(128, 8), 256, 0, stream>>>(
            vb, wo + wOff, wob + L * DD, x1b, x1b, BB * TT, DD, DD);

        // x2 += ff(ln(x1))
        ln_kernel<<<2048, 256, 0, stream>>>(x1b, ln2g + L * DD, ln2b + L * DD, xnb);
        gemm_f32<true, false, true><<<dim3(128, 32), 256, 0, stream>>>(
            xnb, ffw1 + f1Off, ffb1 + L * FFD, nullptr, ohash, BB * TT, FFD, DD);
        gemm_f32<false, true, true><<<dim3(128, 8), 256, 0, stream>>>(
            ohash, ffw2 + f2Off, ffb2 + L * DD, x2b, x2b, BB * TT, DD, FFD);
    }

    head_kernel<<<16, 256, 0, stream>>>(x1b, x2b, lnfg, lnfb, hw1, hb1,
                                        hlng, hlnb, hw2, hb2, out);
}

// Round 2
// 3470.081 us; speedup vs baseline: 2.1159x; 2.1159x over previous
//
#include <hip/hip_runtime.h>
#include <cfloat>
#include <cstdint>

// Problem constants
#define BB      16      // batch
#define TT      512     // seq
#define DD      512     // d_model
#define HH      8       // heads
#define DHH     64      // head dim
#define FFD     2048    // ff dim
#define BHH     128     // BB*HH
#define NHASH   4
#define NCHUNK  8       // NHASH * N_BUCKETS
#define CHUNKSZ 256
#define NLAYER  4

typedef __attribute__((ext_vector_type(8))) short bfrag;    // 8 bf16 (4 VGPR)
typedef __attribute__((ext_vector_type(16))) float f16x;    // 16 f32 acc

union FragU { unsigned u[4]; uint4 v4; bfrag f; };

__device__ __forceinline__ unsigned pk_bf16(float a, float b) {
    union { float f; unsigned u; } x, y;
    x.f = a; y.f = b;
    unsigned lo = ((x.u + 0x7FFFu + ((x.u >> 16) & 1u)) >> 16) & 0xFFFFu;
    unsigned hi = (y.u + 0x7FFFu + ((y.u >> 16) & 1u)) & 0xFFFF0000u;
    return lo | hi;
}
__device__ __forceinline__ unsigned short bf16_1(float a) {
    union { float f; unsigned u; } x; x.f = a;
    return (unsigned short)((x.u + 0x7FFFu + ((x.u >> 16) & 1u)) >> 16);
}

// ---------------------------------------------------------------------------
// Embedding: h = x @ emb_w + emb_b + pos ; write to both x1 and x2
__global__ __launch_bounds__(256)
void embed_kernel(const float* __restrict__ x, const float* __restrict__ ew,
                  const float* __restrict__ eb, const float* __restrict__ pos,
                  float* __restrict__ x1, float* __restrict__ x2)
{
    const int row = blockIdx.x;          // b*T + t
    const int t = row & (TT - 1);
    __shared__ float xr[32];
    if (threadIdx.x < 32) xr[threadIdx.x] = x[row * 32 + threadIdx.x];
    __syncthreads();
    for (int d = threadIdx.x; d < DD; d += 256) {
        float s = eb[d] + pos[t * DD + d];
        #pragma unroll
        for (int k = 0; k < 32; ++k) s = fmaf(xr[k], ew[k * DD + d], s);
        x1[(size_t)row * DD + d] = s;
        x2[(size_t)row * DD + d] = s;
    }
}

// ---------------------------------------------------------------------------
// LayerNorm over last dim (512). 4 rows per 256-thread block (wave per row).
__global__ __launch_bounds__(256)
void ln_kernel(const float* __restrict__ in, const float* __restrict__ g,
               const float* __restrict__ bta, float* __restrict__ out)
{
    const int row = blockIdx.x * 4 + (threadIdx.x >> 6);
    const int lane = threadIdx.x & 63;
    const float* r = in + (size_t)row * DD;
    float vals[8];
    float s = 0.0f;
    #pragma unroll
    for (int i = 0; i < 8; ++i) { vals[i] = r[i * 64 + lane]; s += vals[i]; }
    #pragma unroll
    for (int o = 1; o < 64; o <<= 1) s += __shfl_xor(s, o);
    const float mean = s * (1.0f / 512.0f);
    float vs = 0.0f;
    #pragma unroll
    for (int i = 0; i < 8; ++i) { float d = vals[i] - mean; vs += d * d; }
    #pragma unroll
    for (int o = 1; o < 64; o <<= 1) vs += __shfl_xor(vs, o);
    const float rstd = rsqrtf(vs * (1.0f / 512.0f) + 1e-5f);
    float* orow = out + (size_t)row * DD;
    #pragma unroll
    for (int i = 0; i < 8; ++i) {
        const int d = i * 64 + lane;
        orow[d] = (vals[i] - mean) * rstd * g[d] + bta[d];
    }
}

// ---------------------------------------------------------------------------
// f32 GEMM: C = A(MxK) @ W(KxN) [+bias] [gelu] [+addsrc], tiles 64x64x16
__device__ __forceinline__ float gelu1(float v) {
    return 0.5f * v * (1.0f + erff(v * 0.70710678118654752440f));
}

template<bool GELU, bool ADD, bool BIAS>
__global__ __launch_bounds__(256)
void gemm_f32(const float* __restrict__ A, const float* __restrict__ W,
              const float* __restrict__ bias, const float* __restrict__ addsrc,
              float* __restrict__ C, int M, int N, int K)
{
    __shared__ float As[16][68];
    __shared__ float Ws[16][68];
    const int tid = threadIdx.x;
    const int m0 = blockIdx.x * 64;
    const int n0 = blockIdx.y * 64;
    const int tm = tid >> 4;
    const int tn = tid & 15;
    const int lam = tid >> 2;
    const int lak = (tid & 3) * 4;
    const int lwk = tid >> 4;
    const int lwn = (tid & 15) * 4;
    const float* Ap = A + (size_t)(m0 + lam) * K + lak;
    const float* Wp = W + (size_t)lwk * N + n0 + lwn;
    float c[4][4] = {};
    for (int k0 = 0; k0 < K; k0 += 16) {
        const float4 av = *reinterpret_cast<const float4*>(Ap);
        const float4 wv = *reinterpret_cast<const float4*>(Wp);
        __syncthreads();
        As[lak + 0][lam] = av.x;
        As[lak + 1][lam] = av.y;
        As[lak + 2][lam] = av.z;
        As[lak + 3][lam] = av.w;
        *reinterpret_cast<float4*>(&Ws[lwk][lwn]) = wv;
        __syncthreads();
        #pragma unroll
        for (int kk = 0; kk < 16; ++kk) {
            const float4 a = *reinterpret_cast<const float4*>(&As[kk][tm * 4]);
            const float4 w = *reinterpret_cast<const float4*>(&Ws[kk][tn * 4]);
            const float avr[4] = {a.x, a.y, a.z, a.w};
            const float wvr[4] = {w.x, w.y, w.z, w.w};
            #pragma unroll
            for (int i = 0; i < 4; ++i)
                #pragma unroll
                for (int j = 0; j < 4; ++j)
                    c[i][j] = fmaf(avr[i], wvr[j], c[i][j]);
        }
        Ap += 16;
        Wp += (size_t)16 * N;
    }
    #pragma unroll
    for (int i = 0; i < 4; ++i) {
        const int row = m0 + tm * 4 + i;
        const int col = n0 + tn * 4;
        float4 r = make_float4(c[i][0], c[i][1], c[i][2], c[i][3]);
        if constexpr (BIAS) {
            r.x += bias[col]; r.y += bias[col + 1];
            r.z += bias[col + 2]; r.w += bias[col + 3];
        }
        if constexpr (GELU) {
            r.x = gelu1(r.x); r.y = gelu1(r.y); r.z = gelu1(r.z); r.w = gelu1(r.w);
        }
        if constexpr (ADD) {
            const float4 a4 = *reinterpret_cast<const float4*>(&addsrc[(size_t)row * N + col]);
            r.x += a4.x; r.y += a4.y; r.z += a4.z; r.w += a4.w;
        }
        *reinterpret_cast<float4*>(&C[(size_t)row * N + col]) = r;
    }
}

// ---------------------------------------------------------------------------
// Per (bh,t) key-row inverse norms
__global__ __launch_bounds__(256)
void rownorm_kernel(const float* __restrict__ qk, float* __restrict__ rinv)
{
    const int g = blockIdx.x * 16 + (threadIdx.x >> 4);
    const int li = threadIdx.x & 15;
    const int bh = g >> 9, t = g & 511;
    const int b = bh >> 3, head = bh & 7;
    const float4* row = reinterpret_cast<const float4*>(
        qk + ((size_t)(b * TT + t)) * DD + head * DHH);
    const float4 xv = row[li];
    float ss = xv.x * xv.x + xv.y * xv.y + xv.z * xv.z + xv.w * xv.w;
    ss += __shfl_xor(ss, 1); ss += __shfl_xor(ss, 2);
    ss += __shfl_xor(ss, 4); ss += __shfl_xor(ss, 8);
    if (li == 0) rinv[g] = 1.0f / fmaxf(sqrtf(ss), 1e-12f);
}

// ---------------------------------------------------------------------------
// Bucket assignment + stable partition (f32 — must match numpy exactly)
__global__ __launch_bounds__(512)
void bucket_sort_kernel(const float* __restrict__ qk, const float* __restrict__ rot,
                        int* __restrict__ st)
{
    const int h = blockIdx.x, bh = blockIdx.y;
    const int b = bh >> 3, head = bh & 7;
    const int t = threadIdx.x;
    __shared__ float rc[64];
    __shared__ int zcnt[8];
    if (t < 64) rc[t] = rot[t * NHASH + h];
    __syncthreads();
    const float4* row = reinterpret_cast<const float4*>(
        qk + ((size_t)(b * TT + t)) * DD + head * DHH);
    float r = 0.0f;
    #pragma unroll
    for (int u = 0; u < 16; ++u) {
        const float4 q4 = row[u];
        r += q4.x * rc[u * 4] + q4.y * rc[u * 4 + 1]
           + q4.z * rc[u * 4 + 2] + q4.w * rc[u * 4 + 3];
    }
    const int bit = (r < 0.0f) ? 1 : 0;
    const int wid = t >> 6, lane = t & 63;
    const unsigned long long zm = __ballot(bit == 0);
    if (lane == 0) zcnt[wid] = __popcll(zm);
    __syncthreads();
    int zoff = 0, Z = 0;
    #pragma unroll
    for (int w = 0; w < 8; ++w) { const int cn = zcnt[w]; if (w < wid) zoff += cn; Z += cn; }
    const int zpre = __popcll(zm & ((1ull << lane) - 1ull));
    const int dst = (bit == 0) ? (zoff + zpre)
                               : (Z + (wid * 64 - zoff) + (lane - zpre));
    st[((size_t)bh * NHASH + h) * TT + dst] = t;
}

// ---------------------------------------------------------------------------
// MFMA LSH attention. grid (NCHUNK, BHH), 256 threads (4 waves).
// Wave w owns 64 queries of the 256-query chunk. S^T = K̂·Qᵀ, Oᵀ = V̂ᵀ·Pᵀ
// with 32x32x16 bf16 MFMA; per-query softmax is lane-local (query = C col).
// No online rescale: m = |q|/8 bound (keys unit-norm). Degenerate query
// (all keys masked) -> o = v_self, lse = -5e4 (matches f32 reference).
__global__ __launch_bounds__(256)
void lsh_attn_mfma(const float* __restrict__ qk, const float* __restrict__ v,
                   const float* __restrict__ rinv, const int* __restrict__ st,
                   float* __restrict__ o_hash, float* __restrict__ lse_hash)
{
    const int cc = blockIdx.x, bh = blockIdx.y;
    const int b = bh >> 3, head = bh & 7;
    const int h = cc >> 1, c = cc & 1;
    const int pcc = (cc + 7) & 7;
    const int hp = pcc >> 1, cp = pcc & 1;
    const int tid = threadIdx.x;
    const int w = tid >> 6;
    const int lane = tid & 63;
    const int l31 = lane & 31;
    const int hi = lane >> 5;
    const int* stb = st + (size_t)bh * (NHASH * TT);
    const size_t qkbase = ((size_t)b * TT) * DD + head * DHH;

    __shared__ __align__(16) unsigned short Kbf[64 * 64];   // normalized K, bf16
    __shared__ __align__(16) unsigned short VTbf[64 * 64];  // V transposed [d][k]
    __shared__ int ktl[64];
    __shared__ float lW[4][64];
    __shared__ int qtW[4][64];
    __shared__ float Ost[4][32 * 33];

    // ---- Q fragments in registers (2 queries per lane: qt=0,1) ----
    int q_t[2]; float mq2[2], mnat[2];
    unsigned QF[2][4][4];   // [qt][dstep][reg] packed bf16 pairs
    #pragma unroll
    for (int qt = 0; qt < 2; ++qt) {
        const int qtk = stb[h * TT + c * CHUNKSZ + w * 64 + qt * 32 + l31];
        q_t[qt] = qtk;
        const float* qrow = qk + qkbase + (size_t)qtk * DD;
        float ss = 0.f;
        #pragma unroll
        for (int ds = 0; ds < 4; ++ds) {
            const int d0 = ds * 16 + hi * 8;
            const float4 f0 = *(const float4*)(qrow + d0);
            const float4 f1 = *(const float4*)(qrow + d0 + 4);
            ss += f0.x*f0.x + f0.y*f0.y + f0.z*f0.z + f0.w*f0.w
                + f1.x*f1.x + f1.y*f1.y + f1.z*f1.z + f1.w*f1.w;
            QF[qt][ds][0] = pk_bf16(f0.x, f0.y);
            QF[qt][ds][1] = pk_bf16(f0.z, f0.w);
            QF[qt][ds][2] = pk_bf16(f1.x, f1.y);
            QF[qt][ds][3] = pk_bf16(f1.z, f1.w);
        }
        ss += __shfl_xor(ss, 32);
        const float qn = sqrtf(ss);
        mnat[qt] = qn * 0.125f;
        mq2[qt]  = qn * 0.1803368801111137f;   // |q| * 0.125 * log2(e)
    }

    f16x acc[2][2] = {};      // [dt][qt] : O^T tiles (32d x 32q)
    float lacc[2] = {0.f, 0.f};
    const int kk = tid & 63, seg = tid >> 6;
    const float C1 = 0.1803368801111137f;     // 0.125 * log2(e)

    for (int kt8 = 0; kt8 < 8; ++kt8) {
        // ---- stage K-tile (normalized bf16, swizzled) + V^T tile ----
        const int kj = kt8 * 64 + kk;
        const int k_t = (kj < CHUNKSZ) ? stb[h * TT + c * CHUNKSZ + kj]
                                       : stb[hp * TT + cp * CHUNKSZ + (kj - CHUNKSZ)];
        const float rv = rinv[bh * TT + k_t];
        const float* krow = qk + qkbase + (size_t)k_t * DD + seg * 16;
        const float* vrow = v  + qkbase + (size_t)k_t * DD + seg * 16;
        const float4 ka = ((const float4*)krow)[0], kb2 = ((const float4*)krow)[1],
                     kc = ((const float4*)krow)[2], kd = ((const float4*)krow)[3];
        const float4 va = ((const float4*)vrow)[0], vb2 = ((const float4*)vrow)[1],
                     vc = ((const float4*)vrow)[2], vd = ((const float4*)vrow)[3];
        __syncthreads();   // previous tile fully consumed
        {
            const int rbase = kk * 128 + seg * 32;
            const int swz = (kk & 7) << 4;
            *(uint4*)((char*)Kbf + ((rbase)      ^ swz)) =
                make_uint4(pk_bf16(ka.x*rv, ka.y*rv), pk_bf16(ka.z*rv, ka.w*rv),
                           pk_bf16(kb2.x*rv, kb2.y*rv), pk_bf16(kb2.z*rv, kb2.w*rv));
            *(uint4*)((char*)Kbf + ((rbase + 16) ^ swz)) =
                make_uint4(pk_bf16(kc.x*rv, kc.y*rv), pk_bf16(kc.z*rv, kc.w*rv),
                           pk_bf16(kd.x*rv, kd.y*rv), pk_bf16(kd.z*rv, kd.w*rv));
        }
        {
            const float vv[16] = {va.x,va.y,va.z,va.w, vb2.x,vb2.y,vb2.z,vb2.w,
                                  vc.x,vc.y,vc.z,vc.w, vd.x,vd.y,vd.z,vd.w};
            #pragma unroll
            for (int i = 0; i < 16; ++i) {
                const int d = seg * 16 + i;
                *(unsigned short*)((char*)VTbf + ((d * 128 + kk * 2) ^ ((d & 7) << 4))) = bf16_1(vv[i]);
            }
        }
        if (tid < 64) ktl[tid] = k_t;
        __syncthreads();

        // ---- compute: 2 key-groups of 32 ----
        #pragma unroll
        for (int kt = 0; kt < 2; ++kt) {
            int ktv[16];
            #pragma unroll
            for (int i = 0; i < 16; ++i)
                ktv[i] = ktl[kt * 32 + (i & 3) + 8 * (i >> 2) + 4 * hi];
            FragU KA[4];
            #pragma unroll
            for (int ds = 0; ds < 4; ++ds) {
                const int row = kt * 32 + l31;
                KA[ds].v4 = *(const uint4*)((const char*)Kbf +
                    ((row * 128 + ds * 32 + hi * 16) ^ ((row & 7) << 4)));
            }
            FragU VA[2][2];
            #pragma unroll
            for (int dt = 0; dt < 2; ++dt)
                #pragma unroll
                for (int u = 0; u < 2; ++u) {
                    const int row = dt * 32 + l31;
                    const int ks = kt * 2 + u;
                    VA[dt][u].v4 = *(const uint4*)((const char*)VTbf +
                        ((row * 128 + ks * 32 + hi * 16) ^ ((row & 7) << 4)));
                }
            #pragma unroll
            for (int qt = 0; qt < 2; ++qt) {
                f16x s = {0.f,0.f,0.f,0.f,0.f,0.f,0.f,0.f,
                          0.f,0.f,0.f,0.f,0.f,0.f,0.f,0.f};
                #pragma unroll
                for (int ds = 0; ds < 4; ++ds) {
                    FragU qf;
                    qf.u[0] = QF[qt][ds][0]; qf.u[1] = QF[qt][ds][1];
                    qf.u[2] = QF[qt][ds][2]; qf.u[3] = QF[qt][ds][3];
                    s = __builtin_amdgcn_mfma_f32_32x32x16_bf16(KA[ds].f, qf.f, s, 0, 0, 0);
                }
                float pv[16];
                #pragma unroll
                for (int i = 0; i < 16; ++i) {
                    const float e = exp2f(fmaf(s[i], C1, -mq2[qt]));
                    const float p = (q_t[qt] > ktv[i]) ? e : 0.0f;
                    pv[i] = p;
                    lacc[qt] += p;
                }
                unsigned P2[8], S2[8];
                #pragma unroll
                for (int g = 0; g < 4; ++g) {
                    P2[2*g]   = pk_bf16(pv[4*g],   pv[4*g+1]);
                    P2[2*g+1] = pk_bf16(pv[4*g+2], pv[4*g+3]);
                }
                #pragma unroll
                for (int i = 0; i < 8; ++i)
                    S2[i] = (unsigned)__shfl_xor((int)P2[i], 32);
                #pragma unroll
                for (int u = 0; u < 2; ++u) {
                    FragU bfv;
                    bfv.u[0] = hi ? S2[2*(2*u+1)]     : P2[2*(2*u)];
                    bfv.u[1] = hi ? S2[2*(2*u+1) + 1] : P2[2*(2*u) + 1];
                    bfv.u[2] = hi ? P2[2*(2*u+1)]     : S2[2*(2*u)];
                    bfv.u[3] = hi ? P2[2*(2*u+1) + 1] : S2[2*(2*u) + 1];
                    #pragma unroll
                    for (int dt = 0; dt < 2; ++dt)
                        acc[dt][qt] = __builtin_amdgcn_mfma_f32_32x32x16_bf16(
                            VA[dt][u].f, bfv.f, acc[dt][qt], 0, 0, 0);
                }
            }
        }
    }

    // ---- finalize l, lse ----
    float invl[2];
    #pragma unroll
    for (int qt = 0; qt < 2; ++qt) {
        const float lt = lacc[qt] + __shfl_xor(lacc[qt], 32);
        invl[qt] = (lt > 0.f) ? 1.0f / lt : 0.0f;
        const float lse = (lt > 0.f) ? (mnat[qt] + logf(lt)) : -5.0e4f;
        if (hi == 0) {
            lW[w][qt * 32 + l31] = lt;
            qtW[w][qt * 32 + l31] = q_t[qt];
            lse_hash[(size_t)(bh * NHASH + h) * TT + q_t[qt]] = lse;
        }
    }
    __syncthreads();

    // ---- epilogue: per-wave LDS transpose of O^T tiles -> coalesced stores ----
    float* ost = Ost[w];
    #pragma unroll
    for (int qt = 0; qt < 2; ++qt)
        #pragma unroll
        for (int dt = 0; dt < 2; ++dt) {
            #pragma unroll
            for (int r = 0; r < 16; ++r) {
                const int row = (r & 3) + 8 * (r >> 2) + 4 * hi;
                ost[row * 33 + l31] = acc[dt][qt][r] * invl[qt];
            }
            const int qq = lane >> 1, h2 = lane & 1;
            const int qglob = qtW[w][qt * 32 + qq];
            const float lq = lW[w][qt * 32 + qq];
            float ov[16];
            #pragma unroll
            for (int i = 0; i < 16; ++i)
                ov[i] = ost[(h2 * 16 + i) * 33 + qq];
            float* orow = o_hash + ((size_t)(bh * NHASH + h) * TT + qglob) * DHH
                        + dt * 32 + h2 * 16;
            if (lq > 0.f) {
                ((float4*)orow)[0] = make_float4(ov[0],  ov[1],  ov[2],  ov[3]);
                ((float4*)orow)[1] = make_float4(ov[4],  ov[5],  ov[6],  ov[7]);
                ((float4*)orow)[2] = make_float4(ov[8],  ov[9],  ov[10], ov[11]);
                ((float4*)orow)[3] = make_float4(ov[12], ov[13], ov[14], ov[15]);
            } else {
                const float* vrow = v + qkbase + (size_t)qglob * DD + dt * 32 + h2 * 16;
                ((float4*)orow)[0] = ((const float4*)vrow)[0];
                ((float4*)orow)[1] = ((const float4*)vrow)[1];
                ((float4*)orow)[2] = ((const float4*)vrow)[2];
                ((float4*)orow)[3] = ((const float4*)vrow)[3];
            }
        }
}

// ---------------------------------------------------------------------------
// Combine hash rounds
__global__ __launch_bounds__(256)
void combine_kernel(const float* __restrict__ o_hash, const float* __restrict__ lse_hash,
                    float* __restrict__ am)
{
    const int idx = blockIdx.x * 4 + (threadIdx.x >> 6);
    const int lane = threadIdx.x & 63;
    const int bh = idx >> 9, t = idx & 511;
    const int b = bh >> 3, head = bh & 7;
    const float ls0 = lse_hash[(size_t)(bh * NHASH + 0) * TT + t];
    const float ls1 = lse_hash[(size_t)(bh * NHASH + 1) * TT + t];
    const float ls2 = lse_hash[(size_t)(bh * NHASH + 2) * TT + t];
    const float ls3 = lse_hash[(size_t)(bh * NHASH + 3) * TT + t];
    const float M = fmaxf(fmaxf(ls0, ls1), fmaxf(ls2, ls3));
    const float e0 = __expf(ls0 - M), e1 = __expf(ls1 - M);
    const float e2 = __expf(ls2 - M), e3 = __expf(ls3 - M);
    const float inv = 1.0f / (e0 + e1 + e2 + e3);
    const float o =
        (e0 * o_hash[((size_t)((bh * NHASH + 0) * TT + t)) * DHH + lane] +
         e1 * o_hash[((size_t)((bh * NHASH + 1) * TT + t)) * DHH + lane] +
         e2 * o_hash[((size_t)((bh * NHASH + 2) * TT + t)) * DHH + lane] +
         e3 * o_hash[((size_t)((bh * NHASH + 3) * TT + t)) * DHH + lane]) * inv;
    am[((size_t)(b * TT + t)) * DD + head * DHH + lane] = o;
}

// ---------------------------------------------------------------------------
// Final head
__device__ __forceinline__ float block_sum256(float v, volatile float* red)
{
    const int lane = threadIdx.x & 63, wid = threadIdx.x >> 6;
    #pragma unroll
    for (int o = 1; o < 64; o <<= 1) v += __shfl_xor(v, o);
    __syncthreads();
    if (lane == 0) red[wid] = v;
    __syncthreads();
    return red[0] + red[1] + red[2] + red[3];
}

__global__ __launch_bounds__(256)
void head_kernel(const float* __restrict__ x1, const float* __restrict__ x2,
                 const float* __restrict__ lnfg, const float* __restrict__ lnfb,
                 const float* __restrict__ hw1, const float* __restrict__ hb1,
                 const float* __restrict__ hlng, const float* __restrict__ hlnb,
                 const float* __restrict__ hw2, const float* __restrict__ hb2,
                 float* __restrict__ out)
{
    __shared__ float nrow[512];
    __shared__ float red[4];
    const int b = blockIdx.x, tid = threadIdx.x;
    const size_t roff = ((size_t)b * TT + (TT - 1)) * DD;
    const float v0 = 0.5f * (x1[roff + tid] + x2[roff + tid]);
    const float v1 = 0.5f * (x1[roff + 256 + tid] + x2[roff + 256 + tid]);
    const float mean = block_sum256(v0 + v1, red) * (1.0f / 512.0f);
    const float d0 = v0 - mean, d1 = v1 - mean;
    const float var = block_sum256(d0 * d0 + d1 * d1, red) * (1.0f / 512.0f);
    const float rstd = rsqrtf(var + 1e-5f);
    nrow[tid]       = d0 * rstd * lnfg[tid] + lnfb[tid];
    nrow[tid + 256] = d1 * rstd * lnfg[tid + 256] + lnfb[tid + 256];
    __syncthreads();
    float a = hb1[tid];
    for (int k = 0; k < 512; ++k) a = fmaf(nrow[k], hw1[(size_t)k * 256 + tid], a);
    const float m2 = block_sum256(a, red) * (1.0f / 256.0f);
    const float dd = a - m2;
    const float var2 = block_sum256(dd * dd, red) * (1.0f / 256.0f);
    float y = dd * rsqrtf(var2 + 1e-5f) * hlng[tid] + hlnb[tid];
    y = fmaxf(y, 0.0f);
    const float osum = block_sum256(y * hw2[tid], red);
    if (tid == 0) out[b] = osum + hb2[0];
}

// ---------------------------------------------------------------------------
extern "C" void kernel_launch(void* const* d_in, const int* in_sizes, int n_in,
                              void* d_out, int out_size, void* d_ws, size_t ws_size,
                              hipStream_t stream)
{
    (void)in_sizes; (void)n_in; (void)out_size; (void)ws_size;
    const float* x    = (const float*)d_in[0];
    const float* embw = (const float*)d_in[1];
    const float* embb = (const float*)d_in[2];
    const float* pos  = (const float*)d_in[3];
    const float* ln1g = (const float*)d_in[4];
    const float* ln1b = (const float*)d_in[5];
    const float* wqk  = (const float*)d_in[6];
    const float* wv   = (const float*)d_in[7];
    const float* wo   = (const float*)d_in[8];
    const float* wob  = (const float*)d_in[9];
    const float* ln2g = (const float*)d_in[10];
    const float* ln2b = (const float*)d_in[11];
    const float* ffw1 = (const float*)d_in[12];
    const float* ffb1 = (const float*)d_in[13];
    const float* ffw2 = (const float*)d_in[14];
    const float* ffb2 = (const float*)d_in[15];
    const float* rot  = (const float*)d_in[16];
    const float* lnfg = (const float*)d_in[17];
    const float* lnfb = (const float*)d_in[18];
    const float* hw1  = (const float*)d_in[19];
    const float* hb1  = (const float*)d_in[20];
    const float* hlng = (const float*)d_in[21];
    const float* hlnb = (const float*)d_in[22];
    const float* hw2  = (const float*)d_in[23];
    const float* hb2  = (const float*)d_in[24];
    float* out = (float*)d_out;

    const size_t SZ_BTD = (size_t)BB * TT * DD;
    float* x1b   = (float*)d_ws;
    float* x2b   = x1b + SZ_BTD;
    float* xnb   = x2b + SZ_BTD;
    float* qkb   = xnb + SZ_BTD;
    float* vb    = qkb + SZ_BTD;
    float* ohash = vb + SZ_BTD;
    float* lseb  = ohash + (size_t)BHH * NHASH * TT * DHH;
    float* rinvb = lseb + (size_t)BHH * NHASH * TT;
    int*   stb   = (int*)(rinvb + (size_t)BHH * TT);

    embed_kernel<<<BB * TT, 256, 0, stream>>>(x, embw, embb, pos, x1b, x2b);

    for (int L = 0; L < NLAYER; ++L) {
        const size_t wOff  = (size_t)L * DD * DD;
        const size_t f1Off = (size_t)L * DD * FFD;
        const size_t f2Off = (size_t)L * FFD * DD;

        // x1 += attn(ln(x2))
        ln_kernel<<<2048, 256, 0, stream>>>(x2b, ln1g + L * DD, ln1b + L * DD, xnb);
        gemm_f32<false, false, false><<<dim3(128, 8), 256, 0, stream>>>(
            xnb, wqk + wOff, nullptr, nullptr, qkb, BB * TT, DD, DD);
        gemm_f32<false, false, false><<<dim3(128, 8), 256, 0, stream>>>(
            xnb, wv + wOff, nullptr, nullptr, vb, BB * TT, DD, DD);
        rownorm_kernel<<<4096, 256, 0, stream>>>(qkb, rinvb);
        bucket_sort_kernel<<<dim3(NHASH, BHH), 512, 0, stream>>>(
            qkb, rot + (size_t)L * DHH * NHASH, stb);
        lsh_attn_mfma<<<dim3(NCHUNK, BHH), 256, 0, stream>>>(
            qkb, vb, rinvb, stb, ohash, lseb);
        combine_kernel<<<16384, 256, 0, stream>>>(ohash, lseb, vb);
        gemm_f32<false, true, true><<<dim3(128, 8), 256, 0, stream>>>(
            vb, wo + wOff, wob + L * DD, x1b, x1b, BB * TT, DD, DD);

        // x2 += ff(ln(x1))
        ln_kernel<<<2048, 256, 0, stream>>>(x1b, ln2g + L * DD, ln2b + L * DD, xnb);
        gemm_f32<true, false, true><<<dim3(128, 32), 256, 0, stream>>>(
            xnb, ffw1 + f1Off, ffb1 + L * FFD, nullptr, ohash, BB * TT, FFD, DD);
        gemm_f32<false, true, true><<<dim3(128, 8), 256, 0, stream>>>(
            ohash, ffw2 + f2Off, ffb2 + L * DD, x2b, x2b, BB * TT, DD, FFD);
    }

    head_kernel<<<16, 256, 0, stream>>>(x1b, x2b, lnfg, lnfb, hw1, hb1,
                                        hlng, hlnb, hw2, hb2, out);
}

// Round 3
// 1624.570 us; speedup vs baseline: 4.5196x; 2.1360x over previous
//
#include <hip/hip_runtime.h>
#include <cfloat>
#include <cstdint>

// Problem constants
#define BB      16      // batch
#define TT      512     // seq
#define DD      512     // d_model
#define HH      8       // heads
#define DHH     64      // head dim
#define FFD     2048    // ff dim
#define BHH     128     // BB*HH
#define NHASH   4
#define NCHUNK  8       // NHASH * N_BUCKETS
#define CHUNKSZ 256
#define NLAYER  4

typedef unsigned short u16;
typedef unsigned int   u32;
typedef __attribute__((ext_vector_type(8))) short bfrag;    // 8 bf16 (4 VGPR)
typedef __attribute__((ext_vector_type(4))) float f4x;      // 4 f32 acc
typedef __attribute__((ext_vector_type(16))) float f16x;    // 16 f32 acc

union FragU { u32 u[4]; uint4 v4; bfrag f; };

__device__ __forceinline__ unsigned pk_bf16(float a, float b) {
    union { float f; unsigned u; } x, y;
    x.f = a; y.f = b;
    unsigned lo = ((x.u + 0x7FFFu + ((x.u >> 16) & 1u)) >> 16) & 0xFFFFu;
    unsigned hi = (y.u + 0x7FFFu + ((y.u >> 16) & 1u)) & 0xFFFF0000u;
    return lo | hi;
}
__device__ __forceinline__ u16 bf16_1(float a) {
    union { float f; unsigned u; } x; x.f = a;
    return (u16)((x.u + 0x7FFFu + ((x.u >> 16) & 1u)) >> 16);
}
__device__ __forceinline__ float b2f(u16 h) {
    union { unsigned u; float f; } x; x.u = ((unsigned)h) << 16; return x.f;
}

// async global->LDS, 16B per lane (dest must be linear: base + lane*16)
__device__ __forceinline__ void gload16(const u16* g, u16* l) {
    __builtin_amdgcn_global_load_lds(
        (const __attribute__((address_space(1))) u32*)g,
        (__attribute__((address_space(3))) u32*)l, 16, 0, 0);
}

// ---------------------------------------------------------------------------
// Embedding: h = x @ emb_w + emb_b + pos ; write to both x1 and x2
__global__ __launch_bounds__(256)
void embed_kernel(const float* __restrict__ x, const float* __restrict__ ew,
                  const float* __restrict__ eb, const float* __restrict__ pos,
                  float* __restrict__ x1, float* __restrict__ x2)
{
    const int row = blockIdx.x;          // b*T + t
    const int t = row & (TT - 1);
    __shared__ float xr[32];
    if (threadIdx.x < 32) xr[threadIdx.x] = x[row * 32 + threadIdx.x];
    __syncthreads();
    for (int d = threadIdx.x; d < DD; d += 256) {
        float s = eb[d] + pos[t * DD + d];
        #pragma unroll
        for (int k = 0; k < 32; ++k) s = fmaf(xr[k], ew[k * DD + d], s);
        x1[(size_t)row * DD + d] = s;
        x2[(size_t)row * DD + d] = s;
    }
}

// ---------------------------------------------------------------------------
// LayerNorm over last dim (512); writes f32 AND bf16 outputs.
__global__ __launch_bounds__(256)
void ln_kernel(const float* __restrict__ in, const float* __restrict__ g,
               const float* __restrict__ bta, float* __restrict__ out,
               u16* __restrict__ outh)
{
    const int row = blockIdx.x * 4 + (threadIdx.x >> 6);
    const int lane = threadIdx.x & 63;
    const float* r = in + (size_t)row * DD;
    float vals[8];
    float s = 0.0f;
    #pragma unroll
    for (int i = 0; i < 8; ++i) { vals[i] = r[i * 64 + lane]; s += vals[i]; }
    #pragma unroll
    for (int o = 1; o < 64; o <<= 1) s += __shfl_xor(s, o);
    const float mean = s * (1.0f / 512.0f);
    float vs = 0.0f;
    #pragma unroll
    for (int i = 0; i < 8; ++i) { float d = vals[i] - mean; vs += d * d; }
    #pragma unroll
    for (int o = 1; o < 64; o <<= 1) vs += __shfl_xor(vs, o);
    const float rstd = rsqrtf(vs * (1.0f / 512.0f) + 1e-5f);
    float* orow = out + (size_t)row * DD;
    u16* hrow = outh + (size_t)row * DD;
    #pragma unroll
    for (int i = 0; i < 8; ++i) {
        const int d = i * 64 + lane;
        const float y = (vals[i] - mean) * rstd * g[d] + bta[d];
        orow[d] = y;
        hrow[d] = bf16_1(y);
    }
}

// ---------------------------------------------------------------------------
// Weight transpose+convert: in (K x N, f32) -> out (N x K, bf16)
__global__ __launch_bounds__(256)
void transpose_bf16(const float* __restrict__ in, u16* __restrict__ out,
                    int K, int N)
{
    __shared__ float tile[32][33];
    const int kt = blockIdx.x * 32, nt = blockIdx.y * 32;
    const int r = threadIdx.x >> 3, c4 = (threadIdx.x & 7) * 4;
    const float4 v4 = *(const float4*)(in + (size_t)(kt + r) * N + nt + c4);
    tile[r][c4 + 0] = v4.x; tile[r][c4 + 1] = v4.y;
    tile[r][c4 + 2] = v4.z; tile[r][c4 + 3] = v4.w;
    __syncthreads();
    uint2 p;
    p.x = pk_bf16(tile[c4 + 0][r], tile[c4 + 1][r]);
    p.y = pk_bf16(tile[c4 + 2][r], tile[c4 + 3][r]);
    *(uint2*)(out + (size_t)(nt + r) * K + kt + c4) = p;
}

// ---------------------------------------------------------------------------
// f32 GEMM (qk only — keeps LSH bucket decisions f32-exact).
__device__ __forceinline__ float gelu1(float v) {
    return 0.5f * v * (1.0f + erff(v * 0.70710678118654752440f));
}

template<bool GELU, bool ADD, bool BIAS>
__global__ __launch_bounds__(256)
void gemm_f32(const float* __restrict__ A, const float* __restrict__ W,
              const float* __restrict__ bias, const float* __restrict__ addsrc,
              float* __restrict__ C, int M, int N, int K)
{
    __shared__ float As[16][68];
    __shared__ float Ws[16][68];
    const int tid = threadIdx.x;
    const int m0 = blockIdx.x * 64;
    const int n0 = blockIdx.y * 64;
    const int tm = tid >> 4;
    const int tn = tid & 15;
    const int lam = tid >> 2;
    const int lak = (tid & 3) * 4;
    const int lwk = tid >> 4;
    const int lwn = (tid & 15) * 4;
    const float* Ap = A + (size_t)(m0 + lam) * K + lak;
    const float* Wp = W + (size_t)lwk * N + n0 + lwn;
    float c[4][4] = {};
    for (int k0 = 0; k0 < K; k0 += 16) {
        const float4 av = *reinterpret_cast<const float4*>(Ap);
        const float4 wv = *reinterpret_cast<const float4*>(Wp);
        __syncthreads();
        As[lak + 0][lam] = av.x;
        As[lak + 1][lam] = av.y;
        As[lak + 2][lam] = av.z;
        As[lak + 3][lam] = av.w;
        *reinterpret_cast<float4*>(&Ws[lwk][lwn]) = wv;
        __syncthreads();
        #pragma unroll
        for (int kk = 0; kk < 16; ++kk) {
            const float4 a = *reinterpret_cast<const float4*>(&As[kk][tm * 4]);
            const float4 w = *reinterpret_cast<const float4*>(&Ws[kk][tn * 4]);
            const float avr[4] = {a.x, a.y, a.z, a.w};
            const float wvr[4] = {w.x, w.y, w.z, w.w};
            #pragma unroll
            for (int i = 0; i < 4; ++i)
                #pragma unroll
                for (int j = 0; j < 4; ++j)
                    c[i][j] = fmaf(avr[i], wvr[j], c[i][j]);
        }
        Ap += 16;
        Wp += (size_t)16 * N;
    }
    #pragma unroll
    for (int i = 0; i < 4; ++i) {
        const int row = m0 + tm * 4 + i;
        const int col = n0 + tn * 4;
        float4 r = make_float4(c[i][0], c[i][1], c[i][2], c[i][3]);
        if constexpr (BIAS) {
            r.x += bias[col]; r.y += bias[col + 1];
            r.z += bias[col + 2]; r.w += bias[col + 3];
        }
        if constexpr (GELU) {
            r.x = gelu1(r.x); r.y = gelu1(r.y); r.z = gelu1(r.z); r.w = gelu1(r.w);
        }
        if constexpr (ADD) {
            const float4 a4 = *reinterpret_cast<const float4*>(&addsrc[(size_t)row * N + col]);
            r.x += a4.x; r.y += a4.y; r.z += a4.z; r.w += a4.w;
        }
        *reinterpret_cast<float4*>(&C[(size_t)row * N + col]) = r;
    }
}

// ---------------------------------------------------------------------------
// bf16 MFMA GEMM: C = A(MxK,bf16) @ WT(NxK,bf16)^T, 128x128x32 tiles, 4 waves.
// global_load_lds staging with pre-swizzled global source; swizzled
// ds_read_b128 fragment reads (conflict-free); 16 mfma_f32_16x16x32_bf16
// per wave per K-step (m97 structure).
template<bool GELU, bool ADD, bool BIAS, bool OUTBF>
__global__ __launch_bounds__(256)
void gemm_bf16(const u16* __restrict__ A, const u16* __restrict__ WT,
               const float* __restrict__ bias, const float* __restrict__ addsrc,
               float* __restrict__ Cf, u16* __restrict__ Cb,
               int M, int N, int K)
{
    __shared__ __align__(16) u16 Abuf[128 * 32];
    __shared__ __align__(16) u16 Bbuf[128 * 32];
    const int tid = threadIdx.x;
    const int m0 = blockIdx.x * 128;
    const int n0 = blockIdx.y * 128;

    // staging: LDS linear slot (row rS = tid>>2, chunk' = tid&3);
    // source chunk = chunk' ^ swz(row) so the READ-side XOR lands right.
    const int rS = tid >> 2;
    const int swzS = (rS & 3) ^ ((rS >> 2) & 3);
    const int cS = ((tid & 3) ^ swzS) * 8;
    const u16* aS0 = A  + (size_t)(m0 + rS) * K + cS;
    const u16* aS1 = aS0 + (size_t)64 * K;
    const u16* bS0 = WT + (size_t)(n0 + rS) * K + cS;
    const u16* bS1 = bS0 + (size_t)64 * K;
    u16* aD = Abuf + tid * 8;
    u16* bD = Bbuf + tid * 8;

    // fragment addressing
    const int l = tid & 63;
    const int wv_ = tid >> 6;
    const int wm = (wv_ >> 1) * 64;
    const int wn = (wv_ & 1) * 64;
    const int fr = l & 15;                 // row-in-16-tile (m or n)
    const int fc = l >> 4;                 // k-chunk 0..3
    const int swzL = (fr & 3) ^ ((fr >> 2) & 3);
    const int fco = (fc ^ swzL) << 4;      // swizzled chunk byte offset
    const char* aF = (const char*)Abuf + (size_t)fr * 64 + fco;
    const char* bF = (const char*)Bbuf + (size_t)fr * 64 + fco;

    f4x acc[4][4] = {};
    const int nK = K >> 5;
    for (int ks = 0; ks < nK; ++ks) {
        __syncthreads();                   // previous tile fully consumed
        gload16(aS0, aD);
        gload16(aS1, aD + 64 * 32);
        gload16(bS0, bD);
        gload16(bS1, bD + 64 * 32);
        aS0 += 32; aS1 += 32; bS0 += 32; bS1 += 32;
        __syncthreads();                   // vmcnt(0) drained by compiler
        FragU af[4], bf_[4];
        #pragma unroll
        for (int i = 0; i < 4; ++i) {
            af[i].v4  = *(const uint4*)(aF + (wm + i * 16) * 64);
            bf_[i].v4 = *(const uint4*)(bF + (wn + i * 16) * 64);
        }
        #pragma unroll
        for (int i = 0; i < 4; ++i)
            #pragma unroll
            for (int j = 0; j < 4; ++j)
                acc[i][j] = __builtin_amdgcn_mfma_f32_16x16x32_bf16(
                    af[i].f, bf_[j].f, acc[i][j], 0, 0, 0);
    }

    // epilogue: C row = fc*4 + q (A index), col = fr (B index)
    #pragma unroll
    for (int i = 0; i < 4; ++i) {
        #pragma unroll
        for (int q = 0; q < 4; ++q) {
            const int row = m0 + wm + i * 16 + fc * 4 + q;
            #pragma unroll
            for (int j = 0; j < 4; ++j) {
                const int col = n0 + wn + j * 16 + fr;
                float vx = acc[i][j][q];
                if constexpr (BIAS) vx += bias[col];
                if constexpr (GELU) vx = gelu1(vx);
                if constexpr (ADD) vx += addsrc[(size_t)row * N + col];
                if constexpr (OUTBF) Cb[(size_t)row * N + col] = bf16_1(vx);
                else Cf[(size_t)row * N + col] = vx;
            }
        }
    }
}

// ---------------------------------------------------------------------------
// Per (bh,t) key-row inverse norms (f32 qk)
__global__ __launch_bounds__(256)
void rownorm_kernel(const float* __restrict__ qk, float* __restrict__ rinv)
{
    const int g = blockIdx.x * 16 + (threadIdx.x >> 4);
    const int li = threadIdx.x & 15;
    const int bh = g >> 9, t = g & 511;
    const int b = bh >> 3, head = bh & 7;
    const float4* row = reinterpret_cast<const float4*>(
        qk + ((size_t)(b * TT + t)) * DD + head * DHH);
    const float4 xv = row[li];
    float ss = xv.x * xv.x + xv.y * xv.y + xv.z * xv.z + xv.w * xv.w;
    ss += __shfl_xor(ss, 1); ss += __shfl_xor(ss, 2);
    ss += __shfl_xor(ss, 4); ss += __shfl_xor(ss, 8);
    if (li == 0) rinv[g] = 1.0f / fmaxf(sqrtf(ss), 1e-12f);
}

// ---------------------------------------------------------------------------
// Bucket assignment + stable partition (f32 — must match numpy)
__global__ __launch_bounds__(512)
void bucket_sort_kernel(const float* __restrict__ qk, const float* __restrict__ rot,
                        int* __restrict__ st)
{
    const int h = blockIdx.x, bh = blockIdx.y;
    const int b = bh >> 3, head = bh & 7;
    const int t = threadIdx.x;
    __shared__ float rc[64];
    __shared__ int zcnt[8];
    if (t < 64) rc[t] = rot[t * NHASH + h];
    __syncthreads();
    const float4* row = reinterpret_cast<const float4*>(
        qk + ((size_t)(b * TT + t)) * DD + head * DHH);
    float r = 0.0f;
    #pragma unroll
    for (int u = 0; u < 16; ++u) {
        const float4 q4 = row[u];
        r += q4.x * rc[u * 4] + q4.y * rc[u * 4 + 1]
           + q4.z * rc[u * 4 + 2] + q4.w * rc[u * 4 + 3];
    }
    const int bit = (r < 0.0f) ? 1 : 0;
    const int wid = t >> 6, lane = t & 63;
    const unsigned long long zm = __ballot(bit == 0);
    if (lane == 0) zcnt[wid] = __popcll(zm);
    __syncthreads();
    int zoff = 0, Z = 0;
    #pragma unroll
    for (int w = 0; w < 8; ++w) { const int cn = zcnt[w]; if (w < wid) zoff += cn; Z += cn; }
    const int zpre = __popcll(zm & ((1ull << lane) - 1ull));
    const int dst = (bit == 0) ? (zoff + zpre)
                               : (Z + (wid * 64 - zoff) + (lane - zpre));
    st[((size_t)bh * NHASH + h) * TT + dst] = t;
}

// ---------------------------------------------------------------------------
// MFMA LSH attention (V input bf16; O output f32).
__global__ __launch_bounds__(256)
void lsh_attn_mfma(const float* __restrict__ qk, const u16* __restrict__ v,
                   const float* __restrict__ rinv, const int* __restrict__ st,
                   float* __restrict__ o_hash, float* __restrict__ lse_hash)
{
    const int cc = blockIdx.x, bh = blockIdx.y;
    const int b = bh >> 3, head = bh & 7;
    const int h = cc >> 1, c = cc & 1;
    const int pcc = (cc + 7) & 7;
    const int hp = pcc >> 1, cp = pcc & 1;
    const int tid = threadIdx.x;
    const int w = tid >> 6;
    const int lane = tid & 63;
    const int l31 = lane & 31;
    const int hi = lane >> 5;
    const int* stb = st + (size_t)bh * (NHASH * TT);
    const size_t qkbase = ((size_t)b * TT) * DD + head * DHH;

    __shared__ __align__(16) u16 Kbf[64 * 64];
    __shared__ __align__(16) u16 VTbf[64 * 64];
    __shared__ int ktl[64];
    __shared__ float lW[4][64];
    __shared__ int qtW[4][64];
    __shared__ float Ost[4][32 * 33];

    int q_t[2]; float mq2[2], mnat[2];
    unsigned QF[2][4][4];
    #pragma unroll
    for (int qt = 0; qt < 2; ++qt) {
        const int qtk = stb[h * TT + c * CHUNKSZ + w * 64 + qt * 32 + l31];
        q_t[qt] = qtk;
        const float* qrow = qk + qkbase + (size_t)qtk * DD;
        float ss = 0.f;
        #pragma unroll
        for (int ds = 0; ds < 4; ++ds) {
            const int d0 = ds * 16 + hi * 8;
            const float4 f0 = *(const float4*)(qrow + d0);
            const float4 f1 = *(const float4*)(qrow + d0 + 4);
            ss += f0.x*f0.x + f0.y*f0.y + f0.z*f0.z + f0.w*f0.w
                + f1.x*f1.x + f1.y*f1.y + f1.z*f1.z + f1.w*f1.w;
            QF[qt][ds][0] = pk_bf16(f0.x, f0.y);
            QF[qt][ds][1] = pk_bf16(f0.z, f0.w);
            QF[qt][ds][2] = pk_bf16(f1.x, f1.y);
            QF[qt][ds][3] = pk_bf16(f1.z, f1.w);
        }
        ss += __shfl_xor(ss, 32);
        const float qn = sqrtf(ss);
        mnat[qt] = qn * 0.125f;
        mq2[qt]  = qn * 0.1803368801111137f;
    }

    f16x acc[2][2] = {};
    float lacc[2] = {0.f, 0.f};
    const int kk = tid & 63, seg = tid >> 6;
    const float C1 = 0.1803368801111137f;

    for (int kt8 = 0; kt8 < 8; ++kt8) {
        const int kj = kt8 * 64 + kk;
        const int k_t = (kj < CHUNKSZ) ? stb[h * TT + c * CHUNKSZ + kj]
                                       : stb[hp * TT + cp * CHUNKSZ + (kj - CHUNKSZ)];
        const float rv = rinv[bh * TT + k_t];
        const float* krow = qk + qkbase + (size_t)k_t * DD + seg * 16;
        const u16*   vrow = v  + qkbase + (size_t)k_t * DD + seg * 16;
        const float4 ka = ((const float4*)krow)[0], kb2 = ((const float4*)krow)[1],
                     kc = ((const float4*)krow)[2], kd = ((const float4*)krow)[3];
        const uint4 vw0 = ((const uint4*)vrow)[0];
        const uint4 vw1 = ((const uint4*)vrow)[1];
        __syncthreads();
        {
            const int rbase = kk * 128 + seg * 32;
            const int swz = (kk & 7) << 4;
            *(uint4*)((char*)Kbf + ((rbase)      ^ swz)) =
                make_uint4(pk_bf16(ka.x*rv, ka.y*rv), pk_bf16(ka.z*rv, ka.w*rv),
                           pk_bf16(kb2.x*rv, kb2.y*rv), pk_bf16(kb2.z*rv, kb2.w*rv));
            *(uint4*)((char*)Kbf + ((rbase + 16) ^ swz)) =
                make_uint4(pk_bf16(kc.x*rv, kc.y*rv), pk_bf16(kc.z*rv, kc.w*rv),
                           pk_bf16(kd.x*rv, kd.y*rv), pk_bf16(kd.z*rv, kd.w*rv));
        }
        {
            const unsigned vu[8] = {vw0.x, vw0.y, vw0.z, vw0.w,
                                    vw1.x, vw1.y, vw1.z, vw1.w};
            #pragma unroll
            for (int i = 0; i < 16; ++i) {
                const int d = seg * 16 + i;
                const u16 hv = (u16)((i & 1) ? (vu[i >> 1] >> 16) : (vu[i >> 1] & 0xffff));
                *(u16*)((char*)VTbf + ((d * 128 + kk * 2) ^ ((d & 7) << 4))) = hv;
            }
        }
        if (tid < 64) ktl[tid] = k_t;
        __syncthreads();

        #pragma unroll
        for (int kt = 0; kt < 2; ++kt) {
            int ktv[16];
            #pragma unroll
            for (int i = 0; i < 16; ++i)
                ktv[i] = ktl[kt * 32 + (i & 3) + 8 * (i >> 2) + 4 * hi];
            FragU KA[4];
            #pragma unroll
            for (int ds = 0; ds < 4; ++ds) {
                const int row = kt * 32 + l31;
                KA[ds].v4 = *(const uint4*)((const char*)Kbf +
                    ((row * 128 + ds * 32 + hi * 16) ^ ((row & 7) << 4)));
            }
            FragU VA[2][2];
            #pragma unroll
            for (int dt = 0; dt < 2; ++dt)
                #pragma unroll
                for (int u = 0; u < 2; ++u) {
                    const int row = dt * 32 + l31;
                    const int ks = kt * 2 + u;
                    VA[dt][u].v4 = *(const uint4*)((const char*)VTbf +
                        ((row * 128 + ks * 32 + hi * 16) ^ ((row & 7) << 4)));
                }
            #pragma unroll
            for (int qt = 0; qt < 2; ++qt) {
                f16x s = {0.f,0.f,0.f,0.f,0.f,0.f,0.f,0.f,
                          0.f,0.f,0.f,0.f,0.f,0.f,0.f,0.f};
                #pragma unroll
                for (int ds = 0; ds < 4; ++ds) {
                    FragU qf;
                    qf.u[0] = QF[qt][ds][0]; qf.u[1] = QF[qt][ds][1];
                    qf.u[2] = QF[qt][ds][2]; qf.u[3] = QF[qt][ds][3];
                    s = __builtin_amdgcn_mfma_f32_32x32x16_bf16(KA[ds].f, qf.f, s, 0, 0, 0);
                }
                float pv[16];
                #pragma unroll
                for (int i = 0; i < 16; ++i) {
                    const float e = exp2f(fmaf(s[i], C1, -mq2[qt]));
                    const float p = (q_t[qt] > ktv[i]) ? e : 0.0f;
                    pv[i] = p;
                    lacc[qt] += p;
                }
                unsigned P2[8], S2[8];
                #pragma unroll
                for (int g = 0; g < 4; ++g) {
                    P2[2*g]   = pk_bf16(pv[4*g],   pv[4*g+1]);
                    P2[2*g+1] = pk_bf16(pv[4*g+2], pv[4*g+3]);
                }
                #pragma unroll
                for (int i = 0; i < 8; ++i)
                    S2[i] = (unsigned)__shfl_xor((int)P2[i], 32);
                #pragma unroll
                for (int u = 0; u < 2; ++u) {
                    FragU bfv;
                    bfv.u[0] = hi ? S2[2*(2*u+1)]     : P2[2*(2*u)];
                    bfv.u[1] = hi ? S2[2*(2*u+1) + 1] : P2[2*(2*u) + 1];
                    bfv.u[2] = hi ? P2[2*(2*u+1)]     : S2[2*(2*u)];
                    bfv.u[3] = hi ? P2[2*(2*u+1) + 1] : S2[2*(2*u) + 1];
                    #pragma unroll
                    for (int dt = 0; dt < 2; ++dt)
                        acc[dt][qt] = __builtin_amdgcn_mfma_f32_32x32x16_bf16(
                            VA[dt][u].f, bfv.f, acc[dt][qt], 0, 0, 0);
                }
            }
        }
    }

    float invl[2];
    #pragma unroll
    for (int qt = 0; qt < 2; ++qt) {
        const float lt = lacc[qt] + __shfl_xor(lacc[qt], 32);
        invl[qt] = (lt > 0.f) ? 1.0f / lt : 0.0f;
        const float lse = (lt > 0.f) ? (mnat[qt] + logf(lt)) : -5.0e4f;
        if (hi == 0) {
            lW[w][qt * 32 + l31] = lt;
            qtW[w][qt * 32 + l31] = q_t[qt];
            lse_hash[(size_t)(bh * NHASH + h) * TT + q_t[qt]] = lse;
        }
    }
    __syncthreads();

    float* ost = Ost[w];
    #pragma unroll
    for (int qt = 0; qt < 2; ++qt)
        #pragma unroll
        for (int dt = 0; dt < 2; ++dt) {
            #pragma unroll
            for (int r = 0; r < 16; ++r) {
                const int row = (r & 3) + 8 * (r >> 2) + 4 * hi;
                ost[row * 33 + l31] = acc[dt][qt][r] * invl[qt];
            }
            const int qq = lane >> 1, h2 = lane & 1;
            const int qglob = qtW[w][qt * 32 + qq];
            const float lq = lW[w][qt * 32 + qq];
            float ov[16];
            #pragma unroll
            for (int i = 0; i < 16; ++i)
                ov[i] = ost[(h2 * 16 + i) * 33 + qq];
            float* orow = o_hash + ((size_t)(bh * NHASH + h) * TT + qglob) * DHH
                        + dt * 32 + h2 * 16;
            if (lq > 0.f) {
                ((float4*)orow)[0] = make_float4(ov[0],  ov[1],  ov[2],  ov[3]);
                ((float4*)orow)[1] = make_float4(ov[4],  ov[5],  ov[6],  ov[7]);
                ((float4*)orow)[2] = make_float4(ov[8],  ov[9],  ov[10], ov[11]);
                ((float4*)orow)[3] = make_float4(ov[12], ov[13], ov[14], ov[15]);
            } else {
                const u16* vrow = v + qkbase + (size_t)qglob * DD + dt * 32 + h2 * 16;
                ((float4*)orow)[0] = make_float4(b2f(vrow[0]), b2f(vrow[1]), b2f(vrow[2]), b2f(vrow[3]));
                ((float4*)orow)[1] = make_float4(b2f(vrow[4]), b2f(vrow[5]), b2f(vrow[6]), b2f(vrow[7]));
                ((float4*)orow)[2] = make_float4(b2f(vrow[8]), b2f(vrow[9]), b2f(vrow[10]), b2f(vrow[11]));
                ((float4*)orow)[3] = make_float4(b2f(vrow[12]), b2f(vrow[13]), b2f(vrow[14]), b2f(vrow[15]));
            }
        }
}

// ---------------------------------------------------------------------------
// Combine hash rounds: read o f32, write merged bf16 (wo GEMM A-operand)
__global__ __launch_bounds__(256)
void combine_kernel(const float* __restrict__ o_hash, const float* __restrict__ lse_hash,
                    u16* __restrict__ am)
{
    const int idx = blockIdx.x * 4 + (threadIdx.x >> 6);
    const int lane = threadIdx.x & 63;
    const int bh = idx >> 9, t = idx & 511;
    const int b = bh >> 3, head = bh & 7;
    const float ls0 = lse_hash[(size_t)(bh * NHASH + 0) * TT + t];
    const float ls1 = lse_hash[(size_t)(bh * NHASH + 1) * TT + t];
    const float ls2 = lse_hash[(size_t)(bh * NHASH + 2) * TT + t];
    const float ls3 = lse_hash[(size_t)(bh * NHASH + 3) * TT + t];
    const float M = fmaxf(fmaxf(ls0, ls1), fmaxf(ls2, ls3));
    const float e0 = __expf(ls0 - M), e1 = __expf(ls1 - M);
    const float e2 = __expf(ls2 - M), e3 = __expf(ls3 - M);
    const float inv = 1.0f / (e0 + e1 + e2 + e3);
    const float o =
        (e0 * o_hash[((size_t)((bh * NHASH + 0) * TT + t)) * DHH + lane] +
         e1 * o_hash[((size_t)((bh * NHASH + 1) * TT + t)) * DHH + lane] +
         e2 * o_hash[((size_t)((bh * NHASH + 2) * TT + t)) * DHH + lane] +
         e3 * o_hash[((size_t)((bh * NHASH + 3) * TT + t)) * DHH + lane]) * inv;
    am[((size_t)(b * TT + t)) * DD + head * DHH + lane] = bf16_1(o);
}

// ---------------------------------------------------------------------------
// Final head
__device__ __forceinline__ float block_sum256(float v, volatile float* red)
{
    const int lane = threadIdx.x & 63, wid = threadIdx.x >> 6;
    #pragma unroll
    for (int o = 1; o < 64; o <<= 1) v += __shfl_xor(v, o);
    __syncthreads();
    if (lane == 0) red[wid] = v;
    __syncthreads();
    return red[0] + red[1] + red[2] + red[3];
}

__global__ __launch_bounds__(256)
void head_kernel(const float* __restrict__ x1, const float* __restrict__ x2,
                 const float* __restrict__ lnfg, const float* __restrict__ lnfb,
                 const float* __restrict__ hw1, const float* __restrict__ hb1,
                 const float* __restrict__ hlng, const float* __restrict__ hlnb,
                 const float* __restrict__ hw2, const float* __restrict__ hb2,
                 float* __restrict__ out)
{
    __shared__ float nrow[512];
    __shared__ float red[4];
    const int b = blockIdx.x, tid = threadIdx.x;
    const size_t roff = ((size_t)b * TT + (TT - 1)) * DD;
    const float v0 = 0.5f * (x1[roff + tid] + x2[roff + tid]);
    const float v1 = 0.5f * (x1[roff + 256 + tid] + x2[roff + 256 + tid]);
    const float mean = block_sum256(v0 + v1, red) * (1.0f / 512.0f);
    const float d0 = v0 - mean, d1 = v1 - mean;
    const float var = block_sum256(d0 * d0 + d1 * d1, red) * (1.0f / 512.0f);
    const float rstd = rsqrtf(var + 1e-5f);
    nrow[tid]       = d0 * rstd * lnfg[tid] + lnfb[tid];
    nrow[tid + 256] = d1 * rstd * lnfg[tid + 256] + lnfb[tid + 256];
    __syncthreads();
    float a = hb1[tid];
    for (int k = 0; k < 512; ++k) a = fmaf(nrow[k], hw1[(size_t)k * 256 + tid], a);
    const float m2 = block_sum256(a, red) * (1.0f / 256.0f);
    const float dd = a - m2;
    const float var2 = block_sum256(dd * dd, red) * (1.0f / 256.0f);
    float y = dd * rsqrtf(var2 + 1e-5f) * hlng[tid] + hlnb[tid];
    y = fmaxf(y, 0.0f);
    const float osum = block_sum256(y * hw2[tid], red);
    if (tid == 0) out[b] = osum + hb2[0];
}

// ---------------------------------------------------------------------------
extern "C" void kernel_launch(void* const* d_in, const int* in_sizes, int n_in,
                              void* d_out, int out_size, void* d_ws, size_t ws_size,
                              hipStream_t stream)
{
    (void)in_sizes; (void)n_in; (void)out_size; (void)ws_size;
    const float* x    = (const float*)d_in[0];
    const float* embw = (const float*)d_in[1];
    const float* embb = (const float*)d_in[2];
    const float* pos  = (const float*)d_in[3];
    const float* ln1g = (const float*)d_in[4];
    const float* ln1b = (const float*)d_in[5];
    const float* wqk  = (const float*)d_in[6];
    const float* wv   = (const float*)d_in[7];
    const float* wo   = (const float*)d_in[8];
    const float* wob  = (const float*)d_in[9];
    const float* ln2g = (const float*)d_in[10];
    const float* ln2b = (const float*)d_in[11];
    const float* ffw1 = (const float*)d_in[12];
    const float* ffb1 = (const float*)d_in[13];
    const float* ffw2 = (const float*)d_in[14];
    const float* ffb2 = (const float*)d_in[15];
    const float* rot  = (const float*)d_in[16];
    const float* lnfg = (const float*)d_in[17];
    const float* lnfb = (const float*)d_in[18];
    const float* hw1  = (const float*)d_in[19];
    const float* hb1  = (const float*)d_in[20];
    const float* hlng = (const float*)d_in[21];
    const float* hlnb = (const float*)d_in[22];
    const float* hw2  = (const float*)d_in[23];
    const float* hb2  = (const float*)d_in[24];
    float* out = (float*)d_out;

    const size_t SZ_BTD = (size_t)BB * TT * DD;            // 4,194,304
    const size_t SZ_OH  = (size_t)BHH * NHASH * TT * DHH;  // 16,777,216

    char* p = (char*)d_ws;
    float* x1b = (float*)p;  p += SZ_BTD * 4;
    float* x2b = (float*)p;  p += SZ_BTD * 4;
    float* xnb = (float*)p;  p += SZ_BTD * 4;
    float* qkb = (float*)p;  p += SZ_BTD * 4;
    u16*   vbh = (u16*)p;    p += SZ_BTD * 2;
    float* ohash = (float*)p;                    // 67MB region
    u16*   ffmid = (u16*)p;                      // temporal alias (1st half)
    u16*   xnbh  = (u16*)p + SZ_OH;              // 2nd half of region
    p += SZ_OH * 4;
    float* lseb  = (float*)p; p += (size_t)BHH * NHASH * TT * 4;
    float* rinvb = (float*)p; p += (size_t)BHH * TT * 4;
    int*   stb   = (int*)p;   p += (size_t)BHH * NHASH * TT * 4;
    u16* wvT = (u16*)p; p += (size_t)DD * DD * 2;
    u16* woT = (u16*)p; p += (size_t)DD * DD * 2;
    u16* w1T = (u16*)p; p += (size_t)DD * FFD * 2;
    u16* w2T = (u16*)p; p += (size_t)FFD * DD * 2;
    u16* amb = (u16*)qkb;                        // alias, used after attention

    embed_kernel<<<BB * TT, 256, 0, stream>>>(x, embw, embb, pos, x1b, x2b);

    for (int L = 0; L < NLAYER; ++L) {
        const size_t wOff  = (size_t)L * DD * DD;
        const size_t f1Off = (size_t)L * DD * FFD;
        const size_t f2Off = (size_t)L * FFD * DD;

        transpose_bf16<<<dim3(DD / 32, DD / 32), 256, 0, stream>>>(wv + wOff, wvT, DD, DD);
        transpose_bf16<<<dim3(DD / 32, DD / 32), 256, 0, stream>>>(wo + wOff, woT, DD, DD);
        transpose_bf16<<<dim3(DD / 32, FFD / 32), 256, 0, stream>>>(ffw1 + f1Off, w1T, DD, FFD);
        transpose_bf16<<<dim3(FFD / 32, DD / 32), 256, 0, stream>>>(ffw2 + f2Off, w2T, FFD, DD);

        // x1 += attn(ln(x2))
        ln_kernel<<<2048, 256, 0, stream>>>(x2b, ln1g + L * DD, ln1b + L * DD, xnb, xnbh);
        gemm_f32<false, false, false><<<dim3(128, 8), 256, 0, stream>>>(
            xnb, wqk + wOff, nullptr, nullptr, qkb, BB * TT, DD, DD);
        gemm_bf16<false, false, false, true><<<dim3(64, 4), 256, 0, stream>>>(
            xnbh, wvT, nullptr, nullptr, nullptr, vbh, BB * TT, DD, DD);
        rownorm_kernel<<<4096, 256, 0, stream>>>(qkb, rinvb);
        bucket_sort_kernel<<<dim3(NHASH, BHH), 512, 0, stream>>>(
            qkb, rot + (size_t)L * DHH * NHASH, stb);
        lsh_attn_mfma<<<dim3(NCHUNK, BHH), 256, 0, stream>>>(
            qkb, vbh, rinvb, stb, ohash, lseb);
        combine_kernel<<<16384, 256, 0, stream>>>(ohash, lseb, amb);
        gemm_bf16<false, true, true, false><<<dim3(64, 4), 256, 0, stream>>>(
            amb, woT, wob + L * DD, x1b, x1b, nullptr, BB * TT, DD, DD);

        // x2 += ff(ln(x1))
        ln_kernel<<<2048, 256, 0, stream>>>(x1b, ln2g + L * DD, ln2b + L * DD, xnb, xnbh);
        gemm_bf16<true, false, true, true><<<dim3(64, 16), 256, 0, stream>>>(
            xnbh, w1T, ffb1 + L * FFD, nullptr, nullptr, ffmid, BB * TT, FFD, DD);
        gemm_bf16<false, true, true, false><<<dim3(64, 4), 256, 0, stream>>>(
            ffmid, w2T, ffb2 + L * DD, x2b, x2b, nullptr, BB * TT, DD, FFD);
    }

    head_kernel<<<16, 256, 0, stream>>>(x1b, x2b, lnfg, lnfb, hw1, hb1,
                                        hlng, hlnb, hw2, hb2, out);
}

// Round 4
// 1340.502 us; speedup vs baseline: 5.4773x; 1.2119x over previous
//
#include <hip/hip_runtime.h>
#include <cfloat>
#include <cstdint>

// Problem constants
#define BB      16      // batch
#define TT      512     // seq
#define DD      512     // d_model
#define HH      8       // heads
#define DHH     64      // head dim
#define FFD     2048    // ff dim
#define BHH     128     // BB*HH
#define NHASH   4
#define NCHUNK  8       // NHASH * N_BUCKETS
#define CHUNKSZ 256
#define NLAYER  4

typedef unsigned short u16;
typedef unsigned int   u32;
typedef __attribute__((ext_vector_type(8))) short bfrag;    // 8 bf16 (4 VGPR)
typedef __attribute__((ext_vector_type(4))) float f4x;      // 4 f32 acc
typedef __attribute__((ext_vector_type(16))) float f16x;    // 16 f32 acc

union FragU { u32 u[4]; uint4 v4; bfrag f; };

__device__ __forceinline__ unsigned pk_bf16(float a, float b) {
    union { float f; unsigned u; } x, y;
    x.f = a; y.f = b;
    unsigned lo = ((x.u + 0x7FFFu + ((x.u >> 16) & 1u)) >> 16) & 0xFFFFu;
    unsigned hi = (y.u + 0x7FFFu + ((y.u >> 16) & 1u)) & 0xFFFF0000u;
    return lo | hi;
}
// HW packed f32->bf16 RTNE (1 VALU op; no builtin on gfx950)
__device__ __forceinline__ unsigned cvt_pk(float a, float b) {
    unsigned r;
    asm("v_cvt_pk_bf16_f32 %0, %1, %2" : "=v"(r) : "v"(a), "v"(b));
    return r;
}
__device__ __forceinline__ u16 bf16_1(float a) {
    union { float f; unsigned u; } x; x.f = a;
    return (u16)((x.u + 0x7FFFu + ((x.u >> 16) & 1u)) >> 16);
}
__device__ __forceinline__ float b2f(u16 h) {
    union { unsigned u; float f; } x; x.u = ((unsigned)h) << 16; return x.f;
}

// async global->LDS, 16B per lane (dest must be linear: base + lane*16)
__device__ __forceinline__ void gload16(const u16* g, u16* l) {
    __builtin_amdgcn_global_load_lds(
        (const __attribute__((address_space(1))) u32*)g,
        (__attribute__((address_space(3))) u32*)l, 16, 0, 0);
}

// ---------------------------------------------------------------------------
// Embedding: h = x @ emb_w + emb_b + pos ; write to both x1 and x2
__global__ __launch_bounds__(256)
void embed_kernel(const float* __restrict__ x, const float* __restrict__ ew,
                  const float* __restrict__ eb, const float* __restrict__ pos,
                  float* __restrict__ x1, float* __restrict__ x2)
{
    const int row = blockIdx.x;          // b*T + t
    const int t = row & (TT - 1);
    __shared__ float xr[32];
    if (threadIdx.x < 32) xr[threadIdx.x] = x[row * 32 + threadIdx.x];
    __syncthreads();
    for (int d = threadIdx.x; d < DD; d += 256) {
        float s = eb[d] + pos[t * DD + d];
        #pragma unroll
        for (int k = 0; k < 32; ++k) s = fmaf(xr[k], ew[k * DD + d], s);
        x1[(size_t)row * DD + d] = s;
        x2[(size_t)row * DD + d] = s;
    }
}

// ---------------------------------------------------------------------------
// LayerNorm over last dim (512); writes f32 AND bf16 outputs.
__global__ __launch_bounds__(256)
void ln_kernel(const float* __restrict__ in, const float* __restrict__ g,
               const float* __restrict__ bta, float* __restrict__ out,
               u16* __restrict__ outh)
{
    const int row = blockIdx.x * 4 + (threadIdx.x >> 6);
    const int lane = threadIdx.x & 63;
    const float* r = in + (size_t)row * DD;
    float vals[8];
    float s = 0.0f;
    #pragma unroll
    for (int i = 0; i < 8; ++i) { vals[i] = r[i * 64 + lane]; s += vals[i]; }
    #pragma unroll
    for (int o = 1; o < 64; o <<= 1) s += __shfl_xor(s, o);
    const float mean = s * (1.0f / 512.0f);
    float vs = 0.0f;
    #pragma unroll
    for (int i = 0; i < 8; ++i) { float d = vals[i] - mean; vs += d * d; }
    #pragma unroll
    for (int o = 1; o < 64; o <<= 1) vs += __shfl_xor(vs, o);
    const float rstd = rsqrtf(vs * (1.0f / 512.0f) + 1e-5f);
    float* orow = out + (size_t)row * DD;
    u16* hrow = outh + (size_t)row * DD;
    #pragma unroll
    for (int i = 0; i < 8; ++i) {
        const int d = i * 64 + lane;
        const float y = (vals[i] - mean) * rstd * g[d] + bta[d];
        orow[d] = y;
        hrow[d] = bf16_1(y);
    }
}

// ---------------------------------------------------------------------------
// Weight transpose+convert: in (K x N, f32) -> out (N x K, bf16)
__global__ __launch_bounds__(256)
void transpose_bf16(const float* __restrict__ in, u16* __restrict__ out,
                    int K, int N)
{
    __shared__ float tile[32][33];
    const int kt = blockIdx.x * 32, nt = blockIdx.y * 32;
    const int r = threadIdx.x >> 3, c4 = (threadIdx.x & 7) * 4;
    const float4 v4 = *(const float4*)(in + (size_t)(kt + r) * N + nt + c4);
    tile[r][c4 + 0] = v4.x; tile[r][c4 + 1] = v4.y;
    tile[r][c4 + 2] = v4.z; tile[r][c4 + 3] = v4.w;
    __syncthreads();
    uint2 p;
    p.x = pk_bf16(tile[c4 + 0][r], tile[c4 + 1][r]);
    p.y = pk_bf16(tile[c4 + 2][r], tile[c4 + 3][r]);
    *(uint2*)(out + (size_t)(nt + r) * K + kt + c4) = p;
}

// ---------------------------------------------------------------------------
// f32 GEMM for qk only (keeps LSH bucket decisions f32-exact).
// 64x64 tile, K-step 32, register-prefetch double buffer, 1 LDS buffer.
__global__ __launch_bounds__(256)
void gemm_f32_qk(const float* __restrict__ A, const float* __restrict__ W,
                 float* __restrict__ C, int M, int N, int K)
{
    __shared__ float As[32][68];   // [k][m]
    __shared__ float Ws[32][68];   // [k][n]
    const int tid = threadIdx.x;
    const int m0 = blockIdx.x * 64, n0 = blockIdx.y * 64;
    const int tm = tid >> 4, tn = tid & 15;
    const int lam = tid >> 2, lak = (tid & 3) * 8;   // A: row lam, k lak..+8
    const int lwk = tid >> 3, lwn = (tid & 7) * 8;   // W: k lwk, n lwn..+8
    const float* Ap = A + (size_t)(m0 + lam) * K + lak;
    const float* Wp = W + (size_t)lwk * N + n0 + lwn;
    float4 a0 = ((const float4*)Ap)[0], a1 = ((const float4*)Ap)[1];
    float4 w0 = ((const float4*)Wp)[0], w1 = ((const float4*)Wp)[1];
    float c[4][4] = {};
    const int nT = K >> 5;
    for (int t = 0; t < nT; ++t) {
        __syncthreads();
        As[lak + 0][lam] = a0.x; As[lak + 1][lam] = a0.y;
        As[lak + 2][lam] = a0.z; As[lak + 3][lam] = a0.w;
        As[lak + 4][lam] = a1.x; As[lak + 5][lam] = a1.y;
        As[lak + 6][lam] = a1.z; As[lak + 7][lam] = a1.w;
        *(float4*)&Ws[lwk][lwn] = w0;
        *(float4*)&Ws[lwk][lwn + 4] = w1;
        __syncthreads();
        if (t + 1 < nT) {   // prefetch next tile into regs (hides under FMA)
            Ap += 32; Wp += (size_t)32 * N;
            a0 = ((const float4*)Ap)[0]; a1 = ((const float4*)Ap)[1];
            w0 = ((const float4*)Wp)[0]; w1 = ((const float4*)Wp)[1];
        }
        #pragma unroll
        for (int kk = 0; kk < 32; ++kk) {
            const float4 a = *(const float4*)&As[kk][tm * 4];
            const float4 w = *(const float4*)&Ws[kk][tn * 4];
            const float avr[4] = {a.x, a.y, a.z, a.w};
            const float wvr[4] = {w.x, w.y, w.z, w.w};
            #pragma unroll
            for (int i = 0; i < 4; ++i)
                #pragma unroll
                for (int j = 0; j < 4; ++j)
                    c[i][j] = fmaf(avr[i], wvr[j], c[i][j]);
        }
    }
    #pragma unroll
    for (int i = 0; i < 4; ++i) {
        const int row = m0 + tm * 4 + i;
        *(float4*)&C[(size_t)row * N + n0 + tn * 4] =
            make_float4(c[i][0], c[i][1], c[i][2], c[i][3]);
    }
}

// ---------------------------------------------------------------------------
// bf16 MFMA GEMM, templated tile, double-buffered LDS, 2-phase pipeline:
// one __syncthreads per K-step; STAGE(t+1) issued before compute(t) so
// global_load_lds latency hides under MFMA (T3-minimal).
__device__ __forceinline__ float gelu1(float v) {
    return 0.5f * v * (1.0f + erff(v * 0.70710678118654752440f));
}
__device__ __forceinline__ int swz_row(int r, int BK) {
    return (BK == 32) ? ((r & 3) ^ ((r >> 2) & 3)) : (r & 7);
}

template<int BM, int BN, int BK, bool GELU, bool ADD, bool BIAS, bool OUTBF>
__global__ __launch_bounds__(256)
void gemm_bf16(const u16* __restrict__ A, const u16* __restrict__ WT,
               const float* __restrict__ bias, const float* __restrict__ addsrc,
               float* __restrict__ Cf, u16* __restrict__ Cb,
               int M, int N, int K)
{
    constexpr int NCH = BK / 8;             // 16B chunks per row
    constexpr int CPA = BM * NCH / 256;     // chunks per thread
    constexpr int CPB = BN * NCH / 256;
    constexpr int MR = BM / 32, NR = BN / 32, KR = BK / 32;
    __shared__ __align__(16) u16 Abuf[2][BM * BK];
    __shared__ __align__(16) u16 Bbuf[2][BN * BK];
    const int tid = threadIdx.x;
    const int m0 = blockIdx.x * BM, n0 = blockIdx.y * BN;

    // pre-swizzled global sources (rule #21: linear LDS dest + inv-swz source)
    const u16* aSrc[CPA]; const u16* bSrc[CPB];
    #pragma unroll
    for (int i = 0; i < CPA; ++i) {
        const int s = tid + i * 256, row = s / NCH, ch = s % NCH;
        aSrc[i] = A + (size_t)(m0 + row) * K + (ch ^ swz_row(row, BK)) * 8;
    }
    #pragma unroll
    for (int i = 0; i < CPB; ++i) {
        const int s = tid + i * 256, row = s / NCH, ch = s % NCH;
        bSrc[i] = WT + (size_t)(n0 + row) * K + (ch ^ swz_row(row, BK)) * 8;
    }

    auto STAGE = [&](int bufi, int koff) {
        #pragma unroll
        for (int i = 0; i < CPA; ++i)
            gload16(aSrc[i] + koff, &Abuf[bufi][(tid + i * 256) * 8]);
        #pragma unroll
        for (int i = 0; i < CPB; ++i)
            gload16(bSrc[i] + koff, &Bbuf[bufi][(tid + i * 256) * 8]);
    };

    const int l = tid & 63, wv_ = tid >> 6;
    const int wm = (wv_ >> 1) * (BM / 2);
    const int wn = (wv_ & 1) * (BN / 2);
    const int fr = l & 15, fc = l >> 4;

    f4x acc[MR][NR] = {};
    const int nK = K / BK;
    STAGE(0, 0);
    for (int ks = 0; ks < nK; ++ks) {
        __syncthreads();                    // drains STAGE(ks) [vmcnt(0)+bar]
        if (ks + 1 < nK) STAGE((ks + 1) & 1, (ks + 1) * BK);
        const u16* Ab = Abuf[ks & 1];
        const u16* Bb = Bbuf[ks & 1];
        FragU af[MR][KR], bf_[NR][KR];
        #pragma unroll
        for (int i = 0; i < MR; ++i)
            #pragma unroll
            for (int u = 0; u < KR; ++u) {
                const int r = wm + i * 16 + fr;
                af[i][u].v4 = *(const uint4*)((const char*)Ab +
                    (size_t)r * (2 * BK) + (((u * 4 + fc) ^ swz_row(r, BK)) << 4));
            }
        #pragma unroll
        for (int j = 0; j < NR; ++j)
            #pragma unroll
            for (int u = 0; u < KR; ++u) {
                const int r = wn + j * 16 + fr;
                bf_[j][u].v4 = *(const uint4*)((const char*)Bb +
                    (size_t)r * (2 * BK) + (((u * 4 + fc) ^ swz_row(r, BK)) << 4));
            }
        #pragma unroll
        for (int u = 0; u < KR; ++u)
            #pragma unroll
            for (int i = 0; i < MR; ++i)
                #pragma unroll
                for (int j = 0; j < NR; ++j)
                    acc[i][j] = __builtin_amdgcn_mfma_f32_16x16x32_bf16(
                        af[i][u].f, bf_[j][u].f, acc[i][j], 0, 0, 0);
    }

    // epilogue: C row = fc*4 + q (A index), col = fr (B index)
    #pragma unroll
    for (int i = 0; i < MR; ++i) {
        #pragma unroll
        for (int q = 0; q < 4; ++q) {
            const int row = m0 + wm + i * 16 + fc * 4 + q;
            #pragma unroll
            for (int j = 0; j < NR; ++j) {
                const int col = n0 + wn + j * 16 + fr;
                float vx = acc[i][j][q];
                if constexpr (BIAS) vx += bias[col];
                if constexpr (GELU) vx = gelu1(vx);
                if constexpr (ADD) vx += addsrc[(size_t)row * N + col];
                if constexpr (OUTBF) Cb[(size_t)row * N + col] = bf16_1(vx);
                else Cf[(size_t)row * N + col] = vx;
            }
        }
    }
}

// ---------------------------------------------------------------------------
// K pre-normalization: qkn[bh][t][d] = bf16(qk_row / max(||qk_row||,1e-12))
__global__ __launch_bounds__(256)
void knorm_kernel(const float* __restrict__ qk, u16* __restrict__ qkn)
{
    const int g = blockIdx.x * 16 + (threadIdx.x >> 4);  // bh*T + t
    const int li = threadIdx.x & 15;
    const int bh = g >> 9, t = g & 511;
    const int b = bh >> 3, head = bh & 7;
    const float4 xv = reinterpret_cast<const float4*>(
        qk + ((size_t)(b * TT + t)) * DD + head * DHH)[li];
    float ss = xv.x * xv.x + xv.y * xv.y + xv.z * xv.z + xv.w * xv.w;
    ss += __shfl_xor(ss, 1); ss += __shfl_xor(ss, 2);
    ss += __shfl_xor(ss, 4); ss += __shfl_xor(ss, 8);
    const float rv = 1.0f / fmaxf(sqrtf(ss), 1e-12f);
    uint2 o;
    o.x = cvt_pk(xv.x * rv, xv.y * rv);
    o.y = cvt_pk(xv.z * rv, xv.w * rv);
    *(uint2*)(qkn + ((size_t)bh * TT + t) * DHH + li * 4) = o;
}

// ---------------------------------------------------------------------------
// Bucket assignment + stable partition (f32 — must match numpy)
__global__ __launch_bounds__(512)
void bucket_sort_kernel(const float* __restrict__ qk, const float* __restrict__ rot,
                        int* __restrict__ st)
{
    const int h = blockIdx.x, bh = blockIdx.y;
    const int b = bh >> 3, head = bh & 7;
    const int t = threadIdx.x;
    __shared__ float rc[64];
    __shared__ int zcnt[8];
    if (t < 64) rc[t] = rot[t * NHASH + h];
    __syncthreads();
    const float4* row = reinterpret_cast<const float4*>(
        qk + ((size_t)(b * TT + t)) * DD + head * DHH);
    float r = 0.0f;
    #pragma unroll
    for (int u = 0; u < 16; ++u) {
        const float4 q4 = row[u];
        r += q4.x * rc[u * 4] + q4.y * rc[u * 4 + 1]
           + q4.z * rc[u * 4 + 2] + q4.w * rc[u * 4 + 3];
    }
    const int bit = (r < 0.0f) ? 1 : 0;
    const int wid = t >> 6, lane = t & 63;
    const unsigned long long zm = __ballot(bit == 0);
    if (lane == 0) zcnt[wid] = __popcll(zm);
    __syncthreads();
    int zoff = 0, Z = 0;
    #pragma unroll
    for (int w = 0; w < 8; ++w) { const int cn = zcnt[w]; if (w < wid) zoff += cn; Z += cn; }
    const int zpre = __popcll(zm & ((1ull << lane) - 1ull));
    const int dst = (bit == 0) ? (zoff + zpre)
                               : (Z + (wid * 64 - zoff) + (lane - zpre));
    st[((size_t)bh * NHASH + h) * TT + dst] = t;
}

// ---------------------------------------------------------------------------
// MFMA LSH attention. Q from f32 qk; K from pre-normalized bf16 qkn;
// V bf16; O output bf16.
__global__ __launch_bounds__(256)
void lsh_attn_mfma(const float* __restrict__ qk, const u16* __restrict__ qkn,
                   const u16* __restrict__ v, const int* __restrict__ st,
                   u16* __restrict__ o_hash, float* __restrict__ lse_hash)
{
    const int cc = blockIdx.x, bh = blockIdx.y;
    const int b = bh >> 3, head = bh & 7;
    const int h = cc >> 1, c = cc & 1;
    const int pcc = (cc + 7) & 7;
    const int hp = pcc >> 1, cp = pcc & 1;
    const int tid = threadIdx.x;
    const int w = tid >> 6;
    const int lane = tid & 63;
    const int l31 = lane & 31;
    const int hi = lane >> 5;
    const int* stb = st + (size_t)bh * (NHASH * TT);
    const size_t qkbase = ((size_t)b * TT) * DD + head * DHH;
    const u16* qknb = qkn + (size_t)bh * TT * DHH;

    __shared__ __align__(16) u16 Kbf[64 * 64];
    __shared__ __align__(16) u16 VTbf[64 * 64];
    __shared__ int ktl[64];
    __shared__ float lW[4][64];
    __shared__ int qtW[4][64];
    __shared__ float Ost[4][32 * 33];

    int q_t[2]; float mq2[2], mnat[2];
    unsigned QF[2][4][4];
    #pragma unroll
    for (int qt = 0; qt < 2; ++qt) {
        const int qtk = stb[h * TT + c * CHUNKSZ + w * 64 + qt * 32 + l31];
        q_t[qt] = qtk;
        const float* qrow = qk + qkbase + (size_t)qtk * DD;
        float ss = 0.f;
        #pragma unroll
        for (int ds = 0; ds < 4; ++ds) {
            const int d0 = ds * 16 + hi * 8;
            const float4 f0 = *(const float4*)(qrow + d0);
            const float4 f1 = *(const float4*)(qrow + d0 + 4);
            ss += f0.x*f0.x + f0.y*f0.y + f0.z*f0.z + f0.w*f0.w
                + f1.x*f1.x + f1.y*f1.y + f1.z*f1.z + f1.w*f1.w;
            QF[qt][ds][0] = cvt_pk(f0.x, f0.y);
            QF[qt][ds][1] = cvt_pk(f0.z, f0.w);
            QF[qt][ds][2] = cvt_pk(f1.x, f1.y);
            QF[qt][ds][3] = cvt_pk(f1.z, f1.w);
        }
        ss += __shfl_xor(ss, 32);
        const float qn = sqrtf(ss);
        mnat[qt] = qn * 0.125f;
        mq2[qt]  = qn * 0.1803368801111137f;   // |q| * 0.125 * log2(e)
    }

    f16x acc[2][2] = {};
    float lacc[2] = {0.f, 0.f};
    const int kk = tid & 63, seg = tid >> 6;
    const float C1 = 0.1803368801111137f;      // 0.125 * log2(e)

    for (int kt8 = 0; kt8 < 8; ++kt8) {
        const int kj = kt8 * 64 + kk;
        const int k_t = (kj < CHUNKSZ) ? stb[h * TT + c * CHUNKSZ + kj]
                                       : stb[hp * TT + cp * CHUNKSZ + (kj - CHUNKSZ)];
        const u16* krow = qknb + (size_t)k_t * DHH + seg * 16;
        const u16* vrow = v + qkbase + (size_t)k_t * DD + seg * 16;
        const uint4 kv0 = ((const uint4*)krow)[0];
        const uint4 kv1 = ((const uint4*)krow)[1];
        const uint4 vw0 = ((const uint4*)vrow)[0];
        const uint4 vw1 = ((const uint4*)vrow)[1];
        __syncthreads();
        {
            const int rbase = kk * 128 + seg * 32;
            const int swz = (kk & 7) << 4;
            *(uint4*)((char*)Kbf + ((rbase)      ^ swz)) = kv0;
            *(uint4*)((char*)Kbf + ((rbase + 16) ^ swz)) = kv1;
        }
        {
            const unsigned vu[8] = {vw0.x, vw0.y, vw0.z, vw0.w,
                                    vw1.x, vw1.y, vw1.z, vw1.w};
            #pragma unroll
            for (int i = 0; i < 16; ++i) {
                const int d = seg * 16 + i;
                const u16 hv = (u16)((i & 1) ? (vu[i >> 1] >> 16) : (vu[i >> 1] & 0xffff));
                *(u16*)((char*)VTbf + ((d * 128 + kk * 2) ^ ((d & 7) << 4))) = hv;
            }
        }
        if (tid < 64) ktl[tid] = k_t;
        __syncthreads();

        #pragma unroll
        for (int kt = 0; kt < 2; ++kt) {
            int ktv[16];
            #pragma unroll
            for (int i = 0; i < 16; ++i)
                ktv[i] = ktl[kt * 32 + (i & 3) + 8 * (i >> 2) + 4 * hi];
            FragU KA[4];
            #pragma unroll
            for (int ds = 0; ds < 4; ++ds) {
                const int row = kt * 32 + l31;
                KA[ds].v4 = *(const uint4*)((const char*)Kbf +
                    ((row * 128 + ds * 32 + hi * 16) ^ ((row & 7) << 4)));
            }
            FragU VA[2][2];
            #pragma unroll
            for (int dt = 0; dt < 2; ++dt)
                #pragma unroll
                for (int u = 0; u < 2; ++u) {
                    const int row = dt * 32 + l31;
                    const int ks = kt * 2 + u;
                    VA[dt][u].v4 = *(const uint4*)((const char*)VTbf +
                        ((row * 128 + ks * 32 + hi * 16) ^ ((row & 7) << 4)));
                }
            #pragma unroll
            for (int qt = 0; qt < 2; ++qt) {
                f16x s = {0.f,0.f,0.f,0.f,0.f,0.f,0.f,0.f,
                          0.f,0.f,0.f,0.f,0.f,0.f,0.f,0.f};
                #pragma unroll
                for (int ds = 0; ds < 4; ++ds) {
                    FragU qf;
                    qf.u[0] = QF[qt][ds][0]; qf.u[1] = QF[qt][ds][1];
                    qf.u[2] = QF[qt][ds][2]; qf.u[3] = QF[qt][ds][3];
                    s = __builtin_amdgcn_mfma_f32_32x32x16_bf16(KA[ds].f, qf.f, s, 0, 0, 0);
                }
                float pv[16];
                #pragma unroll
                for (int i = 0; i < 16; ++i) {
                    const float sm = (q_t[qt] > ktv[i]) ? s[i] : -1.0e30f;
                    const float p = exp2f(fmaf(sm, C1, -mq2[qt]));
                    pv[i] = p;
                    lacc[qt] += p;
                }
                unsigned P2[8], S2[8];
                #pragma unroll
                for (int g = 0; g < 4; ++g) {
                    P2[2*g]   = cvt_pk(pv[4*g],   pv[4*g+1]);
                    P2[2*g+1] = cvt_pk(pv[4*g+2], pv[4*g+3]);
                }
                #pragma unroll
                for (int i = 0; i < 8; ++i)
                    S2[i] = (unsigned)__shfl_xor((int)P2[i], 32);
                #pragma unroll
                for (int u = 0; u < 2; ++u) {
                    FragU bfv;
                    bfv.u[0] = hi ? S2[2*(2*u+1)]     : P2[2*(2*u)];
                    bfv.u[1] = hi ? S2[2*(2*u+1) + 1] : P2[2*(2*u) + 1];
                    bfv.u[2] = hi ? P2[2*(2*u+1)]     : S2[2*(2*u)];
                    bfv.u[3] = hi ? P2[2*(2*u+1) + 1] : S2[2*(2*u) + 1];
                    #pragma unroll
                    for (int dt = 0; dt < 2; ++dt)
                        acc[dt][qt] = __builtin_amdgcn_mfma_f32_32x32x16_bf16(
                            VA[dt][u].f, bfv.f, acc[dt][qt], 0, 0, 0);
                }
            }
        }
    }

    float invl[2];
    #pragma unroll
    for (int qt = 0; qt < 2; ++qt) {
        const float lt = lacc[qt] + __shfl_xor(lacc[qt], 32);
        invl[qt] = (lt > 0.f) ? 1.0f / lt : 0.0f;
        const float lse = (lt > 0.f) ? (mnat[qt] + logf(lt)) : -5.0e4f;
        if (hi == 0) {
            lW[w][qt * 32 + l31] = lt;
            qtW[w][qt * 32 + l31] = q_t[qt];
            lse_hash[(size_t)(bh * NHASH + h) * TT + q_t[qt]] = lse;
        }
    }
    __syncthreads();

    float* ost = Ost[w];
    #pragma unroll
    for (int qt = 0; qt < 2; ++qt)
        #pragma unroll
        for (int dt = 0; dt < 2; ++dt) {
            #pragma unroll
            for (int r = 0; r < 16; ++r) {
                const int row = (r & 3) + 8 * (r >> 2) + 4 * hi;
                ost[row * 33 + l31] = acc[dt][qt][r] * invl[qt];
            }
            const int qq = lane >> 1, h2 = lane & 1;
            const int qglob = qtW[w][qt * 32 + qq];
            const float lq = lW[w][qt * 32 + qq];
            float ov[16];
            #pragma unroll
            for (int i = 0; i < 16; ++i)
                ov[i] = ost[(h2 * 16 + i) * 33 + qq];
            u16* orow = o_hash + ((size_t)(bh * NHASH + h) * TT + qglob) * DHH
                      + dt * 32 + h2 * 16;
            if (lq > 0.f) {
                uint4 o0, o1;
                o0.x = cvt_pk(ov[0],  ov[1]);  o0.y = cvt_pk(ov[2],  ov[3]);
                o0.z = cvt_pk(ov[4],  ov[5]);  o0.w = cvt_pk(ov[6],  ov[7]);
                o1.x = cvt_pk(ov[8],  ov[9]);  o1.y = cvt_pk(ov[10], ov[11]);
                o1.z = cvt_pk(ov[12], ov[13]); o1.w = cvt_pk(ov[14], ov[15]);
                ((uint4*)orow)[0] = o0;
                ((uint4*)orow)[1] = o1;
            } else {
                const u16* vr = v + qkbase + (size_t)qglob * DD + dt * 32 + h2 * 16;
                ((uint4*)orow)[0] = ((const uint4*)vr)[0];
                ((uint4*)orow)[1] = ((const uint4*)vr)[1];
            }
        }
}

// ---------------------------------------------------------------------------
// Combine hash rounds: read o_hash bf16, write merged bf16 (wo GEMM A-operand)
__global__ __launch_bounds__(256)
void combine_kernel(const u16* __restrict__ o_hash, const float* __restrict__ lse_hash,
                    u16* __restrict__ am)
{
    const int idx = blockIdx.x * 4 + (threadIdx.x >> 6);
    const int lane = threadIdx.x & 63;
    const int bh = idx >> 9, t = idx & 511;
    const int b = bh >> 3, head = bh & 7;
    const float ls0 = lse_hash[(size_t)(bh * NHASH + 0) * TT + t];
    const float ls1 = lse_hash[(size_t)(bh * NHASH + 1) * TT + t];
    const float ls2 = lse_hash[(size_t)(bh * NHASH + 2) * TT + t];
    const float ls3 = lse_hash[(size_t)(bh * NHASH + 3) * TT + t];
    const float M = fmaxf(fmaxf(ls0, ls1), fmaxf(ls2, ls3));
    const float e0 = __expf(ls0 - M), e1 = __expf(ls1 - M);
    const float e2 = __expf(ls2 - M), e3 = __expf(ls3 - M);
    const float inv = 1.0f / (e0 + e1 + e2 + e3);
    const float o =
        (e0 * b2f(o_hash[((size_t)((bh * NHASH + 0) * TT + t)) * DHH + lane]) +
         e1 * b2f(o_hash[((size_t)((bh * NHASH + 1) * TT + t)) * DHH + lane]) +
         e2 * b2f(o_hash[((size_t)((bh * NHASH + 2) * TT + t)) * DHH + lane]) +
         e3 * b2f(o_hash[((size_t)((bh * NHASH + 3) * TT + t)) * DHH + lane])) * inv;
    am[((size_t)(b * TT + t)) * DD + head * DHH + lane] = bf16_1(o);
}

// ---------------------------------------------------------------------------
// Final head
__device__ __forceinline__ float block_sum256(float v, volatile float* red)
{
    const int lane = threadIdx.x & 63, wid = threadIdx.x >> 6;
    #pragma unroll
    for (int o = 1; o < 64; o <<= 1) v += __shfl_xor(v, o);
    __syncthreads();
    if (lane == 0) red[wid] = v;
    __syncthreads();
    return red[0] + red[1] + red[2] + red[3];
}

__global__ __launch_bounds__(256)
void head_kernel(const float* __restrict__ x1, const float* __restrict__ x2,
                 const float* __restrict__ lnfg, const float* __restrict__ lnfb,
                 const float* __restrict__ hw1, const float* __restrict__ hb1,
                 const float* __restrict__ hlng, const float* __restrict__ hlnb,
                 const float* __restrict__ hw2, const float* __restrict__ hb2,
                 float* __restrict__ out)
{
    __shared__ float nrow[512];
    __shared__ float red[4];
    const int b = blockIdx.x, tid = threadIdx.x;
    const size_t roff = ((size_t)b * TT + (TT - 1)) * DD;
    const float v0 = 0.5f * (x1[roff + tid] + x2[roff + tid]);
    const float v1 = 0.5f * (x1[roff + 256 + tid] + x2[roff + 256 + tid]);
    const float mean = block_sum256(v0 + v1, red) * (1.0f / 512.0f);
    const float d0 = v0 - mean, d1 = v1 - mean;
    const float var = block_sum256(d0 * d0 + d1 * d1, red) * (1.0f / 512.0f);
    const float rstd = rsqrtf(var + 1e-5f);
    nrow[tid]       = d0 * rstd * lnfg[tid] + lnfb[tid];
    nrow[tid + 256] = d1 * rstd * lnfg[tid + 256] + lnfb[tid + 256];
    __syncthreads();
    float a = hb1[tid];
    for (int k = 0; k < 512; ++k) a = fmaf(nrow[k], hw1[(size_t)k * 256 + tid], a);
    const float m2 = block_sum256(a, red) * (1.0f / 256.0f);
    const float dd = a - m2;
    const float var2 = block_sum256(dd * dd, red) * (1.0f / 256.0f);
    float y = dd * rsqrtf(var2 + 1e-5f) * hlng[tid] + hlnb[tid];
    y = fmaxf(y, 0.0f);
    const float osum = block_sum256(y * hw2[tid], red);
    if (tid == 0) out[b] = osum + hb2[0];
}

// ---------------------------------------------------------------------------
extern "C" void kernel_launch(void* const* d_in, const int* in_sizes, int n_in,
                              void* d_out, int out_size, void* d_ws, size_t ws_size,
                              hipStream_t stream)
{
    (void)in_sizes; (void)n_in; (void)out_size; (void)ws_size;
    const float* x    = (const float*)d_in[0];
    const float* embw = (const float*)d_in[1];
    const float* embb = (const float*)d_in[2];
    const float* pos  = (const float*)d_in[3];
    const float* ln1g = (const float*)d_in[4];
    const float* ln1b = (const float*)d_in[5];
    const float* wqk  = (const float*)d_in[6];
    const float* wv   = (const float*)d_in[7];
    const float* wo   = (const float*)d_in[8];
    const float* wob  = (const float*)d_in[9];
    const float* ln2g = (const float*)d_in[10];
    const float* ln2b = (const float*)d_in[11];
    const float* ffw1 = (const float*)d_in[12];
    const float* ffb1 = (const float*)d_in[13];
    const float* ffw2 = (const float*)d_in[14];
    const float* ffb2 = (const float*)d_in[15];
    const float* rot  = (const float*)d_in[16];
    const float* lnfg = (const float*)d_in[17];
    const float* lnfb = (const float*)d_in[18];
    const float* hw1  = (const float*)d_in[19];
    const float* hb1  = (const float*)d_in[20];
    const float* hlng = (const float*)d_in[21];
    const float* hlnb = (const float*)d_in[22];
    const float* hw2  = (const float*)d_in[23];
    const float* hb2  = (const float*)d_in[24];
    float* out = (float*)d_out;

    const size_t SZ_BTD = (size_t)BB * TT * DD;            // 4,194,304
    const size_t SZ_OH  = (size_t)BHH * NHASH * TT * DHH;  // 16,777,216

    char* p = (char*)d_ws;
    float* x1b = (float*)p;  p += SZ_BTD * 4;
    float* x2b = (float*)p;  p += SZ_BTD * 4;
    float* xnb = (float*)p;  p += SZ_BTD * 4;
    float* qkb = (float*)p;  p += SZ_BTD * 4;
    u16*   vbh = (u16*)p;    p += SZ_BTD * 2;
    u16*   xnbh = (u16*)p;   p += SZ_BTD * 2;
    u16*   qknb = (u16*)p;   p += (size_t)BHH * TT * DHH * 2;
    u16*   ohash = (u16*)p;                      // 33.5MB region
    u16*   ffmid = (u16*)p;                      // temporal alias (disjoint life)
    p += SZ_OH * 2;
    float* lseb  = (float*)p; p += (size_t)BHH * NHASH * TT * 4;
    int*   stb   = (int*)p;   p += (size_t)BHH * NHASH * TT * 4;
    u16* wvT = (u16*)p; p += (size_t)DD * DD * 2;
    u16* woT = (u16*)p; p += (size_t)DD * DD * 2;
    u16* w1T = (u16*)p; p += (size_t)DD * FFD * 2;
    u16* w2T = (u16*)p; p += (size_t)FFD * DD * 2;
    u16* amb = (u16*)qkb;                        // alias, used after attention

    embed_kernel<<<BB * TT, 256, 0, stream>>>(x, embw, embb, pos, x1b, x2b);

    for (int L = 0; L < NLAYER; ++L) {
        const size_t wOff  = (size_t)L * DD * DD;
        const size_t f1Off = (size_t)L * DD * FFD;
        const size_t f2Off = (size_t)L * FFD * DD;

        transpose_bf16<<<dim3(DD / 32, DD / 32), 256, 0, stream>>>(wv + wOff, wvT, DD, DD);
        transpose_bf16<<<dim3(DD / 32, DD / 32), 256, 0, stream>>>(wo + wOff, woT, DD, DD);
        transpose_bf16<<<dim3(DD / 32, FFD / 32), 256, 0, stream>>>(ffw1 + f1Off, w1T, DD, FFD);
        transpose_bf16<<<dim3(FFD / 32, DD / 32), 256, 0, stream>>>(ffw2 + f2Off, w2T, FFD, DD);

        // x1 += attn(ln(x2))
        ln_kernel<<<2048, 256, 0, stream>>>(x2b, ln1g + L * DD, ln1b + L * DD, xnb, xnbh);
        gemm_f32_qk<<<dim3(128, 8), 256, 0, stream>>>(xnb, wqk + wOff, qkb, BB * TT, DD, DD);
        gemm_bf16<64, 64, 64, false, false, false, true><<<dim3(128, 8), 256, 0, stream>>>(
            xnbh, wvT, nullptr, nullptr, nullptr, vbh, BB * TT, DD, DD);
        knorm_kernel<<<4096, 256, 0, stream>>>(qkb, qknb);
        bucket_sort_kernel<<<dim3(NHASH, BHH), 512, 0, stream>>>(
            qkb, rot + (size_t)L * DHH * NHASH, stb);
        lsh_attn_mfma<<<dim3(NCHUNK, BHH), 256, 0, stream>>>(
            qkb, qknb, vbh, stb, ohash, lseb);
        combine_kernel<<<16384, 256, 0, stream>>>(ohash, lseb, amb);
        gemm_bf16<64, 64, 64, false, true, true, false><<<dim3(128, 8), 256, 0, stream>>>(
            amb, woT, wob + L * DD, x1b, x1b, nullptr, BB * TT, DD, DD);

        // x2 += ff(ln(x1))
        ln_kernel<<<2048, 256, 0, stream>>>(x1b, ln2g + L * DD, ln2b + L * DD, xnb, xnbh);
        gemm_bf16<128, 128, 32, true, false, true, true><<<dim3(64, 16), 256, 0, stream>>>(
            xnbh, w1T, ffb1 + L * FFD, nullptr, nullptr, ffmid, BB * TT, FFD, DD);
        gemm_bf16<64, 64, 64, false, true, true, false><<<dim3(128, 8), 256, 0, stream>>>(
            ffmid, w2T, ffb2 + L * DD, x2b, x2b, nullptr, BB * TT, DD, FFD);
    }

    head_kernel<<<16, 256, 0, stream>>>(x1b, x2b, lnfg, lnfb, hw1, hb1,
                                        hlng, hlnb, hw2, hb2, out);
}

// Round 5
// 1264.438 us; speedup vs baseline: 5.8068x; 1.0602x over previous
//
#include <hip/hip_runtime.h>
#include <hip/hip_fp16.h>
#include <cfloat>
#include <cstdint>

// Problem constants
#define BB      16      // batch
#define TT      512     // seq
#define DD      512     // d_model
#define HH      8       // heads
#define DHH     64      // head dim
#define FFD     2048    // ff dim
#define BHH     128     // BB*HH
#define NHASH   4
#define NCHUNK  8       // NHASH * N_BUCKETS
#define CHUNKSZ 256
#define NLAYER  4

typedef unsigned short u16;
typedef unsigned int   u32;
typedef __attribute__((ext_vector_type(8))) short bfrag;    // 8 bf16 (4 VGPR)
typedef __attribute__((ext_vector_type(4))) float f4x;      // 4 f32 acc
typedef __attribute__((ext_vector_type(16))) float f16x;    // 16 f32 acc

union FragU { u32 u[4]; uint4 v4; bfrag f; };

__device__ __forceinline__ unsigned pk_bf16(float a, float b) {
    union { float f; unsigned u; } x, y;
    x.f = a; y.f = b;
    unsigned lo = ((x.u + 0x7FFFu + ((x.u >> 16) & 1u)) >> 16) & 0xFFFFu;
    unsigned hi = (y.u + 0x7FFFu + ((y.u >> 16) & 1u)) & 0xFFFF0000u;
    return lo | hi;
}
// HW packed f32->bf16 RTNE (1 VALU op; no builtin on gfx950)
__device__ __forceinline__ unsigned cvt_pk(float a, float b) {
    unsigned r;
    asm("v_cvt_pk_bf16_f32 %0, %1, %2" : "=v"(r) : "v"(a), "v"(b));
    return r;
}
// HW packed f32->f16 (RTZ) — o_hash precision (10-bit mantissa)
__device__ __forceinline__ unsigned pkrtz(float a, float b) {
    unsigned r;
    asm("v_cvt_pkrtz_f16_f32 %0, %1, %2" : "=v"(r) : "v"(a), "v"(b));
    return r;
}
__device__ __forceinline__ u16 bf16_1(float a) {
    union { float f; unsigned u; } x; x.f = a;
    return (u16)((x.u + 0x7FFFu + ((x.u >> 16) & 1u)) >> 16);
}
__device__ __forceinline__ float b2f(u16 h) {
    union { unsigned u; float f; } x; x.u = ((unsigned)h) << 16; return x.f;
}

// async global->LDS, 16B per lane (dest must be linear: base + lane*16)
__device__ __forceinline__ void gload16(const u16* g, u16* l) {
    __builtin_amdgcn_global_load_lds(
        (const __attribute__((address_space(1))) u32*)g,
        (__attribute__((address_space(3))) u32*)l, 16, 0, 0);
}

// ---------------------------------------------------------------------------
// Embedding: h = x @ emb_w + emb_b + pos ; write to both x1 and x2
__global__ __launch_bounds__(256)
void embed_kernel(const float* __restrict__ x, const float* __restrict__ ew,
                  const float* __restrict__ eb, const float* __restrict__ pos,
                  float* __restrict__ x1, float* __restrict__ x2)
{
    const int row = blockIdx.x;          // b*T + t
    const int t = row & (TT - 1);
    __shared__ float xr[32];
    if (threadIdx.x < 32) xr[threadIdx.x] = x[row * 32 + threadIdx.x];
    __syncthreads();
    for (int d = threadIdx.x; d < DD; d += 256) {
        float s = eb[d] + pos[t * DD + d];
        #pragma unroll
        for (int k = 0; k < 32; ++k) s = fmaf(xr[k], ew[k * DD + d], s);
        x1[(size_t)row * DD + d] = s;
        x2[(size_t)row * DD + d] = s;
    }
}

// ---------------------------------------------------------------------------
// LayerNorm over last dim (512); writes f32 AND bf16 outputs.
__global__ __launch_bounds__(256)
void ln_kernel(const float* __restrict__ in, const float* __restrict__ g,
               const float* __restrict__ bta, float* __restrict__ out,
               u16* __restrict__ outh)
{
    const int row = blockIdx.x * 4 + (threadIdx.x >> 6);
    const int lane = threadIdx.x & 63;
    const float* r = in + (size_t)row * DD;
    float vals[8];
    float s = 0.0f;
    #pragma unroll
    for (int i = 0; i < 8; ++i) { vals[i] = r[i * 64 + lane]; s += vals[i]; }
    #pragma unroll
    for (int o = 1; o < 64; o <<= 1) s += __shfl_xor(s, o);
    const float mean = s * (1.0f / 512.0f);
    float vs = 0.0f;
    #pragma unroll
    for (int i = 0; i < 8; ++i) { float d = vals[i] - mean; vs += d * d; }
    #pragma unroll
    for (int o = 1; o < 64; o <<= 1) vs += __shfl_xor(vs, o);
    const float rstd = rsqrtf(vs * (1.0f / 512.0f) + 1e-5f);
    float* orow = out + (size_t)row * DD;
    u16* hrow = outh + (size_t)row * DD;
    #pragma unroll
    for (int i = 0; i < 8; ++i) {
        const int d = i * 64 + lane;
        const float y = (vals[i] - mean) * rstd * g[d] + bta[d];
        orow[d] = y;
        hrow[d] = bf16_1(y);
    }
}

// ---------------------------------------------------------------------------
// Weight transpose+convert: in (K x N, f32) -> out (N x K, bf16)
__global__ __launch_bounds__(256)
void transpose_bf16(const float* __restrict__ in, u16* __restrict__ out,
                    int K, int N)
{
    __shared__ float tile[32][33];
    const int kt = blockIdx.x * 32, nt = blockIdx.y * 32;
    const int r = threadIdx.x >> 3, c4 = (threadIdx.x & 7) * 4;
    const float4 v4 = *(const float4*)(in + (size_t)(kt + r) * N + nt + c4);
    tile[r][c4 + 0] = v4.x; tile[r][c4 + 1] = v4.y;
    tile[r][c4 + 2] = v4.z; tile[r][c4 + 3] = v4.w;
    __syncthreads();
    uint2 p;
    p.x = pk_bf16(tile[c4 + 0][r], tile[c4 + 1][r]);
    p.y = pk_bf16(tile[c4 + 2][r], tile[c4 + 3][r]);
    *(uint2*)(out + (size_t)(nt + r) * K + kt + c4) = p;
}

// ---------------------------------------------------------------------------
// f32 GEMM for qk only (keeps LSH bucket decisions f32-exact).
__global__ __launch_bounds__(256)
void gemm_f32_qk(const float* __restrict__ A, const float* __restrict__ W,
                 float* __restrict__ C, int M, int N, int K)
{
    __shared__ float As[32][68];   // [k][m]
    __shared__ float Ws[32][68];   // [k][n]
    const int tid = threadIdx.x;
    const int m0 = blockIdx.x * 64, n0 = blockIdx.y * 64;
    const int tm = tid >> 4, tn = tid & 15;
    const int lam = tid >> 2, lak = (tid & 3) * 8;
    const int lwk = tid >> 3, lwn = (tid & 7) * 8;
    const float* Ap = A + (size_t)(m0 + lam) * K + lak;
    const float* Wp = W + (size_t)lwk * N + n0 + lwn;
    float4 a0 = ((const float4*)Ap)[0], a1 = ((const float4*)Ap)[1];
    float4 w0 = ((const float4*)Wp)[0], w1 = ((const float4*)Wp)[1];
    float c[4][4] = {};
    const int nT = K >> 5;
    for (int t = 0; t < nT; ++t) {
        __syncthreads();
        As[lak + 0][lam] = a0.x; As[lak + 1][lam] = a0.y;
        As[lak + 2][lam] = a0.z; As[lak + 3][lam] = a0.w;
        As[lak + 4][lam] = a1.x; As[lak + 5][lam] = a1.y;
        As[lak + 6][lam] = a1.z; As[lak + 7][lam] = a1.w;
        *(float4*)&Ws[lwk][lwn] = w0;
        *(float4*)&Ws[lwk][lwn + 4] = w1;
        __syncthreads();
        if (t + 1 < nT) {
            Ap += 32; Wp += (size_t)32 * N;
            a0 = ((const float4*)Ap)[0]; a1 = ((const float4*)Ap)[1];
            w0 = ((const float4*)Wp)[0]; w1 = ((const float4*)Wp)[1];
        }
        #pragma unroll
        for (int kk = 0; kk < 32; ++kk) {
            const float4 a = *(const float4*)&As[kk][tm * 4];
            const float4 w = *(const float4*)&Ws[kk][tn * 4];
            const float avr[4] = {a.x, a.y, a.z, a.w};
            const float wvr[4] = {w.x, w.y, w.z, w.w};
            #pragma unroll
            for (int i = 0; i < 4; ++i)
                #pragma unroll
                for (int j = 0; j < 4; ++j)
                    c[i][j] = fmaf(avr[i], wvr[j], c[i][j]);
        }
    }
    #pragma unroll
    for (int i = 0; i < 4; ++i) {
        const int row = m0 + tm * 4 + i;
        *(float4*)&C[(size_t)row * N + n0 + tn * 4] =
            make_float4(c[i][0], c[i][1], c[i][2], c[i][3]);
    }
}

// ---------------------------------------------------------------------------
// bf16 MFMA GEMM, templated tile, double-buffered LDS, 2-phase pipeline.
__device__ __forceinline__ float gelu1(float v) {
    return 0.5f * v * (1.0f + erff(v * 0.70710678118654752440f));
}
__device__ __forceinline__ int swz_row(int r, int BK) {
    return (BK == 32) ? ((r & 3) ^ ((r >> 2) & 3)) : (r & 7);
}

template<int BM, int BN, int BK, bool GELU, bool ADD, bool BIAS, bool OUTBF>
__global__ __launch_bounds__(256)
void gemm_bf16(const u16* __restrict__ A, const u16* __restrict__ WT,
               const float* __restrict__ bias, const float* __restrict__ addsrc,
               float* __restrict__ Cf, u16* __restrict__ Cb,
               int M, int N, int K)
{
    constexpr int NCH = BK / 8;
    constexpr int CPA = BM * NCH / 256;
    constexpr int CPB = BN * NCH / 256;
    constexpr int MR = BM / 32, NR = BN / 32, KR = BK / 32;
    __shared__ __align__(16) u16 Abuf[2][BM * BK];
    __shared__ __align__(16) u16 Bbuf[2][BN * BK];
    const int tid = threadIdx.x;
    const int m0 = blockIdx.x * BM, n0 = blockIdx.y * BN;

    const u16* aSrc[CPA]; const u16* bSrc[CPB];
    #pragma unroll
    for (int i = 0; i < CPA; ++i) {
        const int s = tid + i * 256, row = s / NCH, ch = s % NCH;
        aSrc[i] = A + (size_t)(m0 + row) * K + (ch ^ swz_row(row, BK)) * 8;
    }
    #pragma unroll
    for (int i = 0; i < CPB; ++i) {
        const int s = tid + i * 256, row = s / NCH, ch = s % NCH;
        bSrc[i] = WT + (size_t)(n0 + row) * K + (ch ^ swz_row(row, BK)) * 8;
    }

    auto STAGE = [&](int bufi, int koff) {
        #pragma unroll
        for (int i = 0; i < CPA; ++i)
            gload16(aSrc[i] + koff, &Abuf[bufi][(tid + i * 256) * 8]);
        #pragma unroll
        for (int i = 0; i < CPB; ++i)
            gload16(bSrc[i] + koff, &Bbuf[bufi][(tid + i * 256) * 8]);
    };

    const int l = tid & 63, wv_ = tid >> 6;
    const int wm = (wv_ >> 1) * (BM / 2);
    const int wn = (wv_ & 1) * (BN / 2);
    const int fr = l & 15, fc = l >> 4;

    f4x acc[MR][NR] = {};
    const int nK = K / BK;
    STAGE(0, 0);
    for (int ks = 0; ks < nK; ++ks) {
        __syncthreads();
        if (ks + 1 < nK) STAGE((ks + 1) & 1, (ks + 1) * BK);
        const u16* Ab = Abuf[ks & 1];
        const u16* Bb = Bbuf[ks & 1];
        FragU af[MR][KR], bf_[NR][KR];
        #pragma unroll
        for (int i = 0; i < MR; ++i)
            #pragma unroll
            for (int u = 0; u < KR; ++u) {
                const int r = wm + i * 16 + fr;
                af[i][u].v4 = *(const uint4*)((const char*)Ab +
                    (size_t)r * (2 * BK) + (((u * 4 + fc) ^ swz_row(r, BK)) << 4));
            }
        #pragma unroll
        for (int j = 0; j < NR; ++j)
            #pragma unroll
            for (int u = 0; u < KR; ++u) {
                const int r = wn + j * 16 + fr;
                bf_[j][u].v4 = *(const uint4*)((const char*)Bb +
                    (size_t)r * (2 * BK) + (((u * 4 + fc) ^ swz_row(r, BK)) << 4));
            }
        #pragma unroll
        for (int u = 0; u < KR; ++u)
            #pragma unroll
            for (int i = 0; i < MR; ++i)
                #pragma unroll
                for (int j = 0; j < NR; ++j)
                    acc[i][j] = __builtin_amdgcn_mfma_f32_16x16x32_bf16(
                        af[i][u].f, bf_[j][u].f, acc[i][j], 0, 0, 0);
    }

    #pragma unroll
    for (int i = 0; i < MR; ++i) {
        #pragma unroll
        for (int q = 0; q < 4; ++q) {
            const int row = m0 + wm + i * 16 + fc * 4 + q;
            #pragma unroll
            for (int j = 0; j < NR; ++j) {
                const int col = n0 + wn + j * 16 + fr;
                float vx = acc[i][j][q];
                if constexpr (BIAS) vx += bias[col];
                if constexpr (GELU) vx = gelu1(vx);
                if constexpr (ADD) vx += addsrc[(size_t)row * N + col];
                if constexpr (OUTBF) Cb[(size_t)row * N + col] = bf16_1(vx);
                else Cf[(size_t)row * N + col] = vx;
            }
        }
    }
}

// ---------------------------------------------------------------------------
// K/Q pre-normalization: qkn = bf16(row/|row|), qnrm = |row| (f32, exact)
__global__ __launch_bounds__(256)
void knorm_kernel(const float* __restrict__ qk, u16* __restrict__ qkn,
                  float* __restrict__ qnrm)
{
    const int g = blockIdx.x * 16 + (threadIdx.x >> 4);  // bh*T + t
    const int li = threadIdx.x & 15;
    const int bh = g >> 9, t = g & 511;
    const int b = bh >> 3, head = bh & 7;
    const float4 xv = reinterpret_cast<const float4*>(
        qk + ((size_t)(b * TT + t)) * DD + head * DHH)[li];
    float ss = xv.x * xv.x + xv.y * xv.y + xv.z * xv.z + xv.w * xv.w;
    ss += __shfl_xor(ss, 1); ss += __shfl_xor(ss, 2);
    ss += __shfl_xor(ss, 4); ss += __shfl_xor(ss, 8);
    const float qn = sqrtf(ss);
    const float rv = 1.0f / fmaxf(qn, 1e-12f);
    uint2 o;
    o.x = cvt_pk(xv.x * rv, xv.y * rv);
    o.y = cvt_pk(xv.z * rv, xv.w * rv);
    *(uint2*)(qkn + ((size_t)bh * TT + t) * DHH + li * 4) = o;
    if (li == 0) qnrm[(size_t)bh * TT + t] = qn;
}

// ---------------------------------------------------------------------------
// Bucket assignment + stable partition (f32 — must match numpy)
__global__ __launch_bounds__(512)
void bucket_sort_kernel(const float* __restrict__ qk, const float* __restrict__ rot,
                        int* __restrict__ st)
{
    const int h = blockIdx.x, bh = blockIdx.y;
    const int b = bh >> 3, head = bh & 7;
    const int t = threadIdx.x;
    __shared__ float rc[64];
    __shared__ int zcnt[8];
    if (t < 64) rc[t] = rot[t * NHASH + h];
    __syncthreads();
    const float4* row = reinterpret_cast<const float4*>(
        qk + ((size_t)(b * TT + t)) * DD + head * DHH);
    float r = 0.0f;
    #pragma unroll
    for (int u = 0; u < 16; ++u) {
        const float4 q4 = row[u];
        r += q4.x * rc[u * 4] + q4.y * rc[u * 4 + 1]
           + q4.z * rc[u * 4 + 2] + q4.w * rc[u * 4 + 3];
    }
    const int bit = (r < 0.0f) ? 1 : 0;
    const int wid = t >> 6, lane = t & 63;
    const unsigned long long zm = __ballot(bit == 0);
    if (lane == 0) zcnt[wid] = __popcll(zm);
    __syncthreads();
    int zoff = 0, Z = 0;
    #pragma unroll
    for (int w = 0; w < 8; ++w) { const int cn = zcnt[w]; if (w < wid) zoff += cn; Z += cn; }
    const int zpre = __popcll(zm & ((1ull << lane) - 1ull));
    const int dst = (bit == 0) ? (zoff + zpre)
                               : (Z + (wid * 64 - zoff) + (lane - zpre));
    st[((size_t)bh * NHASH + h) * TT + dst] = t;
}

// ---------------------------------------------------------------------------
// MFMA LSH attention. Q,K both from normalized bf16 qkn (scores rescaled by
// |q| afterwards); V bf16; O output f16. Coalesced gathers (4 lanes per row)
// + register prefetch of next tile (T14).
__global__ __launch_bounds__(256)
void lsh_attn_mfma(const u16* __restrict__ qkn, const u16* __restrict__ v,
                   const float* __restrict__ qnrm, const int* __restrict__ st,
                   __half* __restrict__ o_hash, float* __restrict__ lse_hash)
{
    const int cc = blockIdx.x, bh = blockIdx.y;
    const int b = bh >> 3, head = bh & 7;
    const int h = cc >> 1, c = cc & 1;
    const int pcc = (cc + 7) & 7;
    const int hp = pcc >> 1, cp = pcc & 1;
    const int tid = threadIdx.x;
    const int w = tid >> 6;
    const int lane = tid & 63;
    const int l31 = lane & 31;
    const int hi = lane >> 5;
    const int* stb = st + (size_t)bh * (NHASH * TT);
    const size_t vbase = ((size_t)b * TT) * DD + head * DHH;
    const u16* qknb = qkn + (size_t)bh * TT * DHH;

    __shared__ __align__(16) u16 Kbf[64 * 64];
    __shared__ __align__(16) u16 VTbf[64 * 64];
    __shared__ int ktl[64];
    __shared__ float lW[4][64];
    __shared__ int qtW[4][64];
    __shared__ float Ost[4][32 * 33];

    // ---- Q fragments (bf16 normalized) + per-query scale ----
    int q_t[2]; float aC[2], mnat[2];
    uint4 QF4[2][4];
    #pragma unroll
    for (int qt = 0; qt < 2; ++qt) {
        const int qtk = stb[h * TT + c * CHUNKSZ + w * 64 + qt * 32 + l31];
        q_t[qt] = qtk;
        const float qn = qnrm[(size_t)bh * TT + qtk];
        mnat[qt] = qn * 0.125f;
        aC[qt]   = qn * 0.1803368801111137f;   // |q| * 0.125 * log2(e)
        const u16* qrow = qknb + (size_t)qtk * DHH;
        #pragma unroll
        for (int ds = 0; ds < 4; ++ds)
            QF4[qt][ds] = *(const uint4*)(qrow + ds * 16 + hi * 8);
    }

    f16x acc[2][2] = {};
    float lacc[2] = {0.f, 0.f};
    const int k8 = tid >> 2;     // key slot 0..63 (16 rows per wave -> coalesced)
    const int q4 = tid & 3;      // 32B quarter of the 128B row

    // gather one tile's K/V into regs
    auto gather = [&](int t8, uint4& kv0, uint4& kv1, uint4& vv0, uint4& vv1,
                      int& ktc) {
        const int kj = t8 * 64 + k8;
        const int k_t = (kj < CHUNKSZ) ? stb[h * TT + c * CHUNKSZ + kj]
                                       : stb[hp * TT + cp * CHUNKSZ + (kj - CHUNKSZ)];
        ktc = k_t;
        const u16* krow = qknb + (size_t)k_t * DHH + q4 * 16;
        const u16* vrow = v + vbase + (size_t)k_t * DD + q4 * 16;
        kv0 = ((const uint4*)krow)[0]; kv1 = ((const uint4*)krow)[1];
        vv0 = ((const uint4*)vrow)[0]; vv1 = ((const uint4*)vrow)[1];
    };

    uint4 kv0, kv1, vv0, vv1; int ktc;
    gather(0, kv0, kv1, vv0, vv1, ktc);

    for (int kt8 = 0; kt8 < 8; ++kt8) {
        __syncthreads();   // previous tile fully consumed
        {   // K: row k8, d-range [q4*16, q4*16+16)
            const int rbase = k8 * 128 + q4 * 32;
            const int swz = (k8 & 7) << 4;
            *(uint4*)((char*)Kbf + ((rbase)      ^ swz)) = kv0;
            *(uint4*)((char*)Kbf + ((rbase + 16) ^ swz)) = kv1;
        }
        {   // V^T: d = q4*16 + i, col k8
            const unsigned vu[8] = {vv0.x, vv0.y, vv0.z, vv0.w,
                                    vv1.x, vv1.y, vv1.z, vv1.w};
            #pragma unroll
            for (int i = 0; i < 16; ++i) {
                const int d = q4 * 16 + i;
                const u16 hv = (u16)((i & 1) ? (vu[i >> 1] >> 16) : (vu[i >> 1] & 0xffff));
                *(u16*)((char*)VTbf + ((d * 128 + k8 * 2) ^ ((d & 7) << 4))) = hv;
            }
        }
        if (q4 == 0) ktl[k8] = ktc;
        __syncthreads();

        // prefetch next tile (wraps to 0 on last iter — harmless valid loads)
        const int t8n = (kt8 < 7) ? kt8 + 1 : 0;
        gather(t8n, kv0, kv1, vv0, vv1, ktc);

        #pragma unroll
        for (int kt = 0; kt < 2; ++kt) {
            int ktv[16];
            #pragma unroll
            for (int i = 0; i < 16; ++i)
                ktv[i] = ktl[kt * 32 + (i & 3) + 8 * (i >> 2) + 4 * hi];
            FragU KA[4];
            #pragma unroll
            for (int ds = 0; ds < 4; ++ds) {
                const int row = kt * 32 + l31;
                KA[ds].v4 = *(const uint4*)((const char*)Kbf +
                    ((row * 128 + ds * 32 + hi * 16) ^ ((row & 7) << 4)));
            }
            FragU VA[2][2];
            #pragma unroll
            for (int dt = 0; dt < 2; ++dt)
                #pragma unroll
                for (int u = 0; u < 2; ++u) {
                    const int row = dt * 32 + l31;
                    const int ks = kt * 2 + u;
                    VA[dt][u].v4 = *(const uint4*)((const char*)VTbf +
                        ((row * 128 + ks * 32 + hi * 16) ^ ((row & 7) << 4)));
                }
            #pragma unroll
            for (int qt = 0; qt < 2; ++qt) {
                f16x s = {0.f,0.f,0.f,0.f,0.f,0.f,0.f,0.f,
                          0.f,0.f,0.f,0.f,0.f,0.f,0.f,0.f};
                #pragma unroll
                for (int ds = 0; ds < 4; ++ds) {
                    FragU qf; qf.v4 = QF4[qt][ds];
                    s = __builtin_amdgcn_mfma_f32_32x32x16_bf16(KA[ds].f, qf.f, s, 0, 0, 0);
                }
                const float a = aC[qt];
                float pv[16];
                #pragma unroll
                for (int i = 0; i < 16; ++i) {
                    const float e = exp2f(fmaf(s[i], a, -a));   // exp(qn/8*(s-1))
                    const float p = (q_t[qt] > ktv[i]) ? e : 0.0f;
                    pv[i] = p;
                    lacc[qt] += p;
                }
                unsigned P2[8], S2[8];
                #pragma unroll
                for (int g = 0; g < 4; ++g) {
                    P2[2*g]   = cvt_pk(pv[4*g],   pv[4*g+1]);
                    P2[2*g+1] = cvt_pk(pv[4*g+2], pv[4*g+3]);
                }
                #pragma unroll
                for (int i = 0; i < 8; ++i)
                    S2[i] = (unsigned)__shfl_xor((int)P2[i], 32);
                #pragma unroll
                for (int u = 0; u < 2; ++u) {
                    FragU bfv;
                    bfv.u[0] = hi ? S2[2*(2*u+1)]     : P2[2*(2*u)];
                    bfv.u[1] = hi ? S2[2*(2*u+1) + 1] : P2[2*(2*u) + 1];
                    bfv.u[2] = hi ? P2[2*(2*u+1)]     : S2[2*(2*u)];
                    bfv.u[3] = hi ? P2[2*(2*u+1) + 1] : S2[2*(2*u) + 1];
                    #pragma unroll
                    for (int dt = 0; dt < 2; ++dt)
                        acc[dt][qt] = __builtin_amdgcn_mfma_f32_32x32x16_bf16(
                            VA[dt][u].f, bfv.f, acc[dt][qt], 0, 0, 0);
                }
            }
        }
    }

    float invl[2];
    #pragma unroll
    for (int qt = 0; qt < 2; ++qt) {
        const float lt = lacc[qt] + __shfl_xor(lacc[qt], 32);
        invl[qt] = (lt > 0.f) ? 1.0f / lt : 0.0f;
        const float lse = (lt > 0.f) ? (mnat[qt] + logf(lt)) : -5.0e4f;
        if (hi == 0) {
            lW[w][qt * 32 + l31] = lt;
            qtW[w][qt * 32 + l31] = q_t[qt];
            lse_hash[(size_t)(bh * NHASH + h) * TT + q_t[qt]] = lse;
        }
    }
    __syncthreads();

    float* ost = Ost[w];
    #pragma unroll
    for (int qt = 0; qt < 2; ++qt)
        #pragma unroll
        for (int dt = 0; dt < 2; ++dt) {
            #pragma unroll
            for (int r = 0; r < 16; ++r) {
                const int row = (r & 3) + 8 * (r >> 2) + 4 * hi;
                ost[row * 33 + l31] = acc[dt][qt][r] * invl[qt];
            }
            const int qq = lane >> 1, h2 = lane & 1;
            const int qglob = qtW[w][qt * 32 + qq];
            const float lq = lW[w][qt * 32 + qq];
            float ov[16];
            #pragma unroll
            for (int i = 0; i < 16; ++i)
                ov[i] = ost[(h2 * 16 + i) * 33 + qq];
            __half* orow = o_hash + ((size_t)(bh * NHASH + h) * TT + qglob) * DHH
                         + dt * 32 + h2 * 16;
            if (lq > 0.f) {
                uint4 o0;
                o0.x = pkrtz(ov[0],  ov[1]);  o0.y = pkrtz(ov[2],  ov[3]);
                o0.z = pkrtz(ov[4],  ov[5]);  o0.w = pkrtz(ov[6],  ov[7]);
                uint4 o1;
                o1.x = pkrtz(ov[8],  ov[9]);  o1.y = pkrtz(ov[10], ov[11]);
                o1.z = pkrtz(ov[12], ov[13]); o1.w = pkrtz(ov[14], ov[15]);
                ((uint4*)orow)[0] = o0;
                ((uint4*)orow)[1] = o1;
            } else {
                const u16* vr = v + vbase + (size_t)qglob * DD + dt * 32 + h2 * 16;
                uint4 o0, o1;
                o0.x = pkrtz(b2f(vr[0]),  b2f(vr[1]));
                o0.y = pkrtz(b2f(vr[2]),  b2f(vr[3]));
                o0.z = pkrtz(b2f(vr[4]),  b2f(vr[5]));
                o0.w = pkrtz(b2f(vr[6]),  b2f(vr[7]));
                o1.x = pkrtz(b2f(vr[8]),  b2f(vr[9]));
                o1.y = pkrtz(b2f(vr[10]), b2f(vr[11]));
                o1.z = pkrtz(b2f(vr[12]), b2f(vr[13]));
                o1.w = pkrtz(b2f(vr[14]), b2f(vr[15]));
                ((uint4*)orow)[0] = o0;
                ((uint4*)orow)[1] = o1;
            }
        }
}

// ---------------------------------------------------------------------------
// Combine hash rounds: read o_hash f16, write merged bf16 (wo GEMM A-operand)
__global__ __launch_bounds__(256)
void combine_kernel(const __half* __restrict__ o_hash, const float* __restrict__ lse_hash,
                    u16* __restrict__ am)
{
    const int idx = blockIdx.x * 4 + (threadIdx.x >> 6);
    const int lane = threadIdx.x & 63;
    const int bh = idx >> 9, t = idx & 511;
    const int b = bh >> 3, head = bh & 7;
    const float ls0 = lse_hash[(size_t)(bh * NHASH + 0) * TT + t];
    const float ls1 = lse_hash[(size_t)(bh * NHASH + 1) * TT + t];
    const float ls2 = lse_hash[(size_t)(bh * NHASH + 2) * TT + t];
    const float ls3 = lse_hash[(size_t)(bh * NHASH + 3) * TT + t];
    const float M = fmaxf(fmaxf(ls0, ls1), fmaxf(ls2, ls3));
    const float e0 = __expf(ls0 - M), e1 = __expf(ls1 - M);
    const float e2 = __expf(ls2 - M), e3 = __expf(ls3 - M);
    const float inv = 1.0f / (e0 + e1 + e2 + e3);
    const float o =
        (e0 * __half2float(o_hash[((size_t)((bh * NHASH + 0) * TT + t)) * DHH + lane]) +
         e1 * __half2float(o_hash[((size_t)((bh * NHASH + 1) * TT + t)) * DHH + lane]) +
         e2 * __half2float(o_hash[((size_t)((bh * NHASH + 2) * TT + t)) * DHH + lane]) +
         e3 * __half2float(o_hash[((size_t)((bh * NHASH + 3) * TT + t)) * DHH + lane])) * inv;
    am[((size_t)(b * TT + t)) * DD + head * DHH + lane] = bf16_1(o);
}

// ---------------------------------------------------------------------------
// Final head
__device__ __forceinline__ float block_sum256(float v, volatile float* red)
{
    const int lane = threadIdx.x & 63, wid = threadIdx.x >> 6;
    #pragma unroll
    for (int o = 1; o < 64; o <<= 1) v += __shfl_xor(v, o);
    __syncthreads();
    if (lane == 0) red[wid] = v;
    __syncthreads();
    return red[0] + red[1] + red[2] + red[3];
}

__global__ __launch_bounds__(256)
void head_kernel(const float* __restrict__ x1, const float* __restrict__ x2,
                 const float* __restrict__ lnfg, const float* __restrict__ lnfb,
                 const float* __restrict__ hw1, const float* __restrict__ hb1,
                 const float* __restrict__ hlng, const float* __restrict__ hlnb,
                 const float* __restrict__ hw2, const float* __restrict__ hb2,
                 float* __restrict__ out)
{
    __shared__ float nrow[512];
    __shared__ float red[4];
    const int b = blockIdx.x, tid = threadIdx.x;
    const size_t roff = ((size_t)b * TT + (TT - 1)) * DD;
    const float v0 = 0.5f * (x1[roff + tid] + x2[roff + tid]);
    const float v1 = 0.5f * (x1[roff + 256 + tid] + x2[roff + 256 + tid]);
    const float mean = block_sum256(v0 + v1, red) * (1.0f / 512.0f);
    const float d0 = v0 - mean, d1 = v1 - mean;
    const float var = block_sum256(d0 * d0 + d1 * d1, red) * (1.0f / 512.0f);
    const float rstd = rsqrtf(var + 1e-5f);
    nrow[tid]       = d0 * rstd * lnfg[tid] + lnfb[tid];
    nrow[tid + 256] = d1 * rstd * lnfg[tid + 256] + lnfb[tid + 256];
    __syncthreads();
    float a = hb1[tid];
    for (int k = 0; k < 512; ++k) a = fmaf(nrow[k], hw1[(size_t)k * 256 + tid], a);
    const float m2 = block_sum256(a, red) * (1.0f / 256.0f);
    const float dd = a - m2;
    const float var2 = block_sum256(dd * dd, red) * (1.0f / 256.0f);
    float y = dd * rsqrtf(var2 + 1e-5f) * hlng[tid] + hlnb[tid];
    y = fmaxf(y, 0.0f);
    const float osum = block_sum256(y * hw2[tid], red);
    if (tid == 0) out[b] = osum + hb2[0];
}

// ---------------------------------------------------------------------------
extern "C" void kernel_launch(void* const* d_in, const int* in_sizes, int n_in,
                              void* d_out, int out_size, void* d_ws, size_t ws_size,
                              hipStream_t stream)
{
    (void)in_sizes; (void)n_in; (void)out_size; (void)ws_size;
    const float* x    = (const float*)d_in[0];
    const float* embw = (const float*)d_in[1];
    const float* embb = (const float*)d_in[2];
    const float* pos  = (const float*)d_in[3];
    const float* ln1g = (const float*)d_in[4];
    const float* ln1b = (const float*)d_in[5];
    const float* wqk  = (const float*)d_in[6];
    const float* wv   = (const float*)d_in[7];
    const float* wo   = (const float*)d_in[8];
    const float* wob  = (const float*)d_in[9];
    const float* ln2g = (const float*)d_in[10];
    const float* ln2b = (const float*)d_in[11];
    const float* ffw1 = (const float*)d_in[12];
    const float* ffb1 = (const float*)d_in[13];
    const float* ffw2 = (const float*)d_in[14];
    const float* ffb2 = (const float*)d_in[15];
    const float* rot  = (const float*)d_in[16];
    const float* lnfg = (const float*)d_in[17];
    const float* lnfb = (const float*)d_in[18];
    const float* hw1  = (const float*)d_in[19];
    const float* hb1  = (const float*)d_in[20];
    const float* hlng = (const float*)d_in[21];
    const float* hlnb = (const float*)d_in[22];
    const float* hw2  = (const float*)d_in[23];
    const float* hb2  = (const float*)d_in[24];
    float* out = (float*)d_out;

    const size_t SZ_BTD = (size_t)BB * TT * DD;            // 4,194,304
    const size_t SZ_OH  = (size_t)BHH * NHASH * TT * DHH;  // 16,777,216

    char* p = (char*)d_ws;
    float* x1b = (float*)p;  p += SZ_BTD * 4;
    float* x2b = (float*)p;  p += SZ_BTD * 4;
    float* xnb = (float*)p;  p += SZ_BTD * 4;
    float* qkb = (float*)p;  p += SZ_BTD * 4;
    u16*   vbh = (u16*)p;    p += SZ_BTD * 2;
    u16*   xnbh = (u16*)p;   p += SZ_BTD * 2;
    u16*   qknb = (u16*)p;   p += (size_t)BHH * TT * DHH * 2;
    float* qnrm = (float*)p; p += (size_t)BHH * TT * 4;
    __half* ohash = (__half*)p;                  // 33.5MB region
    u16*    ffmid = (u16*)p;                     // temporal alias (disjoint life)
    p += SZ_OH * 2;
    float* lseb  = (float*)p; p += (size_t)BHH * NHASH * TT * 4;
    int*   stb   = (int*)p;   p += (size_t)BHH * NHASH * TT * 4;
    u16* wvT = (u16*)p; p += (size_t)DD * DD * 2;
    u16* woT = (u16*)p; p += (size_t)DD * DD * 2;
    u16* w1T = (u16*)p; p += (size_t)DD * FFD * 2;
    u16* w2T = (u16*)p; p += (size_t)FFD * DD * 2;
    u16* amb = (u16*)qkb;                        // alias, used after attention

    embed_kernel<<<BB * TT, 256, 0, stream>>>(x, embw, embb, pos, x1b, x2b);

    for (int L = 0; L < NLAYER; ++L) {
        const size_t wOff  = (size_t)L * DD * DD;
        const size_t f1Off = (size_t)L * DD * FFD;
        const size_t f2Off = (size_t)L * FFD * DD;

        transpose_bf16<<<dim3(DD / 32, DD / 32), 256, 0, stream>>>(wv + wOff, wvT, DD, DD);
        transpose_bf16<<<dim3(DD / 32, DD / 32), 256, 0, stream>>>(wo + wOff, woT, DD, DD);
        transpose_bf16<<<dim3(DD / 32, FFD / 32), 256, 0, stream>>>(ffw1 + f1Off, w1T, DD, FFD);
        transpose_bf16<<<dim3(FFD / 32, DD / 32), 256, 0, stream>>>(ffw2 + f2Off, w2T, FFD, DD);

        // x1 += attn(ln(x2))
        ln_kernel<<<2048, 256, 0, stream>>>(x2b, ln1g + L * DD, ln1b + L * DD, xnb, xnbh);
        gemm_f32_qk<<<dim3(128, 8), 256, 0, stream>>>(xnb, wqk + wOff, qkb, BB * TT, DD, DD);
        gemm_bf16<64, 64, 64, false, false, false, true><<<dim3(128, 8), 256, 0, stream>>>(
            xnbh, wvT, nullptr, nullptr, nullptr, vbh, BB * TT, DD, DD);
        knorm_kernel<<<4096, 256, 0, stream>>>(qkb, qknb, qnrm);
        bucket_sort_kernel<<<dim3(NHASH, BHH), 512, 0, stream>>>(
            qkb, rot + (size_t)L * DHH * NHASH, stb);
        lsh_attn_mfma<<<dim3(NCHUNK, BHH), 256, 0, stream>>>(
            qknb, vbh, qnrm, stb, ohash, lseb);
        combine_kernel<<<16384, 256, 0, stream>>>(ohash, lseb, amb);
        gemm_bf16<64, 64, 64, false, true, true, false><<<dim3(128, 8), 256, 0, stream>>>(
            amb, woT, wob + L * DD, x1b, x1b, nullptr, BB * TT, DD, DD);

        // x2 += ff(ln(x1))
        ln_kernel<<<2048, 256, 0, stream>>>(x1b, ln2g + L * DD, ln2b + L * DD, xnb, xnbh);
        gemm_bf16<128, 128, 32, true, false, true, true><<<dim3(64, 16), 256, 0, stream>>>(
            xnbh, w1T, ffb1 + L * FFD, nullptr, nullptr, ffmid, BB * TT, FFD, DD);
        gemm_bf16<64, 64, 64, false, true, true, false><<<dim3(128, 8), 256, 0, stream>>>(
            ffmid, w2T, ffb2 + L * DD, x2b, x2b, nullptr, BB * TT, DD, FFD);
    }

    head_kernel<<<16, 256, 0, stream>>>(x1b, x2b, lnfg, lnfb, hw1, hb1,
                                        hlng, hlnb, hw2, hb2, out);
}

// Round 6
// 1032.141 us; speedup vs baseline: 7.1137x; 1.2251x over previous
//
#include <hip/hip_runtime.h>
#include <hip/hip_fp16.h>
#include <cfloat>
#include <cstdint>

// Problem constants
#define BB      16      // batch
#define TT      512     // seq
#define DD      512     // d_model
#define HH      8       // heads
#define DHH     64      // head dim
#define FFD     2048    // ff dim
#define BHH     128     // BB*HH
#define NHASH   4
#define NCHUNK  8       // NHASH * N_BUCKETS
#define CHUNKSZ 256
#define NLAYER  4

typedef unsigned short u16;
typedef unsigned int   u32;
typedef __attribute__((ext_vector_type(8))) short bfrag;    // 8 bf16 (4 VGPR)
typedef __attribute__((ext_vector_type(4))) float f4x;      // 4 f32 acc
typedef __attribute__((ext_vector_type(16))) float f16x;    // 16 f32 acc

union FragU { u32 u[4]; uint4 v4; bfrag f; };

__device__ __forceinline__ unsigned pk_bf16(float a, float b) {
    union { float f; unsigned u; } x, y;
    x.f = a; y.f = b;
    unsigned lo = ((x.u + 0x7FFFu + ((x.u >> 16) & 1u)) >> 16) & 0xFFFFu;
    unsigned hi = (y.u + 0x7FFFu + ((y.u >> 16) & 1u)) & 0xFFFF0000u;
    return lo | hi;
}
// HW packed f32->bf16 RTNE (1 VALU op; no builtin on gfx950)
__device__ __forceinline__ unsigned cvt_pk(float a, float b) {
    unsigned r;
    asm("v_cvt_pk_bf16_f32 %0, %1, %2" : "=v"(r) : "v"(a), "v"(b));
    return r;
}
// HW packed f32->f16 (RTZ) — o_hash precision (10-bit mantissa)
__device__ __forceinline__ unsigned pkrtz(float a, float b) {
    unsigned r;
    asm("v_cvt_pkrtz_f16_f32 %0, %1, %2" : "=v"(r) : "v"(a), "v"(b));
    return r;
}
__device__ __forceinline__ u16 bf16_1(float a) {
    union { float f; unsigned u; } x; x.f = a;
    return (u16)((x.u + 0x7FFFu + ((x.u >> 16) & 1u)) >> 16);
}
__device__ __forceinline__ float b2f(u16 h) {
    union { unsigned u; float f; } x; x.u = ((unsigned)h) << 16; return x.f;
}

// async global->LDS, 16B per lane (dest must be linear: base + lane*16)
__device__ __forceinline__ void gload16(const u16* g, u16* l) {
    __builtin_amdgcn_global_load_lds(
        (const __attribute__((address_space(1))) u32*)g,
        (__attribute__((address_space(3))) u32*)l, 16, 0, 0);
}

// ---------------------------------------------------------------------------
// Embedding: h = x @ emb_w + emb_b + pos ; write to both x1 and x2
__global__ __launch_bounds__(256)
void embed_kernel(const float* __restrict__ x, const float* __restrict__ ew,
                  const float* __restrict__ eb, const float* __restrict__ pos,
                  float* __restrict__ x1, float* __restrict__ x2)
{
    const int row = blockIdx.x;          // b*T + t
    const int t = row & (TT - 1);
    __shared__ float xr[32];
    if (threadIdx.x < 32) xr[threadIdx.x] = x[row * 32 + threadIdx.x];
    __syncthreads();
    for (int d = threadIdx.x; d < DD; d += 256) {
        float s = eb[d] + pos[t * DD + d];
        #pragma unroll
        for (int k = 0; k < 32; ++k) s = fmaf(xr[k], ew[k * DD + d], s);
        x1[(size_t)row * DD + d] = s;
        x2[(size_t)row * DD + d] = s;
    }
}

// ---------------------------------------------------------------------------
// LayerNorm over last dim (512); writes f32 AND bf16 outputs.
__global__ __launch_bounds__(256)
void ln_kernel(const float* __restrict__ in, const float* __restrict__ g,
               const float* __restrict__ bta, float* __restrict__ out,
               u16* __restrict__ outh)
{
    const int row = blockIdx.x * 4 + (threadIdx.x >> 6);
    const int lane = threadIdx.x & 63;
    const float* r = in + (size_t)row * DD;
    float vals[8];
    float s = 0.0f;
    #pragma unroll
    for (int i = 0; i < 8; ++i) { vals[i] = r[i * 64 + lane]; s += vals[i]; }
    #pragma unroll
    for (int o = 1; o < 64; o <<= 1) s += __shfl_xor(s, o);
    const float mean = s * (1.0f / 512.0f);
    float vs = 0.0f;
    #pragma unroll
    for (int i = 0; i < 8; ++i) { float d = vals[i] - mean; vs += d * d; }
    #pragma unroll
    for (int o = 1; o < 64; o <<= 1) vs += __shfl_xor(vs, o);
    const float rstd = rsqrtf(vs * (1.0f / 512.0f) + 1e-5f);
    float* orow = out + (size_t)row * DD;
    u16* hrow = outh + (size_t)row * DD;
    #pragma unroll
    for (int i = 0; i < 8; ++i) {
        const int d = i * 64 + lane;
        const float y = (vals[i] - mean) * rstd * g[d] + bta[d];
        orow[d] = y;
        hrow[d] = bf16_1(y);
    }
}

// ---------------------------------------------------------------------------
// Batched weight prep: transpose+bf16 ALL layers' wqk/wv/wo/ff1/ff2 in ONE
// dispatch. Input (KxN f32) -> output (NxK bf16). 11264 tiles of 32x32.
__global__ __launch_bounds__(256)
void prep_weights(const float* __restrict__ wqk, const float* __restrict__ wv,
                  const float* __restrict__ wo, const float* __restrict__ ffw1,
                  const float* __restrict__ ffw2,
                  u16* __restrict__ wqkT, u16* __restrict__ wvT,
                  u16* __restrict__ woT, u16* __restrict__ w1T,
                  u16* __restrict__ w2T)
{
    const int id = blockIdx.x;
    const float* in; u16* outp; int K, N, kt, nt;
    if (id < 3072) {                       // wqk / wv / wo : 512x512, 256 tiles/L
        const int fam = id >> 10;
        const int r = id & 1023;
        const int L = r >> 8, t = r & 255;
        K = 512; N = 512;
        const size_t off = (size_t)L * 512 * 512;
        in   = (fam == 0 ? wqk  : fam == 1 ? wv  : wo ) + off;
        outp = (fam == 0 ? wqkT : fam == 1 ? wvT : woT) + off;
        kt = (t & 15) << 5; nt = (t >> 4) << 5;
    } else if (id < 7168) {                // ff1: 512x2048, 1024 tiles/L
        const int r = id - 3072;
        const int L = r >> 10, t = r & 1023;
        K = 512; N = 2048;
        in = ffw1 + (size_t)L * 512 * 2048;
        outp = w1T + (size_t)L * 2048 * 512;
        kt = (t & 15) << 5; nt = (t >> 4) << 5;
    } else {                               // ff2: 2048x512, 1024 tiles/L
        const int r = id - 7168;
        const int L = r >> 10, t = r & 1023;
        K = 2048; N = 512;
        in = ffw2 + (size_t)L * 2048 * 512;
        outp = w2T + (size_t)L * 512 * 2048;
        kt = (t & 63) << 5; nt = (t >> 6) << 5;
    }
    __shared__ float tile[32][33];
    const int rr = threadIdx.x >> 3, c4 = (threadIdx.x & 7) * 4;
    const float4 v4 = *(const float4*)(in + (size_t)(kt + rr) * N + nt + c4);
    tile[rr][c4 + 0] = v4.x; tile[rr][c4 + 1] = v4.y;
    tile[rr][c4 + 2] = v4.z; tile[rr][c4 + 3] = v4.w;
    __syncthreads();
    uint2 p;
    p.x = pk_bf16(tile[c4 + 0][rr], tile[c4 + 1][rr]);
    p.y = pk_bf16(tile[c4 + 2][rr], tile[c4 + 3][rr]);
    *(uint2*)(outp + (size_t)(nt + rr) * K + kt + c4) = p;
}

// ---------------------------------------------------------------------------
// wrot[L][f][h*4+hash] = sum_d wqk[L][f][h*64+d] * rot[L][d][hash]
// (factorized bucket rotation: rotated = xn @ wrot, f32-exact association)
__global__ __launch_bounds__(256)
void wrot_kernel(const float* __restrict__ wqk, const float* __restrict__ rot,
                 float* __restrict__ wrotAll)
{
    const int hh = blockIdx.x, L = blockIdx.y;
    const int head = hh >> 2, h = hh & 3;
    __shared__ float rc[64];
    if (threadIdx.x < 64)
        rc[threadIdx.x] = rot[((size_t)L * 64 + threadIdx.x) * 4 + h];
    __syncthreads();
    for (int f = threadIdx.x; f < 512; f += 256) {
        const float* wrow = wqk + (size_t)L * 512 * 512 + (size_t)f * 512 + head * 64;
        float s = 0.0f;
        #pragma unroll
        for (int d = 0; d < 64; d += 4) {
            const float4 w4 = *(const float4*)(wrow + d);
            s += w4.x * rc[d] + w4.y * rc[d + 1] + w4.z * rc[d + 2] + w4.w * rc[d + 3];
        }
        wrotAll[((size_t)L * 512 + f) * 32 + hh] = s;
    }
}

// ---------------------------------------------------------------------------
// rotated[8192][32] = xn[8192][512] @ wrot[512][32], all f32. grid 128.
__global__ __launch_bounds__(256)
void rot_gemm(const float* __restrict__ A, const float* __restrict__ Wr,
              float* __restrict__ C)
{
    __shared__ float As[64][36];
    __shared__ float Ws[32][36];
    const int m0 = blockIdx.x * 64;
    const int r = threadIdx.x >> 2, cg = threadIdx.x & 3;
    float acc[8] = {};
    for (int f0 = 0; f0 < 512; f0 += 32) {
        __syncthreads();
        {
            const int lr = threadIdx.x >> 2, lc = (threadIdx.x & 3) * 8;
            const float* ap = A + (size_t)(m0 + lr) * 512 + f0 + lc;
            *(float4*)&As[lr][lc]     = ((const float4*)ap)[0];
            *(float4*)&As[lr][lc + 4] = ((const float4*)ap)[1];
            const int wr = threadIdx.x >> 3, wc = (threadIdx.x & 7) * 4;
            *(float4*)&Ws[wr][wc] = *(const float4*)(Wr + (size_t)(f0 + wr) * 32 + wc);
        }
        __syncthreads();
        #pragma unroll
        for (int kk = 0; kk < 32; ++kk) {
            const float a = As[r][kk];
            #pragma unroll
            for (int c = 0; c < 8; ++c)
                acc[c] = fmaf(a, Ws[kk][cg * 8 + c], acc[c]);
        }
    }
    float* crow = C + (size_t)(m0 + r) * 32 + cg * 8;
    *(float4*)crow       = make_float4(acc[0], acc[1], acc[2], acc[3]);
    *(float4*)(crow + 4) = make_float4(acc[4], acc[5], acc[6], acc[7]);
}

// ---------------------------------------------------------------------------
// bf16 MFMA GEMM, templated tile, double-buffered LDS, 2-phase pipeline.
// QKL: write output in per-head layout qkh[(b*8+h)][t][d] (bf16).
__device__ __forceinline__ float gelu1(float v) {
    return 0.5f * v * (1.0f + erff(v * 0.70710678118654752440f));
}
__device__ __forceinline__ int swz_row(int r, int BK) {
    return (BK == 32) ? ((r & 3) ^ ((r >> 2) & 3)) : (r & 7);
}

template<int BM, int BN, int BK, bool GELU, bool ADD, bool BIAS, bool OUTBF, bool QKL>
__global__ __launch_bounds__(256)
void gemm_bf16(const u16* __restrict__ A, const u16* __restrict__ WT,
               const float* __restrict__ bias, const float* __restrict__ addsrc,
               float* __restrict__ Cf, u16* __restrict__ Cb,
               int M, int N, int K)
{
    constexpr int NCH = BK / 8;
    constexpr int CPA = BM * NCH / 256;
    constexpr int CPB = BN * NCH / 256;
    constexpr int MR = BM / 32, NR = BN / 32, KR = BK / 32;
    __shared__ __align__(16) u16 Abuf[2][BM * BK];
    __shared__ __align__(16) u16 Bbuf[2][BN * BK];
    const int tid = threadIdx.x;
    const int m0 = blockIdx.x * BM, n0 = blockIdx.y * BN;

    const u16* aSrc[CPA]; const u16* bSrc[CPB];
    #pragma unroll
    for (int i = 0; i < CPA; ++i) {
        const int s = tid + i * 256, row = s / NCH, ch = s % NCH;
        aSrc[i] = A + (size_t)(m0 + row) * K + (ch ^ swz_row(row, BK)) * 8;
    }
    #pragma unroll
    for (int i = 0; i < CPB; ++i) {
        const int s = tid + i * 256, row = s / NCH, ch = s % NCH;
        bSrc[i] = WT + (size_t)(n0 + row) * K + (ch ^ swz_row(row, BK)) * 8;
    }

    auto STAGE = [&](int bufi, int koff) {
        #pragma unroll
        for (int i = 0; i < CPA; ++i)
            gload16(aSrc[i] + koff, &Abuf[bufi][(tid + i * 256) * 8]);
        #pragma unroll
        for (int i = 0; i < CPB; ++i)
            gload16(bSrc[i] + koff, &Bbuf[bufi][(tid + i * 256) * 8]);
    };

    const int l = tid & 63, wv_ = tid >> 6;
    const int wm = (wv_ >> 1) * (BM / 2);
    const int wn = (wv_ & 1) * (BN / 2);
    const int fr = l & 15, fc = l >> 4;

    f4x acc[MR][NR] = {};
    const int nK = K / BK;
    STAGE(0, 0);
    for (int ks = 0; ks < nK; ++ks) {
        __syncthreads();
        if (ks + 1 < nK) STAGE((ks + 1) & 1, (ks + 1) * BK);
        const u16* Ab = Abuf[ks & 1];
        const u16* Bb = Bbuf[ks & 1];
        FragU af[MR][KR], bf_[NR][KR];
        #pragma unroll
        for (int i = 0; i < MR; ++i)
            #pragma unroll
            for (int u = 0; u < KR; ++u) {
                const int r = wm + i * 16 + fr;
                af[i][u].v4 = *(const uint4*)((const char*)Ab +
                    (size_t)r * (2 * BK) + (((u * 4 + fc) ^ swz_row(r, BK)) << 4));
            }
        #pragma unroll
        for (int j = 0; j < NR; ++j)
            #pragma unroll
            for (int u = 0; u < KR; ++u) {
                const int r = wn + j * 16 + fr;
                bf_[j][u].v4 = *(const uint4*)((const char*)Bb +
                    (size_t)r * (2 * BK) + (((u * 4 + fc) ^ swz_row(r, BK)) << 4));
            }
        #pragma unroll
        for (int u = 0; u < KR; ++u)
            #pragma unroll
            for (int i = 0; i < MR; ++i)
                #pragma unroll
                for (int j = 0; j < NR; ++j)
                    acc[i][j] = __builtin_amdgcn_mfma_f32_16x16x32_bf16(
                        af[i][u].f, bf_[j][u].f, acc[i][j], 0, 0, 0);
    }

    #pragma unroll
    for (int i = 0; i < MR; ++i) {
        #pragma unroll
        for (int q = 0; q < 4; ++q) {
            const int row = m0 + wm + i * 16 + fc * 4 + q;
            #pragma unroll
            for (int j = 0; j < NR; ++j) {
                const int col = n0 + wn + j * 16 + fr;
                float vx = acc[i][j][q];
                if constexpr (BIAS) vx += bias[col];
                if constexpr (GELU) vx = gelu1(vx);
                if constexpr (ADD) vx += addsrc[(size_t)row * N + col];
                if constexpr (QKL) {
                    // per-head layout: [(b*8+h)][t][d]
                    const int bq = row >> 9, tq = row & 511;
                    const int hq = col >> 6, dq = col & 63;
                    Cb[(((size_t)(bq * 8 + hq) * 512) + tq) * 64 + dq] = bf16_1(vx);
                } else if constexpr (OUTBF) {
                    Cb[(size_t)row * N + col] = bf16_1(vx);
                } else {
                    Cf[(size_t)row * N + col] = vx;
                }
            }
        }
    }
}

// ---------------------------------------------------------------------------
// K/Q pre-normalization from bf16 qkh: qkn = bf16(row/|row|), qnrm = |row|
__global__ __launch_bounds__(256)
void knorm_kernel(const u16* __restrict__ qkh, u16* __restrict__ qkn,
                  float* __restrict__ qnrm)
{
    const int g = blockIdx.x * 16 + (threadIdx.x >> 4);  // bh*T + t
    const int li = threadIdx.x & 15;
    const uint2 raw = *(const uint2*)(qkh + (size_t)g * 64 + li * 4);
    const float v0 = b2f((u16)(raw.x & 0xffff)), v1 = b2f((u16)(raw.x >> 16));
    const float v2 = b2f((u16)(raw.y & 0xffff)), v3 = b2f((u16)(raw.y >> 16));
    float ss = v0 * v0 + v1 * v1 + v2 * v2 + v3 * v3;
    ss += __shfl_xor(ss, 1); ss += __shfl_xor(ss, 2);
    ss += __shfl_xor(ss, 4); ss += __shfl_xor(ss, 8);
    const float qn = sqrtf(ss);
    const float rv = 1.0f / fmaxf(qn, 1e-12f);
    uint2 o;
    o.x = cvt_pk(v0 * rv, v1 * rv);
    o.y = cvt_pk(v2 * rv, v3 * rv);
    *(uint2*)(qkn + (size_t)g * 64 + li * 4) = o;
    if (li == 0) qnrm[g] = qn;
}

// ---------------------------------------------------------------------------
// Bucket assignment + stable partition from precomputed rotated (f32)
__global__ __launch_bounds__(512)
void bucket_sort_kernel(const float* __restrict__ rotated, int* __restrict__ st)
{
    const int h = blockIdx.x, bh = blockIdx.y;
    const int b = bh >> 3, head = bh & 7;
    const int t = threadIdx.x;
    __shared__ int zcnt[8];
    const float r = rotated[((size_t)(b * TT + t)) * 32 + head * 4 + h];
    const int bit = (r < 0.0f) ? 1 : 0;
    const int wid = t >> 6, lane = t & 63;
    const unsigned long long zm = __ballot(bit == 0);
    if (lane == 0) zcnt[wid] = __popcll(zm);
    __syncthreads();
    int zoff = 0, Z = 0;
    #pragma unroll
    for (int w = 0; w < 8; ++w) { const int cn = zcnt[w]; if (w < wid) zoff += cn; Z += cn; }
    const int zpre = __popcll(zm & ((1ull << lane) - 1ull));
    const int dst = (bit == 0) ? (zoff + zpre)
                               : (Z + (wid * 64 - zoff) + (lane - zpre));
    st[((size_t)bh * NHASH + h) * TT + dst] = t;
}

// ---------------------------------------------------------------------------
// MFMA LSH attention. Q,K from normalized bf16 qkn; V bf16; O out f16.
// Coalesced gathers, register prefetch, b128 ktv loads, permlane32 P-exchange.
__global__ __launch_bounds__(256)
void lsh_attn_mfma(const u16* __restrict__ qkn, const u16* __restrict__ v,
                   const float* __restrict__ qnrm, const int* __restrict__ st,
                   __half* __restrict__ o_hash, float* __restrict__ lse_hash)
{
    const int cc = blockIdx.x, bh = blockIdx.y;
    const int b = bh >> 3, head = bh & 7;
    const int h = cc >> 1, c = cc & 1;
    const int pcc = (cc + 7) & 7;
    const int hp = pcc >> 1, cp = pcc & 1;
    const int tid = threadIdx.x;
    const int w = tid >> 6;
    const int lane = tid & 63;
    const int l31 = lane & 31;
    const int hi = lane >> 5;
    const int* stb = st + (size_t)bh * (NHASH * TT);
    const size_t vbase = ((size_t)b * TT) * DD + head * DHH;
    const u16* qknb = qkn + (size_t)bh * TT * DHH;

    __shared__ __align__(16) u16 Kbf[64 * 64];
    __shared__ __align__(16) u16 VTbf[64 * 64];
    __shared__ __align__(16) int ktl[64];
    __shared__ float lW[4][64];
    __shared__ int qtW[4][64];
    __shared__ float Ost[4][32 * 33];

    // ---- Q fragments (bf16 normalized) + per-query scale ----
    int q_t[2]; float aC[2], mnat[2];
    uint4 QF4[2][4];
    #pragma unroll
    for (int qt = 0; qt < 2; ++qt) {
        const int qtk = stb[h * TT + c * CHUNKSZ + w * 64 + qt * 32 + l31];
        q_t[qt] = qtk;
        const float qn = qnrm[(size_t)bh * TT + qtk];
        mnat[qt] = qn * 0.125f;
        aC[qt]   = qn * 0.1803368801111137f;   // |q| * 0.125 * log2(e)
        const u16* qrow = qknb + (size_t)qtk * DHH;
        #pragma unroll
        for (int ds = 0; ds < 4; ++ds)
            QF4[qt][ds] = *(const uint4*)(qrow + ds * 16 + hi * 8);
    }

    f16x acc[2][2] = {};
    float lacc[2] = {0.f, 0.f};
    const int k8 = tid >> 2;     // key slot 0..63 (coalesced gathers)
    const int q4 = tid & 3;      // 32B quarter of the 128B row

    auto gather = [&](int t8, uint4& kv0, uint4& kv1, uint4& vv0, uint4& vv1,
                      int& ktc) {
        const int kj = t8 * 64 + k8;
        const int k_t = (kj < CHUNKSZ) ? stb[h * TT + c * CHUNKSZ + kj]
                                       : stb[hp * TT + cp * CHUNKSZ + (kj - CHUNKSZ)];
        ktc = k_t;
        const u16* krow = qknb + (size_t)k_t * DHH + q4 * 16;
        const u16* vrow = v + vbase + (size_t)k_t * DD + q4 * 16;
        kv0 = ((const uint4*)krow)[0]; kv1 = ((const uint4*)krow)[1];
        vv0 = ((const uint4*)vrow)[0]; vv1 = ((const uint4*)vrow)[1];
    };

    uint4 kv0, kv1, vv0, vv1; int ktc;
    gather(0, kv0, kv1, vv0, vv1, ktc);

    for (int kt8 = 0; kt8 < 8; ++kt8) {
        __syncthreads();   // previous tile fully consumed
        {   // K: row k8, d-range [q4*16, q4*16+16)
            const int rbase = k8 * 128 + q4 * 32;
            const int swz = (k8 & 7) << 4;
            *(uint4*)((char*)Kbf + ((rbase)      ^ swz)) = kv0;
            *(uint4*)((char*)Kbf + ((rbase + 16) ^ swz)) = kv1;
        }
        {   // V^T: d = q4*16 + i, col k8
            const unsigned vu[8] = {vv0.x, vv0.y, vv0.z, vv0.w,
                                    vv1.x, vv1.y, vv1.z, vv1.w};
            #pragma unroll
            for (int i = 0; i < 16; ++i) {
                const int d = q4 * 16 + i;
                const u16 hv = (u16)((i & 1) ? (vu[i >> 1] >> 16) : (vu[i >> 1] & 0xffff));
                *(u16*)((char*)VTbf + ((d * 128 + k8 * 2) ^ ((d & 7) << 4))) = hv;
            }
        }
        if (q4 == 0) ktl[k8] = ktc;
        __syncthreads();

        const int t8n = (kt8 < 7) ? kt8 + 1 : 0;
        gather(t8n, kv0, kv1, vv0, vv1, ktc);

        #pragma unroll
        for (int kt = 0; kt < 2; ++kt) {
            // ktv via 4x ds_read_b128 (was 16x b32): key = r + 8j + 4hi
            int4 kt4[4];
            #pragma unroll
            for (int j = 0; j < 4; ++j)
                kt4[j] = *(const int4*)&ktl[kt * 32 + 8 * j + 4 * hi];
            const int* ktvp = (const int*)kt4;
            FragU KA[4];
            #pragma unroll
            for (int ds = 0; ds < 4; ++ds) {
                const int row = kt * 32 + l31;
                KA[ds].v4 = *(const uint4*)((const char*)Kbf +
                    ((row * 128 + ds * 32 + hi * 16) ^ ((row & 7) << 4)));
            }
            FragU VA[2][2];
            #pragma unroll
            for (int dt = 0; dt < 2; ++dt)
                #pragma unroll
                for (int u = 0; u < 2; ++u) {
                    const int row = dt * 32 + l31;
                    const int ks = kt * 2 + u;
                    VA[dt][u].v4 = *(const uint4*)((const char*)VTbf +
                        ((row * 128 + ks * 32 + hi * 16) ^ ((row & 7) << 4)));
                }
            #pragma unroll
            for (int qt = 0; qt < 2; ++qt) {
                f16x s = {0.f,0.f,0.f,0.f,0.f,0.f,0.f,0.f,
                          0.f,0.f,0.f,0.f,0.f,0.f,0.f,0.f};
                #pragma unroll
                for (int ds = 0; ds < 4; ++ds) {
                    FragU qf; qf.v4 = QF4[qt][ds];
                    s = __builtin_amdgcn_mfma_f32_32x32x16_bf16(KA[ds].f, qf.f, s, 0, 0, 0);
                }
                const float a = aC[qt];
                float pv[16];
                #pragma unroll
                for (int i = 0; i < 16; ++i) {
                    const float e = exp2f(fmaf(s[i], a, -a));   // exp(qn/8*(s-1))
                    const float p = (q_t[qt] > ktvp[i]) ? e : 0.0f;
                    pv[i] = p;
                    lacc[qt] += p;
                }
                unsigned P2[8];
                #pragma unroll
                for (int g = 0; g < 4; ++g) {
                    P2[2*g]   = cvt_pk(pv[4*g],   pv[4*g+1]);
                    P2[2*g+1] = cvt_pk(pv[4*g+2], pv[4*g+3]);
                }
                // B-fragment exchange via v_permlane32_swap (T12):
                // swap(P2[4u], P2[4u+2]) -> words 0,2 ; swap(P2[4u+1], P2[4u+3]) -> 1,3
                #pragma unroll
                for (int u = 0; u < 2; ++u) {
                    unsigned a0 = P2[4*u + 0], b0 = P2[4*u + 2];
                    unsigned a1 = P2[4*u + 1], b1 = P2[4*u + 3];
                    asm("v_permlane32_swap_b32 %0, %1" : "+v"(a0), "+v"(b0));
                    asm("v_permlane32_swap_b32 %0, %1" : "+v"(a1), "+v"(b1));
                    FragU bfv;
                    bfv.u[0] = a0; bfv.u[1] = a1; bfv.u[2] = b0; bfv.u[3] = b1;
                    #pragma unroll
                    for (int dt = 0; dt < 2; ++dt)
                        acc[dt][qt] = __builtin_amdgcn_mfma_f32_32x32x16_bf16(
                            VA[dt][u].f, bfv.f, acc[dt][qt], 0, 0, 0);
                }
            }
        }
    }

    float invl[2];
    #pragma unroll
    for (int qt = 0; qt < 2; ++qt) {
        const float lt = lacc[qt] + __shfl_xor(lacc[qt], 32);
        invl[qt] = (lt > 0.f) ? 1.0f / lt : 0.0f;
        const float lse = (lt > 0.f) ? (mnat[qt] + logf(lt)) : -5.0e4f;
        if (hi == 0) {
            lW[w][qt * 32 + l31] = lt;
            qtW[w][qt * 32 + l31] = q_t[qt];
            lse_hash[(size_t)(bh * NHASH + h) * TT + q_t[qt]] = lse;
        }
    }
    __syncthreads();

    float* ost = Ost[w];
    #pragma unroll
    for (int qt = 0; qt < 2; ++qt)
        #pragma unroll
        for (int dt = 0; dt < 2; ++dt) {
            #pragma unroll
            for (int r = 0; r < 16; ++r) {
                const int row = (r & 3) + 8 * (r >> 2) + 4 * hi;
                ost[row * 33 + l31] = acc[dt][qt][r] * invl[qt];
            }
            const int qq = lane >> 1, h2 = lane & 1;
            const int qglob = qtW[w][qt * 32 + qq];
            const float lq = lW[w][qt * 32 + qq];
            float ov[16];
            #pragma unroll
            for (int i = 0; i < 16; ++i)
                ov[i] = ost[(h2 * 16 + i) * 33 + qq];
            __half* orow = o_hash + ((size_t)(bh * NHASH + h) * TT + qglob) * DHH
                         + dt * 32 + h2 * 16;
            if (lq > 0.f) {
                uint4 o0, o1;
                o0.x = pkrtz(ov[0],  ov[1]);  o0.y = pkrtz(ov[2],  ov[3]);
                o0.z = pkrtz(ov[4],  ov[5]);  o0.w = pkrtz(ov[6],  ov[7]);
                o1.x = pkrtz(ov[8],  ov[9]);  o1.y = pkrtz(ov[10], ov[11]);
                o1.z = pkrtz(ov[12], ov[13]); o1.w = pkrtz(ov[14], ov[15]);
                ((uint4*)orow)[0] = o0;
                ((uint4*)orow)[1] = o1;
            } else {
                const u16* vr = v + vbase + (size_t)qglob * DD + dt * 32 + h2 * 16;
                uint4 o0, o1;
                o0.x = pkrtz(b2f(vr[0]),  b2f(vr[1]));
                o0.y = pkrtz(b2f(vr[2]),  b2f(vr[3]));
                o0.z = pkrtz(b2f(vr[4]),  b2f(vr[5]));
                o0.w = pkrtz(b2f(vr[6]),  b2f(vr[7]));
                o1.x = pkrtz(b2f(vr[8]),  b2f(vr[9]));
                o1.y = pkrtz(b2f(vr[10]), b2f(vr[11]));
                o1.z = pkrtz(b2f(vr[12]), b2f(vr[13]));
                o1.w = pkrtz(b2f(vr[14]), b2f(vr[15]));
                ((uint4*)orow)[0] = o0;
                ((uint4*)orow)[1] = o1;
            }
        }
}

// ---------------------------------------------------------------------------
// Combine hash rounds: read o_hash f16, write merged bf16 (wo GEMM A-operand)
__global__ __launch_bounds__(256)
void combine_kernel(const __half* __restrict__ o_hash, const float* __restrict__ lse_hash,
                    u16* __restrict__ am)
{
    const int idx = blockIdx.x * 4 + (threadIdx.x >> 6);
    const int lane = threadIdx.x & 63;
    const int bh = idx >> 9, t = idx & 511;
    const int b = bh >> 3, head = bh & 7;
    const float ls0 = lse_hash[(size_t)(bh * NHASH + 0) * TT + t];
    const float ls1 = lse_hash[(size_t)(bh * NHASH + 1) * TT + t];
    const float ls2 = lse_hash[(size_t)(bh * NHASH + 2) * TT + t];
    const float ls3 = lse_hash[(size_t)(bh * NHASH + 3) * TT + t];
    const float M = fmaxf(fmaxf(ls0, ls1), fmaxf(ls2, ls3));
    const float e0 = __expf(ls0 - M), e1 = __expf(ls1 - M);
    const float e2 = __expf(ls2 - M), e3 = __expf(ls3 - M);
    const float inv = 1.0f / (e0 + e1 + e2 + e3);
    const float o =
        (e0 * __half2float(o_hash[((size_t)((bh * NHASH + 0) * TT + t)) * DHH + lane]) +
         e1 * __half2float(o_hash[((size_t)((bh * NHASH + 1) * TT + t)) * DHH + lane]) +
         e2 * __half2float(o_hash[((size_t)((bh * NHASH + 2) * TT + t)) * DHH + lane]) +
         e3 * __half2float(o_hash[((size_t)((bh * NHASH + 3) * TT + t)) * DHH + lane])) * inv;
    am[((size_t)(b * TT + t)) * DD + head * DHH + lane] = bf16_1(o);
}

// ---------------------------------------------------------------------------
// Final head
__device__ __forceinline__ float block_sum256(float v, volatile float* red)
{
    const int lane = threadIdx.x & 63, wid = threadIdx.x >> 6;
    #pragma unroll
    for (int o = 1; o < 64; o <<= 1) v += __shfl_xor(v, o);
    __syncthreads();
    if (lane == 0) red[wid] = v;
    __syncthreads();
    return red[0] + red[1] + red[2] + red[3];
}

__global__ __launch_bounds__(256)
void head_kernel(const float* __restrict__ x1, const float* __restrict__ x2,
                 const float* __restrict__ lnfg, const float* __restrict__ lnfb,
                 const float* __restrict__ hw1, const float* __restrict__ hb1,
                 const float* __restrict__ hlng, const float* __restrict__ hlnb,
                 const float* __restrict__ hw2, const float* __restrict__ hb2,
                 float* __restrict__ out)
{
    __shared__ float nrow[512];
    __shared__ float red[4];
    const int b = blockIdx.x, tid = threadIdx.x;
    const size_t roff = ((size_t)b * TT + (TT - 1)) * DD;
    const float v0 = 0.5f * (x1[roff + tid] + x2[roff + tid]);
    const float v1 = 0.5f * (x1[roff + 256 + tid] + x2[roff + 256 + tid]);
    const float mean = block_sum256(v0 + v1, red) * (1.0f / 512.0f);
    const float d0 = v0 - mean, d1 = v1 - mean;
    const float var = block_sum256(d0 * d0 + d1 * d1, red) * (1.0f / 512.0f);
    const float rstd = rsqrtf(var + 1e-5f);
    nrow[tid]       = d0 * rstd * lnfg[tid] + lnfb[tid];
    nrow[tid + 256] = d1 * rstd * lnfg[tid + 256] + lnfb[tid + 256];
    __syncthreads();
    float a = hb1[tid];
    for (int k = 0; k < 512; ++k) a = fmaf(nrow[k], hw1[(size_t)k * 256 + tid], a);
    const float m2 = block_sum256(a, red) * (1.0f / 256.0f);
    const float dd = a - m2;
    const float var2 = block_sum256(dd * dd, red) * (1.0f / 256.0f);
    float y = dd * rsqrtf(var2 + 1e-5f) * hlng[tid] + hlnb[tid];
    y = fmaxf(y, 0.0f);
    const float osum = block_sum256(y * hw2[tid], red);
    if (tid == 0) out[b] = osum + hb2[0];
}

// ---------------------------------------------------------------------------
extern "C" void kernel_launch(void* const* d_in, const int* in_sizes, int n_in,
                              void* d_out, int out_size, void* d_ws, size_t ws_size,
                              hipStream_t stream)
{
    (void)in_sizes; (void)n_in; (void)out_size; (void)ws_size;
    const float* x    = (const float*)d_in[0];
    const float* embw = (const float*)d_in[1];
    const float* embb = (const float*)d_in[2];
    const float* pos  = (const float*)d_in[3];
    const float* ln1g = (const float*)d_in[4];
    const float* ln1b = (const float*)d_in[5];
    const float* wqk  = (const float*)d_in[6];
    const float* wv   = (const float*)d_in[7];
    const float* wo   = (const float*)d_in[8];
    const float* wob  = (const float*)d_in[9];
    const float* ln2g = (const float*)d_in[10];
    const float* ln2b = (const float*)d_in[11];
    const float* ffw1 = (const float*)d_in[12];
    const float* ffb1 = (const float*)d_in[13];
    const float* ffw2 = (const float*)d_in[14];
    const float* ffb2 = (const float*)d_in[15];
    const float* rot  = (const float*)d_in[16];
    const float* lnfg = (const float*)d_in[17];
    const float* lnfb = (const float*)d_in[18];
    const float* hw1  = (const float*)d_in[19];
    const float* hb1  = (const float*)d_in[20];
    const float* hlng = (const float*)d_in[21];
    const float* hlnb = (const float*)d_in[22];
    const float* hw2  = (const float*)d_in[23];
    const float* hb2  = (const float*)d_in[24];
    float* out = (float*)d_out;

    const size_t SZ_BTD = (size_t)BB * TT * DD;            // 4,194,304
    const size_t SZ_OH  = (size_t)BHH * NHASH * TT * DHH;  // 16,777,216

    char* p = (char*)d_ws;
    float* x1b = (float*)p;  p += SZ_BTD * 4;
    float* x2b = (float*)p;  p += SZ_BTD * 4;
    float* xnb = (float*)p;  p += SZ_BTD * 4;              // also amb (bf16) late
    u16*   vbh = (u16*)p;    p += SZ_BTD * 2;
    u16*   xnbh = (u16*)p;   p += SZ_BTD * 2;
    u16*   qkh  = (u16*)p;   p += SZ_BTD * 2;              // bf16 qk, per-head layout
    u16*   qknb = (u16*)p;   p += (size_t)BHH * TT * DHH * 2;
    float* qnrm = (float*)p; p += (size_t)BHH * TT * 4;
    float* rotated = (float*)p; p += (size_t)BB * TT * 32 * 4;
    __half* ohash = (__half*)p;                  // 33.5MB region
    u16*    ffmid = (u16*)p;                     // temporal alias (disjoint life)
    p += SZ_OH * 2;
    float* lseb  = (float*)p; p += (size_t)BHH * NHASH * TT * 4;
    int*   stb   = (int*)p;   p += (size_t)BHH * NHASH * TT * 4;
    u16* wqkT = (u16*)p; p += (size_t)NLAYER * DD * DD * 2;
    u16* wvT  = (u16*)p; p += (size_t)NLAYER * DD * DD * 2;
    u16* woT  = (u16*)p; p += (size_t)NLAYER * DD * DD * 2;
    u16* w1T  = (u16*)p; p += (size_t)NLAYER * DD * FFD * 2;
    u16* w2T  = (u16*)p; p += (size_t)NLAYER * FFD * DD * 2;
    float* wrotAll = (float*)p; p += (size_t)NLAYER * DD * 32 * 4;
    u16* amb = (u16*)xnb;                        // alias (xnb dead after GEMMs)

    // ---- one-time weight prep (all layers) ----
    prep_weights<<<11264, 256, 0, stream>>>(wqk, wv, wo, ffw1, ffw2,
                                            wqkT, wvT, woT, w1T, w2T);
    wrot_kernel<<<dim3(32, NLAYER), 256, 0, stream>>>(wqk, rot, wrotAll);

    embed_kernel<<<BB * TT, 256, 0, stream>>>(x, embw, embb, pos, x1b, x2b);

    for (int L = 0; L < NLAYER; ++L) {
        const size_t w512 = (size_t)L * DD * DD;
        const size_t wff  = (size_t)L * DD * FFD;

        // x1 += attn(ln(x2))
        ln_kernel<<<2048, 256, 0, stream>>>(x2b, ln1g + L * DD, ln1b + L * DD, xnb, xnbh);
        rot_gemm<<<128, 256, 0, stream>>>(xnb, wrotAll + (size_t)L * DD * 32, rotated);
        gemm_bf16<64, 64, 64, false, false, false, true, true><<<dim3(128, 8), 256, 0, stream>>>(
            xnbh, wqkT + w512, nullptr, nullptr, nullptr, qkh, BB * TT, DD, DD);
        gemm_bf16<64, 64, 64, false, false, false, true, false><<<dim3(128, 8), 256, 0, stream>>>(
            xnbh, wvT + w512, nullptr, nullptr, nullptr, vbh, BB * TT, DD, DD);
        bucket_sort_kernel<<<dim3(NHASH, BHH), 512, 0, stream>>>(rotated, stb);
        knorm_kernel<<<4096, 256, 0, stream>>>(qkh, qknb, qnrm);
        lsh_attn_mfma<<<dim3(NCHUNK, BHH), 256, 0, stream>>>(
            qknb, vbh, qnrm, stb, ohash, lseb);
        combine_kernel<<<16384, 256, 0, stream>>>(ohash, lseb, amb);
        gemm_bf16<64, 64, 64, false, true, true, false, false><<<dim3(128, 8), 256, 0, stream>>>(
            amb, woT + w512, wob + L * DD, x1b, x1b, nullptr, BB * TT, DD, DD);

        // x2 += ff(ln(x1))
        ln_kernel<<<2048, 256, 0, stream>>>(x1b, ln2g + L * DD, ln2b + L * DD, xnb, xnbh);
        gemm_bf16<128, 128, 32, true, false, true, true, false><<<dim3(64, 16), 256, 0, stream>>>(
            xnbh, w1T + wff, ffb1 + L * FFD, nullptr, nullptr, ffmid, BB * TT, FFD, DD);
        gemm_bf16<64, 64, 64, false, true, true, false, false><<<dim3(128, 8), 256, 0, stream>>>(
            ffmid, w2T + wff, ffb2 + L * DD, x2b, x2b, nullptr, BB * TT, DD, FFD);
    }

    head_kernel<<<16, 256, 0, stream>>>(x1b, x2b, lnfg, lnfb, hw1, hb1,
                                        hlng, hlnb, hw2, hb2, out);
}

// Round 7
// 947.948 us; speedup vs baseline: 7.7455x; 1.0888x over previous
//
#include <hip/hip_runtime.h>
#include <hip/hip_fp16.h>
#include <cfloat>
#include <cstdint>

// Problem constants
#define BB      16      // batch
#define TT      512     // seq
#define DD      512     // d_model
#define HH      8       // heads
#define DHH     64      // head dim
#define FFD     2048    // ff dim
#define BHH     128     // BB*HH
#define NHASH   4
#define NCHUNK  8       // NHASH * N_BUCKETS
#define CHUNKSZ 256
#define NLAYER  4

typedef unsigned short u16;
typedef unsigned int   u32;
typedef __attribute__((ext_vector_type(8))) short bfrag;    // 8 bf16 (4 VGPR)
typedef __attribute__((ext_vector_type(4))) float f4x;      // 4 f32 acc
typedef __attribute__((ext_vector_type(16))) float f16x;    // 16 f32 acc

union FragU { u32 u[4]; uint4 v4; bfrag f; };

__device__ __forceinline__ unsigned pk_bf16(float a, float b) {
    union { float f; unsigned u; } x, y;
    x.f = a; y.f = b;
    unsigned lo = ((x.u + 0x7FFFu + ((x.u >> 16) & 1u)) >> 16) & 0xFFFFu;
    unsigned hi = (y.u + 0x7FFFu + ((y.u >> 16) & 1u)) & 0xFFFF0000u;
    return lo | hi;
}
// HW packed f32->bf16 RTNE (1 VALU op; no builtin on gfx950)
__device__ __forceinline__ unsigned cvt_pk(float a, float b) {
    unsigned r;
    asm("v_cvt_pk_bf16_f32 %0, %1, %2" : "=v"(r) : "v"(a), "v"(b));
    return r;
}
// HW packed f32->f16 (RTZ) — o_hash precision (10-bit mantissa)
__device__ __forceinline__ unsigned pkrtz(float a, float b) {
    unsigned r;
    asm("v_cvt_pkrtz_f16_f32 %0, %1, %2" : "=v"(r) : "v"(a), "v"(b));
    return r;
}
__device__ __forceinline__ u16 bf16_1(float a) {
    union { float f; unsigned u; } x; x.f = a;
    return (u16)((x.u + 0x7FFFu + ((x.u >> 16) & 1u)) >> 16);
}
__device__ __forceinline__ float b2f(u16 h) {
    union { unsigned u; float f; } x; x.u = ((unsigned)h) << 16; return x.f;
}

// async global->LDS, 16B per lane (dest must be linear: base + lane*16)
__device__ __forceinline__ void gload16(const u16* g, u16* l) {
    __builtin_amdgcn_global_load_lds(
        (const __attribute__((address_space(1))) u32*)g,
        (__attribute__((address_space(3))) u32*)l, 16, 0, 0);
}

// ---------------------------------------------------------------------------
// Embedding: h = x @ emb_w + emb_b + pos ; write to both x1 and x2
__global__ __launch_bounds__(256)
void embed_kernel(const float* __restrict__ x, const float* __restrict__ ew,
                  const float* __restrict__ eb, const float* __restrict__ pos,
                  float* __restrict__ x1, float* __restrict__ x2)
{
    const int row = blockIdx.x;          // b*T + t
    const int t = row & (TT - 1);
    __shared__ float xr[32];
    if (threadIdx.x < 32) xr[threadIdx.x] = x[row * 32 + threadIdx.x];
    __syncthreads();
    for (int d = threadIdx.x; d < DD; d += 256) {
        float s = eb[d] + pos[t * DD + d];
        #pragma unroll
        for (int k = 0; k < 32; ++k) s = fmaf(xr[k], ew[k * DD + d], s);
        x1[(size_t)row * DD + d] = s;
        x2[(size_t)row * DD + d] = s;
    }
}

// ---------------------------------------------------------------------------
// LayerNorm over last dim (512); writes bf16 (always) and f32 (if out!=null).
__global__ __launch_bounds__(256)
void ln_kernel(const float* __restrict__ in, const float* __restrict__ g,
               const float* __restrict__ bta, float* __restrict__ out,
               u16* __restrict__ outh)
{
    const int row = blockIdx.x * 4 + (threadIdx.x >> 6);
    const int lane = threadIdx.x & 63;
    const float* r = in + (size_t)row * DD;
    float vals[8];
    float s = 0.0f;
    #pragma unroll
    for (int i = 0; i < 8; ++i) { vals[i] = r[i * 64 + lane]; s += vals[i]; }
    #pragma unroll
    for (int o = 1; o < 64; o <<= 1) s += __shfl_xor(s, o);
    const float mean = s * (1.0f / 512.0f);
    float vs = 0.0f;
    #pragma unroll
    for (int i = 0; i < 8; ++i) { float d = vals[i] - mean; vs += d * d; }
    #pragma unroll
    for (int o = 1; o < 64; o <<= 1) vs += __shfl_xor(vs, o);
    const float rstd = rsqrtf(vs * (1.0f / 512.0f) + 1e-5f);
    u16* hrow = outh + (size_t)row * DD;
    #pragma unroll
    for (int i = 0; i < 8; ++i) {
        const int d = i * 64 + lane;
        const float y = (vals[i] - mean) * rstd * g[d] + bta[d];
        if (out != nullptr) out[(size_t)row * DD + d] = y;
        hrow[d] = bf16_1(y);
    }
}

// ---------------------------------------------------------------------------
// Batched weight prep: transpose+bf16 ALL layers' wqk/wv/wo/ff1/ff2 in ONE
// dispatch. Input (KxN f32) -> output (NxK bf16). 11264 tiles of 32x32.
__global__ __launch_bounds__(256)
void prep_weights(const float* __restrict__ wqk, const float* __restrict__ wv,
                  const float* __restrict__ wo, const float* __restrict__ ffw1,
                  const float* __restrict__ ffw2,
                  u16* __restrict__ wqkT, u16* __restrict__ wvT,
                  u16* __restrict__ woT, u16* __restrict__ w1T,
                  u16* __restrict__ w2T)
{
    const int id = blockIdx.x;
    const float* in; u16* outp; int K, N, kt, nt;
    if (id < 3072) {                       // wqk / wv / wo : 512x512, 256 tiles/L
        const int fam = id >> 10;
        const int r = id & 1023;
        const int L = r >> 8, t = r & 255;
        K = 512; N = 512;
        const size_t off = (size_t)L * 512 * 512;
        in   = (fam == 0 ? wqk  : fam == 1 ? wv  : wo ) + off;
        outp = (fam == 0 ? wqkT : fam == 1 ? wvT : woT) + off;
        kt = (t & 15) << 5; nt = (t >> 4) << 5;
    } else if (id < 7168) {                // ff1: 512x2048, 1024 tiles/L
        const int r = id - 3072;
        const int L = r >> 10, t = r & 1023;
        K = 512; N = 2048;
        in = ffw1 + (size_t)L * 512 * 2048;
        outp = w1T + (size_t)L * 2048 * 512;
        kt = (t & 15) << 5; nt = (t >> 4) << 5;
    } else {                               // ff2: 2048x512, 1024 tiles/L
        const int r = id - 7168;
        const int L = r >> 10, t = r & 1023;
        K = 2048; N = 512;
        in = ffw2 + (size_t)L * 2048 * 512;
        outp = w2T + (size_t)L * 512 * 2048;
        kt = (t & 63) << 5; nt = (t >> 6) << 5;
    }
    __shared__ float tile[32][33];
    const int rr = threadIdx.x >> 3, c4 = (threadIdx.x & 7) * 4;
    const float4 v4 = *(const float4*)(in + (size_t)(kt + rr) * N + nt + c4);
    tile[rr][c4 + 0] = v4.x; tile[rr][c4 + 1] = v4.y;
    tile[rr][c4 + 2] = v4.z; tile[rr][c4 + 3] = v4.w;
    __syncthreads();
    uint2 p;
    p.x = pk_bf16(tile[c4 + 0][rr], tile[c4 + 1][rr]);
    p.y = pk_bf16(tile[c4 + 2][rr], tile[c4 + 3][rr]);
    *(uint2*)(outp + (size_t)(nt + rr) * K + kt + c4) = p;
}

// ---------------------------------------------------------------------------
// wrot[L][f][h*4+hash] = sum_d wqk[L][f][h*64+d] * rot[L][d][hash]
__global__ __launch_bounds__(256)
void wrot_kernel(const float* __restrict__ wqk, const float* __restrict__ rot,
                 float* __restrict__ wrotAll)
{
    const int hh = blockIdx.x, L = blockIdx.y;
    const int head = hh >> 2, h = hh & 3;
    __shared__ float rc[64];
    if (threadIdx.x < 64)
        rc[threadIdx.x] = rot[((size_t)L * 64 + threadIdx.x) * 4 + h];
    __syncthreads();
    for (int f = threadIdx.x; f < 512; f += 256) {
        const float* wrow = wqk + (size_t)L * 512 * 512 + (size_t)f * 512 + head * 64;
        float s = 0.0f;
        #pragma unroll
        for (int d = 0; d < 64; d += 4) {
            const float4 w4 = *(const float4*)(wrow + d);
            s += w4.x * rc[d] + w4.y * rc[d + 1] + w4.z * rc[d + 2] + w4.w * rc[d + 3];
        }
        wrotAll[((size_t)L * 512 + f) * 32 + hh] = s;
    }
}

// ---------------------------------------------------------------------------
// rotated[8192][32] = xn[8192][512] @ wrot[512][32], all f32. grid 128.
__global__ __launch_bounds__(256)
void rot_gemm(const float* __restrict__ A, const float* __restrict__ Wr,
              float* __restrict__ C)
{
    __shared__ float As[64][36];
    __shared__ float Ws[32][36];
    const int m0 = blockIdx.x * 64;
    const int r = threadIdx.x >> 2, cg = threadIdx.x & 3;
    float acc[8] = {};
    for (int f0 = 0; f0 < 512; f0 += 32) {
        __syncthreads();
        {
            const int lr = threadIdx.x >> 2, lc = (threadIdx.x & 3) * 8;
            const float* ap = A + (size_t)(m0 + lr) * 512 + f0 + lc;
            *(float4*)&As[lr][lc]     = ((const float4*)ap)[0];
            *(float4*)&As[lr][lc + 4] = ((const float4*)ap)[1];
            const int wr = threadIdx.x >> 3, wc = (threadIdx.x & 7) * 4;
            *(float4*)&Ws[wr][wc] = *(const float4*)(Wr + (size_t)(f0 + wr) * 32 + wc);
        }
        __syncthreads();
        #pragma unroll
        for (int kk = 0; kk < 32; ++kk) {
            const float a = As[r][kk];
            #pragma unroll
            for (int c = 0; c < 8; ++c)
                acc[c] = fmaf(a, Ws[kk][cg * 8 + c], acc[c]);
        }
    }
    float* crow = C + (size_t)(m0 + r) * 32 + cg * 8;
    *(float4*)crow       = make_float4(acc[0], acc[1], acc[2], acc[3]);
    *(float4*)(crow + 4) = make_float4(acc[4], acc[5], acc[6], acc[7]);
}

// ---------------------------------------------------------------------------
// bf16 MFMA GEMM, templated tile, double-buffered LDS, 2-phase pipeline.
__device__ __forceinline__ float gelu1(float v) {
    return 0.5f * v * (1.0f + erff(v * 0.70710678118654752440f));
}
__device__ __forceinline__ int swz_row(int r, int BK) {
    return (BK == 32) ? ((r & 3) ^ ((r >> 2) & 3)) : (r & 7);
}

template<int BM, int BN, int BK, bool GELU, bool ADD, bool BIAS, bool OUTBF, bool QKL>
__global__ __launch_bounds__(256)
void gemm_bf16(const u16* __restrict__ A, const u16* __restrict__ WT,
               const float* __restrict__ bias, const float* __restrict__ addsrc,
               float* __restrict__ Cf, u16* __restrict__ Cb,
               int M, int N, int K)
{
    constexpr int NCH = BK / 8;
    constexpr int CPA = BM * NCH / 256;
    constexpr int CPB = BN * NCH / 256;
    constexpr int MR = BM / 32, NR = BN / 32, KR = BK / 32;
    __shared__ __align__(16) u16 Abuf[2][BM * BK];
    __shared__ __align__(16) u16 Bbuf[2][BN * BK];
    const int tid = threadIdx.x;
    const int m0 = blockIdx.x * BM, n0 = blockIdx.y * BN;

    const u16* aSrc[CPA]; const u16* bSrc[CPB];
    #pragma unroll
    for (int i = 0; i < CPA; ++i) {
        const int s = tid + i * 256, row = s / NCH, ch = s % NCH;
        aSrc[i] = A + (size_t)(m0 + row) * K + (ch ^ swz_row(row, BK)) * 8;
    }
    #pragma unroll
    for (int i = 0; i < CPB; ++i) {
        const int s = tid + i * 256, row = s / NCH, ch = s % NCH;
        bSrc[i] = WT + (size_t)(n0 + row) * K + (ch ^ swz_row(row, BK)) * 8;
    }

    auto STAGE = [&](int bufi, int koff) {
        #pragma unroll
        for (int i = 0; i < CPA; ++i)
            gload16(aSrc[i] + koff, &Abuf[bufi][(tid + i * 256) * 8]);
        #pragma unroll
        for (int i = 0; i < CPB; ++i)
            gload16(bSrc[i] + koff, &Bbuf[bufi][(tid + i * 256) * 8]);
    };

    const int l = tid & 63, wv_ = tid >> 6;
    const int wm = (wv_ >> 1) * (BM / 2);
    const int wn = (wv_ & 1) * (BN / 2);
    const int fr = l & 15, fc = l >> 4;

    f4x acc[MR][NR] = {};
    const int nK = K / BK;
    STAGE(0, 0);
    for (int ks = 0; ks < nK; ++ks) {
        __syncthreads();
        if (ks + 1 < nK) STAGE((ks + 1) & 1, (ks + 1) * BK);
        const u16* Ab = Abuf[ks & 1];
        const u16* Bb = Bbuf[ks & 1];
        FragU af[MR][KR], bf_[NR][KR];
        #pragma unroll
        for (int i = 0; i < MR; ++i)
            #pragma unroll
            for (int u = 0; u < KR; ++u) {
                const int r = wm + i * 16 + fr;
                af[i][u].v4 = *(const uint4*)((const char*)Ab +
                    (size_t)r * (2 * BK) + (((u * 4 + fc) ^ swz_row(r, BK)) << 4));
            }
        #pragma unroll
        for (int j = 0; j < NR; ++j)
            #pragma unroll
            for (int u = 0; u < KR; ++u) {
                const int r = wn + j * 16 + fr;
                bf_[j][u].v4 = *(const uint4*)((const char*)Bb +
                    (size_t)r * (2 * BK) + (((u * 4 + fc) ^ swz_row(r, BK)) << 4));
            }
        #pragma unroll
        for (int u = 0; u < KR; ++u)
            #pragma unroll
            for (int i = 0; i < MR; ++i)
                #pragma unroll
                for (int j = 0; j < NR; ++j)
                    acc[i][j] = __builtin_amdgcn_mfma_f32_16x16x32_bf16(
                        af[i][u].f, bf_[j][u].f, acc[i][j], 0, 0, 0);
    }

    #pragma unroll
    for (int i = 0; i < MR; ++i) {
        #pragma unroll
        for (int q = 0; q < 4; ++q) {
            const int row = m0 + wm + i * 16 + fc * 4 + q;
            #pragma unroll
            for (int j = 0; j < NR; ++j) {
                const int col = n0 + wn + j * 16 + fr;
                float vx = acc[i][j][q];
                if constexpr (BIAS) vx += bias[col];
                if constexpr (GELU) vx = gelu1(vx);
                if constexpr (ADD) vx += addsrc[(size_t)row * N + col];
                if constexpr (QKL) {
                    const int bq = row >> 9, tq = row & 511;
                    const int hq = col >> 6, dq = col & 63;
                    Cb[(((size_t)(bq * 8 + hq) * 512) + tq) * 64 + dq] = bf16_1(vx);
                } else if constexpr (OUTBF) {
                    Cb[(size_t)row * N + col] = bf16_1(vx);
                } else {
                    Cf[(size_t)row * N + col] = vx;
                }
            }
        }
    }
}

// ---------------------------------------------------------------------------
// K/Q pre-normalization from bf16 qkh: qkn = bf16(row/|row|), qnrm = |row|
__global__ __launch_bounds__(256)
void knorm_kernel(const u16* __restrict__ qkh, u16* __restrict__ qkn,
                  float* __restrict__ qnrm)
{
    const int g = blockIdx.x * 16 + (threadIdx.x >> 4);  // bh*T + t
    const int li = threadIdx.x & 15;
    const uint2 raw = *(const uint2*)(qkh + (size_t)g * 64 + li * 4);
    const float v0 = b2f((u16)(raw.x & 0xffff)), v1 = b2f((u16)(raw.x >> 16));
    const float v2 = b2f((u16)(raw.y & 0xffff)), v3 = b2f((u16)(raw.y >> 16));
    float ss = v0 * v0 + v1 * v1 + v2 * v2 + v3 * v3;
    ss += __shfl_xor(ss, 1); ss += __shfl_xor(ss, 2);
    ss += __shfl_xor(ss, 4); ss += __shfl_xor(ss, 8);
    const float qn = sqrtf(ss);
    const float rv = 1.0f / fmaxf(qn, 1e-12f);
    uint2 o;
    o.x = cvt_pk(v0 * rv, v1 * rv);
    o.y = cvt_pk(v2 * rv, v3 * rv);
    *(uint2*)(qkn + (size_t)g * 64 + li * 4) = o;
    if (li == 0) qnrm[g] = qn;
}

// ---------------------------------------------------------------------------
// Bucket assignment + stable partition from precomputed rotated (f32)
__global__ __launch_bounds__(512)
void bucket_sort_kernel(const float* __restrict__ rotated, int* __restrict__ st)
{
    const int h = blockIdx.x, bh = blockIdx.y;
    const int b = bh >> 3, head = bh & 7;
    const int t = threadIdx.x;
    __shared__ int zcnt[8];
    const float r = rotated[((size_t)(b * TT + t)) * 32 + head * 4 + h];
    const int bit = (r < 0.0f) ? 1 : 0;
    const int wid = t >> 6, lane = t & 63;
    const unsigned long long zm = __ballot(bit == 0);
    if (lane == 0) zcnt[wid] = __popcll(zm);
    __syncthreads();
    int zoff = 0, Z = 0;
    #pragma unroll
    for (int w = 0; w < 8; ++w) { const int cn = zcnt[w]; if (w < wid) zoff += cn; Z += cn; }
    const int zpre = __popcll(zm & ((1ull << lane) - 1ull));
    const int dst = (bit == 0) ? (zoff + zpre)
                               : (Z + (wid * 64 - zoff) + (lane - zpre));
    st[((size_t)bh * NHASH + h) * TT + dst] = t;
}

// ---------------------------------------------------------------------------
// MFMA LSH attention — 8 waves x 32 queries (512 threads), VGPR-capped for
// 4 waves/SIMD. Q,K from normalized bf16 qkn; V bf16; O out f16.
// Register-free epilogue via v_permlane32_swap (no Ost LDS).
__global__ __launch_bounds__(512, 4)
void lsh_attn_mfma(const u16* __restrict__ qkn, const u16* __restrict__ v,
                   const float* __restrict__ qnrm, const int* __restrict__ st,
                   __half* __restrict__ o_hash, float* __restrict__ lse_hash)
{
    const int cc = blockIdx.x, bh = blockIdx.y;
    const int b = bh >> 3, head = bh & 7;
    const int h = cc >> 1, c = cc & 1;
    const int pcc = (cc + 7) & 7;
    const int hp = pcc >> 1, cp = pcc & 1;
    const int tid = threadIdx.x;
    const int w = tid >> 6;          // wave 0..7 -> queries w*32..+32
    const int lane = tid & 63;
    const int l31 = lane & 31;
    const int hi = lane >> 5;
    const int* stb = st + (size_t)bh * (NHASH * TT);
    const size_t vbase = ((size_t)b * TT) * DD + head * DHH;
    const u16* qknb = qkn + (size_t)bh * TT * DHH;

    __shared__ __align__(16) u16 Kbf[64 * 64];
    __shared__ __align__(16) u16 VTbf[64 * 64];
    __shared__ __align__(16) int ktl[64];

    // ---- Q fragment (one query per lane-column) ----
    const int q_t = stb[h * TT + c * CHUNKSZ + w * 32 + l31];
    const float qn = qnrm[(size_t)bh * TT + q_t];
    const float mnat = qn * 0.125f;
    const float aC = qn * 0.1803368801111137f;   // |q| * 0.125 * log2(e)
    uint4 QF4[4];
    {
        const u16* qrow = qknb + (size_t)q_t * DHH;
        #pragma unroll
        for (int ds = 0; ds < 4; ++ds)
            QF4[ds] = *(const uint4*)(qrow + ds * 16 + hi * 8);
    }

    f16x acc[2] = {};           // [dt] O^T tiles (32d x 32q)
    float lacc = 0.f;
    const int k8 = tid >> 3;    // key row 0..63 (8 lanes per 128B row)
    const int c8 = tid & 7;     // 16B chunk of the row

    auto gather = [&](int t8, uint4& kc, uint4& vc, int& ktc) {
        const int kj = t8 * 64 + k8;
        const int k_t = (kj < CHUNKSZ) ? stb[h * TT + c * CHUNKSZ + kj]
                                       : stb[hp * TT + cp * CHUNKSZ + (kj - CHUNKSZ)];
        ktc = k_t;
        kc = *(const uint4*)(qknb + (size_t)k_t * DHH + c8 * 8);
        vc = *(const uint4*)(v + vbase + (size_t)k_t * DD + c8 * 8);
    };

    uint4 kc, vc; int ktc;
    gather(0, kc, vc, ktc);

    for (int kt8 = 0; kt8 < 8; ++kt8) {
        __syncthreads();   // previous tile fully consumed
        // K: row k8, chunk c8 (swizzled) — single b128
        *(uint4*)((char*)Kbf + ((k8 * 128 + c8 * 16) ^ ((k8 & 7) << 4))) = kc;
        {   // V^T: d = c8*8 + i, col k8 ; d&7 == i
            const unsigned vu[4] = {vc.x, vc.y, vc.z, vc.w};
            #pragma unroll
            for (int i = 0; i < 8; ++i) {
                const int d = c8 * 8 + i;
                const u16 hv = (u16)((i & 1) ? (vu[i >> 1] >> 16) : (vu[i >> 1] & 0xffff));
                *(u16*)((char*)VTbf + ((d * 128 + k8 * 2) ^ (i << 4))) = hv;
            }
        }
        if (c8 == 0) ktl[k8] = ktc;
        __syncthreads();

        const int t8n = (kt8 < 7) ? kt8 + 1 : 0;
        gather(t8n, kc, vc, ktc);

        #pragma unroll
        for (int kt = 0; kt < 2; ++kt) {
            int4 kt4[4];
            #pragma unroll
            for (int j = 0; j < 4; ++j)
                kt4[j] = *(const int4*)&ktl[kt * 32 + 8 * j + 4 * hi];
            const int* ktvp = (const int*)kt4;
            FragU KA[4];
            #pragma unroll
            for (int ds = 0; ds < 4; ++ds) {
                const int row = kt * 32 + l31;
                KA[ds].v4 = *(const uint4*)((const char*)Kbf +
                    ((row * 128 + ds * 32 + hi * 16) ^ ((row & 7) << 4)));
            }
            FragU VA[2][2];
            #pragma unroll
            for (int dt = 0; dt < 2; ++dt)
                #pragma unroll
                for (int u = 0; u < 2; ++u) {
                    const int row = dt * 32 + l31;
                    const int ks = kt * 2 + u;
                    VA[dt][u].v4 = *(const uint4*)((const char*)VTbf +
                        ((row * 128 + ks * 32 + hi * 16) ^ ((row & 7) << 4)));
                }
            f16x s = {0.f,0.f,0.f,0.f,0.f,0.f,0.f,0.f,
                      0.f,0.f,0.f,0.f,0.f,0.f,0.f,0.f};
            #pragma unroll
            for (int ds = 0; ds < 4; ++ds) {
                FragU qf; qf.v4 = QF4[ds];
                s = __builtin_amdgcn_mfma_f32_32x32x16_bf16(KA[ds].f, qf.f, s, 0, 0, 0);
            }
            float pv[16];
            #pragma unroll
            for (int i = 0; i < 16; ++i) {
                const float e = exp2f(fmaf(s[i], aC, -aC));   // exp(qn/8*(s-1))
                const float p = (q_t > ktvp[i]) ? e : 0.0f;
                pv[i] = p;
                lacc += p;
            }
            unsigned P2[8];
            #pragma unroll
            for (int g = 0; g < 4; ++g) {
                P2[2*g]   = cvt_pk(pv[4*g],   pv[4*g+1]);
                P2[2*g+1] = cvt_pk(pv[4*g+2], pv[4*g+3]);
            }
            #pragma unroll
            for (int u = 0; u < 2; ++u) {
                unsigned a0 = P2[4*u + 0], b0 = P2[4*u + 2];
                unsigned a1 = P2[4*u + 1], b1 = P2[4*u + 3];
                asm("v_permlane32_swap_b32 %0, %1" : "+v"(a0), "+v"(b0));
                asm("v_permlane32_swap_b32 %0, %1" : "+v"(a1), "+v"(b1));
                FragU bfv;
                bfv.u[0] = a0; bfv.u[1] = a1; bfv.u[2] = b0; bfv.u[3] = b1;
                #pragma unroll
                for (int dt = 0; dt < 2; ++dt)
                    acc[dt] = __builtin_amdgcn_mfma_f32_32x32x16_bf16(
                        VA[dt][u].f, bfv.f, acc[dt], 0, 0, 0);
            }
        }
    }

    // ---- finalize: l, lse, in-register transpose-free epilogue ----
    const float lt = lacc + __shfl_xor(lacc, 32);
    const float invl = (lt > 0.f) ? 1.0f / lt : 0.0f;
    if (hi == 0) {
        const float lse = (lt > 0.f) ? (mnat + logf(lt)) : -5.0e4f;
        lse_hash[(size_t)(bh * NHASH + h) * TT + q_t] = lse;
    }
    // pack to f16 pairs: wa = dt0 words (d-pairs at +4*hi), wb = dt1
    unsigned wa[8], wb[8];
    #pragma unroll
    for (int m = 0; m < 8; ++m) {
        wa[m] = pkrtz(acc[0][2*m] * invl, acc[0][2*m+1] * invl);
        wb[m] = pkrtz(acc[1][2*m] * invl, acc[1][2*m+1] * invl);
    }
    // swap a.hi32 <-> b.lo32: lane<32 ends with full dt0 (d 0..31),
    // lane>=32 with full dt1 (d 32..63)
    #pragma unroll
    for (int m = 0; m < 8; ++m)
        asm("v_permlane32_swap_b32 %0, %1" : "+v"(wa[m]), "+v"(wb[m]));
    __half* orow = o_hash + ((size_t)(bh * NHASH + h) * TT + q_t) * DHH + hi * 32;
    if (lt > 0.f) {
        #pragma unroll
        for (int g = 0; g < 4; ++g) {
            uint4 o;
            o.x = wa[2*g]; o.y = wa[2*g+1];
            o.z = wb[2*g]; o.w = wb[2*g+1];
            ((uint4*)orow)[g] = o;
        }
    } else {
        const u16* vr = v + vbase + (size_t)q_t * DD + hi * 32;
        #pragma unroll
        for (int g = 0; g < 4; ++g) {
            uint4 o;
            o.x = pkrtz(b2f(vr[8*g+0]), b2f(vr[8*g+1]));
            o.y = pkrtz(b2f(vr[8*g+2]), b2f(vr[8*g+3]));
            o.z = pkrtz(b2f(vr[8*g+4]), b2f(vr[8*g+5]));
            o.w = pkrtz(b2f(vr[8*g+6]), b2f(vr[8*g+7]));
            ((uint4*)orow)[g] = o;
        }
    }
}

// ---------------------------------------------------------------------------
// Combine hash rounds: read o_hash f16, write merged bf16 (wo GEMM A-operand)
__global__ __launch_bounds__(256)
void combine_kernel(const __half* __restrict__ o_hash, const float* __restrict__ lse_hash,
                    u16* __restrict__ am)
{
    const int idx = blockIdx.x * 4 + (threadIdx.x >> 6);
    const int lane = threadIdx.x & 63;
    const int bh = idx >> 9, t = idx & 511;
    const int b = bh >> 3, head = bh & 7;
    const float ls0 = lse_hash[(size_t)(bh * NHASH + 0) * TT + t];
    const float ls1 = lse_hash[(size_t)(bh * NHASH + 1) * TT + t];
    const float ls2 = lse_hash[(size_t)(bh * NHASH + 2) * TT + t];
    const float ls3 = lse_hash[(size_t)(bh * NHASH + 3) * TT + t];
    const float M = fmaxf(fmaxf(ls0, ls1), fmaxf(ls2, ls3));
    const float e0 = __expf(ls0 - M), e1 = __expf(ls1 - M);
    const float e2 = __expf(ls2 - M), e3 = __expf(ls3 - M);
    const float inv = 1.0f / (e0 + e1 + e2 + e3);
    const float o =
        (e0 * __half2float(o_hash[((size_t)((bh * NHASH + 0) * TT + t)) * DHH + lane]) +
         e1 * __half2float(o_hash[((size_t)((bh * NHASH + 1) * TT + t)) * DHH + lane]) +
         e2 * __half2float(o_hash[((size_t)((bh * NHASH + 2) * TT + t)) * DHH + lane]) +
         e3 * __half2float(o_hash[((size_t)((bh * NHASH + 3) * TT + t)) * DHH + lane])) * inv;
    am[((size_t)(b * TT + t)) * DD + head * DHH + lane] = bf16_1(o);
}

// ---------------------------------------------------------------------------
// Final head
__device__ __forceinline__ float block_sum256(float v, volatile float* red)
{
    const int lane = threadIdx.x & 63, wid = threadIdx.x >> 6;
    #pragma unroll
    for (int o = 1; o < 64; o <<= 1) v += __shfl_xor(v, o);
    __syncthreads();
    if (lane == 0) red[wid] = v;
    __syncthreads();
    return red[0] + red[1] + red[2] + red[3];
}

__global__ __launch_bounds__(256)
void head_kernel(const float* __restrict__ x1, const float* __restrict__ x2,
                 const float* __restrict__ lnfg, const float* __restrict__ lnfb,
                 const float* __restrict__ hw1, const float* __restrict__ hb1,
                 const float* __restrict__ hlng, const float* __restrict__ hlnb,
                 const float* __restrict__ hw2, const float* __restrict__ hb2,
                 float* __restrict__ out)
{
    __shared__ float nrow[512];
    __shared__ float red[4];
    const int b = blockIdx.x, tid = threadIdx.x;
    const size_t roff = ((size_t)b * TT + (TT - 1)) * DD;
    const float v0 = 0.5f * (x1[roff + tid] + x2[roff + tid]);
    const float v1 = 0.5f * (x1[roff + 256 + tid] + x2[roff + 256 + tid]);
    const float mean = block_sum256(v0 + v1, red) * (1.0f / 512.0f);
    const float d0 = v0 - mean, d1 = v1 - mean;
    const float var = block_sum256(d0 * d0 + d1 * d1, red) * (1.0f / 512.0f);
    const float rstd = rsqrtf(var + 1e-5f);
    nrow[tid]       = d0 * rstd * lnfg[tid] + lnfb[tid];
    nrow[tid + 256] = d1 * rstd * lnfg[tid + 256] + lnfb[tid + 256];
    __syncthreads();
    float a = hb1[tid];
    for (int k = 0; k < 512; ++k) a = fmaf(nrow[k], hw1[(size_t)k * 256 + tid], a);
    const float m2 = block_sum256(a, red) * (1.0f / 256.0f);
    const float dd = a - m2;
    const float var2 = block_sum256(dd * dd, red) * (1.0f / 256.0f);
    float y = dd * rsqrtf(var2 + 1e-5f) * hlng[tid] + hlnb[tid];
    y = fmaxf(y, 0.0f);
    const float osum = block_sum256(y * hw2[tid], red);
    if (tid == 0) out[b] = osum + hb2[0];
}

// ---------------------------------------------------------------------------
extern "C" void kernel_launch(void* const* d_in, const int* in_sizes, int n_in,
                              void* d_out, int out_size, void* d_ws, size_t ws_size,
                              hipStream_t stream)
{
    (void)in_sizes; (void)n_in; (void)out_size; (void)ws_size;
    const float* x    = (const float*)d_in[0];
    const float* embw = (const float*)d_in[1];
    const float* embb = (const float*)d_in[2];
    const float* pos  = (const float*)d_in[3];
    const float* ln1g = (const float*)d_in[4];
    const float* ln1b = (const float*)d_in[5];
    const float* wqk  = (const float*)d_in[6];
    const float* wv   = (const float*)d_in[7];
    const float* wo   = (const float*)d_in[8];
    const float* wob  = (const float*)d_in[9];
    const float* ln2g = (const float*)d_in[10];
    const float* ln2b = (const float*)d_in[11];
    const float* ffw1 = (const float*)d_in[12];
    const float* ffb1 = (const float*)d_in[13];
    const float* ffw2 = (const float*)d_in[14];
    const float* ffb2 = (const float*)d_in[15];
    const float* rot  = (const float*)d_in[16];
    const float* lnfg = (const float*)d_in[17];
    const float* lnfb = (const float*)d_in[18];
    const float* hw1  = (const float*)d_in[19];
    const float* hb1  = (const float*)d_in[20];
    const float* hlng = (const float*)d_in[21];
    const float* hlnb = (const float*)d_in[22];
    const float* hw2  = (const float*)d_in[23];
    const float* hb2  = (const float*)d_in[24];
    float* out = (float*)d_out;

    const size_t SZ_BTD = (size_t)BB * TT * DD;            // 4,194,304
    const size_t SZ_OH  = (size_t)BHH * NHASH * TT * DHH;  // 16,777,216

    char* p = (char*)d_ws;
    float* x1b = (float*)p;  p += SZ_BTD * 4;
    float* x2b = (float*)p;  p += SZ_BTD * 4;
    float* xnb = (float*)p;  p += SZ_BTD * 4;              // also amb (bf16) late
    u16*   vbh = (u16*)p;    p += SZ_BTD * 2;
    u16*   xnbh = (u16*)p;   p += SZ_BTD * 2;
    u16*   qkh  = (u16*)p;   p += SZ_BTD * 2;              // bf16 qk, per-head layout
    u16*   qknb = (u16*)p;   p += (size_t)BHH * TT * DHH * 2;
    float* qnrm = (float*)p; p += (size_t)BHH * TT * 4;
    float* rotated = (float*)p; p += (size_t)BB * TT * 32 * 4;
    __half* ohash = (__half*)p;                  // 33.5MB region
    u16*    ffmid = (u16*)p;                     // temporal alias (disjoint life)
    p += SZ_OH * 2;
    float* lseb  = (float*)p; p += (size_t)BHH * NHASH * TT * 4;
    int*   stb   = (int*)p;   p += (size_t)BHH * NHASH * TT * 4;
    u16* wqkT = (u16*)p; p += (size_t)NLAYER * DD * DD * 2;
    u16* wvT  = (u16*)p; p += (size_t)NLAYER * DD * DD * 2;
    u16* woT  = (u16*)p; p += (size_t)NLAYER * DD * DD * 2;
    u16* w1T  = (u16*)p; p += (size_t)NLAYER * DD * FFD * 2;
    u16* w2T  = (u16*)p; p += (size_t)NLAYER * FFD * DD * 2;
    float* wrotAll = (float*)p; p += (size_t)NLAYER * DD * 32 * 4;
    u16* amb = (u16*)xnb;                        // alias (xnb dead after GEMMs)

    // ---- one-time weight prep (all layers) ----
    prep_weights<<<11264, 256, 0, stream>>>(wqk, wv, wo, ffw1, ffw2,
                                            wqkT, wvT, woT, w1T, w2T);
    wrot_kernel<<<dim3(32, NLAYER), 256, 0, stream>>>(wqk, rot, wrotAll);

    embed_kernel<<<BB * TT, 256, 0, stream>>>(x, embw, embb, pos, x1b, x2b);

    for (int L = 0; L < NLAYER; ++L) {
        const size_t w512 = (size_t)L * DD * DD;
        const size_t wff  = (size_t)L * DD * FFD;

        // x1 += attn(ln(x2))
        ln_kernel<<<2048, 256, 0, stream>>>(x2b, ln1g + L * DD, ln1b + L * DD, xnb, xnbh);
        rot_gemm<<<128, 256, 0, stream>>>(xnb, wrotAll + (size_t)L * DD * 32, rotated);
        gemm_bf16<64, 64, 64, false, false, false, true, true><<<dim3(128, 8), 256, 0, stream>>>(
            xnbh, wqkT + w512, nullptr, nullptr, nullptr, qkh, BB * TT, DD, DD);
        gemm_bf16<64, 64, 64, false, false, false, true, false><<<dim3(128, 8), 256, 0, stream>>>(
            xnbh, wvT + w512, nullptr, nullptr, nullptr, vbh, BB * TT, DD, DD);
        bucket_sort_kernel<<<dim3(NHASH, BHH), 512, 0, stream>>>(rotated, stb);
        knorm_kernel<<<4096, 256, 0, stream>>>(qkh, qknb, qnrm);
        lsh_attn_mfma<<<dim3(NCHUNK, BHH), 512, 0, stream>>>(
            qknb, vbh, qnrm, stb, ohash, lseb);
        combine_kernel<<<16384, 256, 0, stream>>>(ohash, lseb, amb);
        gemm_bf16<64, 64, 64, false, true, true, false, false><<<dim3(128, 8), 256, 0, stream>>>(
            amb, woT + w512, wob + L * DD, x1b, x1b, nullptr, BB * TT, DD, DD);

        // x2 += ff(ln(x1))
        ln_kernel<<<2048, 256, 0, stream>>>(x1b, ln2g + L * DD, ln2b + L * DD, nullptr, xnbh);
        gemm_bf16<128, 128, 32, true, false, true, true, false><<<dim3(64, 16), 256, 0, stream>>>(
            xnbh, w1T + wff, ffb1 + L * FFD, nullptr, nullptr, ffmid, BB * TT, FFD, DD);
        gemm_bf16<64, 64, 64, false, true, true, false, false><<<dim3(128, 8), 256, 0, stream>>>(
            ffmid, w2T + wff, ffb2 + L * DD, x2b, x2b, nullptr, BB * TT, DD, FFD);
    }

    head_kernel<<<16, 256, 0, stream>>>(x1b, x2b, lnfg, lnfb, hw1, hb1,
                                        hlng, hlnb, hw2, hb2, out);
}

// Round 8
// 923.931 us; speedup vs baseline: 7.9469x; 1.0260x over previous
//
#include <hip/hip_runtime.h>
#include <hip/hip_fp16.h>
#include <cfloat>
#include <cstdint>

// Problem constants
#define BB      16      // batch
#define TT      512     // seq
#define DD      512     // d_model
#define HH      8       // heads
#define DHH     64      // head dim
#define FFD     2048    // ff dim
#define BHH     128     // BB*HH
#define NHASH   4
#define NCHUNK  8       // NHASH * N_BUCKETS
#define CHUNKSZ 256
#define NLAYER  4

typedef unsigned short u16;
typedef unsigned int   u32;
typedef __attribute__((ext_vector_type(8))) short bfrag;    // 8 bf16 (4 VGPR)
typedef __attribute__((ext_vector_type(4))) float f4x;      // 4 f32 acc
typedef __attribute__((ext_vector_type(16))) float f16x;    // 16 f32 acc

union FragU { u32 u[4]; uint4 v4; bfrag f; };

__device__ __forceinline__ unsigned pk_bf16(float a, float b) {
    union { float f; unsigned u; } x, y;
    x.f = a; y.f = b;
    unsigned lo = ((x.u + 0x7FFFu + ((x.u >> 16) & 1u)) >> 16) & 0xFFFFu;
    unsigned hi = (y.u + 0x7FFFu + ((y.u >> 16) & 1u)) & 0xFFFF0000u;
    return lo | hi;
}
// HW packed f32->bf16 RTNE (1 VALU op; no builtin on gfx950)
__device__ __forceinline__ unsigned cvt_pk(float a, float b) {
    unsigned r;
    asm("v_cvt_pk_bf16_f32 %0, %1, %2" : "=v"(r) : "v"(a), "v"(b));
    return r;
}
// HW packed f32->f16 (RTZ) — o_hash precision (10-bit mantissa)
__device__ __forceinline__ unsigned pkrtz(float a, float b) {
    unsigned r;
    asm("v_cvt_pkrtz_f16_f32 %0, %1, %2" : "=v"(r) : "v"(a), "v"(b));
    return r;
}
__device__ __forceinline__ u16 bf16_1(float a) {
    union { float f; unsigned u; } x; x.f = a;
    return (u16)((x.u + 0x7FFFu + ((x.u >> 16) & 1u)) >> 16);
}
__device__ __forceinline__ float b2f(u16 h) {
    union { unsigned u; float f; } x; x.u = ((unsigned)h) << 16; return x.f;
}

// async global->LDS, 16B per lane (dest must be linear: base + lane*16)
__device__ __forceinline__ void gload16(const u16* g, u16* l) {
    __builtin_amdgcn_global_load_lds(
        (const __attribute__((address_space(1))) u32*)g,
        (__attribute__((address_space(3))) u32*)l, 16, 0, 0);
}

// ---------------------------------------------------------------------------
// Embedding: h = x @ emb_w + emb_b + pos ; write to both x1 and x2
__global__ __launch_bounds__(256)
void embed_kernel(const float* __restrict__ x, const float* __restrict__ ew,
                  const float* __restrict__ eb, const float* __restrict__ pos,
                  float* __restrict__ x1, float* __restrict__ x2)
{
    const int row = blockIdx.x;          // b*T + t
    const int t = row & (TT - 1);
    __shared__ float xr[32];
    if (threadIdx.x < 32) xr[threadIdx.x] = x[row * 32 + threadIdx.x];
    __syncthreads();
    for (int d = threadIdx.x; d < DD; d += 256) {
        float s = eb[d] + pos[t * DD + d];
        #pragma unroll
        for (int k = 0; k < 32; ++k) s = fmaf(xr[k], ew[k * DD + d], s);
        x1[(size_t)row * DD + d] = s;
        x2[(size_t)row * DD + d] = s;
    }
}

// ---------------------------------------------------------------------------
// LayerNorm over last dim (512); writes bf16 (always) and f32 (if out!=null).
__global__ __launch_bounds__(256)
void ln_kernel(const float* __restrict__ in, const float* __restrict__ g,
               const float* __restrict__ bta, float* __restrict__ out,
               u16* __restrict__ outh)
{
    const int row = blockIdx.x * 4 + (threadIdx.x >> 6);
    const int lane = threadIdx.x & 63;
    const float* r = in + (size_t)row * DD;
    float vals[8];
    float s = 0.0f;
    #pragma unroll
    for (int i = 0; i < 8; ++i) { vals[i] = r[i * 64 + lane]; s += vals[i]; }
    #pragma unroll
    for (int o = 1; o < 64; o <<= 1) s += __shfl_xor(s, o);
    const float mean = s * (1.0f / 512.0f);
    float vs = 0.0f;
    #pragma unroll
    for (int i = 0; i < 8; ++i) { float d = vals[i] - mean; vs += d * d; }
    #pragma unroll
    for (int o = 1; o < 64; o <<= 1) vs += __shfl_xor(vs, o);
    const float rstd = rsqrtf(vs * (1.0f / 512.0f) + 1e-5f);
    u16* hrow = outh + (size_t)row * DD;
    #pragma unroll
    for (int i = 0; i < 8; ++i) {
        const int d = i * 64 + lane;
        const float y = (vals[i] - mean) * rstd * g[d] + bta[d];
        if (out != nullptr) out[(size_t)row * DD + d] = y;
        hrow[d] = bf16_1(y);
    }
}

// ---------------------------------------------------------------------------
// Batched weight prep: transpose+bf16 ALL layers in ONE dispatch.
// wqk+wv go into a CONCATENATED wqkvT [1024][512] per layer (qk rows 0..511,
// v rows 512..1023) so qk & v GEMMs merge into one N=1024 dispatch.
__global__ __launch_bounds__(256)
void prep_weights(const float* __restrict__ wqk, const float* __restrict__ wv,
                  const float* __restrict__ wo, const float* __restrict__ ffw1,
                  const float* __restrict__ ffw2,
                  u16* __restrict__ wqkvT, u16* __restrict__ woT,
                  u16* __restrict__ w1T, u16* __restrict__ w2T)
{
    const int id = blockIdx.x;
    const float* in; u16* outp; int K, N, kt, nt;
    if (id < 3072) {                       // wqk / wv / wo : 512x512, 256 tiles/L
        const int fam = id >> 10;
        const int r = id & 1023;
        const int L = r >> 8, t = r & 255;
        K = 512; N = 512;
        const size_t off = (size_t)L * 512 * 512;
        in = (fam == 0 ? wqk : fam == 1 ? wv : wo) + off;
        outp = (fam == 2) ? (woT + off)
                          : (wqkvT + (size_t)L * 1024 * 512 + (fam == 1 ? (size_t)512 * 512 : 0));
        kt = (t & 15) << 5; nt = (t >> 4) << 5;
    } else if (id < 7168) {                // ff1: 512x2048, 1024 tiles/L
        const int r = id - 3072;
        const int L = r >> 10, t = r & 1023;
        K = 512; N = 2048;
        in = ffw1 + (size_t)L * 512 * 2048;
        outp = w1T + (size_t)L * 2048 * 512;
        kt = (t & 15) << 5; nt = (t >> 4) << 5;
    } else {                               // ff2: 2048x512, 1024 tiles/L
        const int r = id - 7168;
        const int L = r >> 10, t = r & 1023;
        K = 2048; N = 512;
        in = ffw2 + (size_t)L * 2048 * 512;
        outp = w2T + (size_t)L * 512 * 2048;
        kt = (t & 63) << 5; nt = (t >> 6) << 5;
    }
    __shared__ float tile[32][33];
    const int rr = threadIdx.x >> 3, c4 = (threadIdx.x & 7) * 4;
    const float4 v4 = *(const float4*)(in + (size_t)(kt + rr) * N + nt + c4);
    tile[rr][c4 + 0] = v4.x; tile[rr][c4 + 1] = v4.y;
    tile[rr][c4 + 2] = v4.z; tile[rr][c4 + 3] = v4.w;
    __syncthreads();
    uint2 p;
    p.x = pk_bf16(tile[c4 + 0][rr], tile[c4 + 1][rr]);
    p.y = pk_bf16(tile[c4 + 2][rr], tile[c4 + 3][rr]);
    *(uint2*)(outp + (size_t)(nt + rr) * K + kt + c4) = p;
}

// ---------------------------------------------------------------------------
// wrot[L][f][h*4+hash] = sum_d wqk[L][f][h*64+d] * rot[L][d][hash]
__global__ __launch_bounds__(256)
void wrot_kernel(const float* __restrict__ wqk, const float* __restrict__ rot,
                 float* __restrict__ wrotAll)
{
    const int hh = blockIdx.x, L = blockIdx.y;
    const int head = hh >> 2, h = hh & 3;
    __shared__ float rc[64];
    if (threadIdx.x < 64)
        rc[threadIdx.x] = rot[((size_t)L * 64 + threadIdx.x) * 4 + h];
    __syncthreads();
    for (int f = threadIdx.x; f < 512; f += 256) {
        const float* wrow = wqk + (size_t)L * 512 * 512 + (size_t)f * 512 + head * 64;
        float s = 0.0f;
        #pragma unroll
        for (int d = 0; d < 64; d += 4) {
            const float4 w4 = *(const float4*)(wrow + d);
            s += w4.x * rc[d] + w4.y * rc[d + 1] + w4.z * rc[d + 2] + w4.w * rc[d + 3];
        }
        wrotAll[((size_t)L * 512 + f) * 32 + hh] = s;
    }
}

// ---------------------------------------------------------------------------
// rotated[8192][32] = xn[8192][512] @ wrot[512][32], all f32. grid 128.
__global__ __launch_bounds__(256)
void rot_gemm(const float* __restrict__ A, const float* __restrict__ Wr,
              float* __restrict__ C)
{
    __shared__ float As[64][36];
    __shared__ float Ws[32][36];
    const int m0 = blockIdx.x * 64;
    const int r = threadIdx.x >> 2, cg = threadIdx.x & 3;
    float acc[8] = {};
    for (int f0 = 0; f0 < 512; f0 += 32) {
        __syncthreads();
        {
            const int lr = threadIdx.x >> 2, lc = (threadIdx.x & 3) * 8;
            const float* ap = A + (size_t)(m0 + lr) * 512 + f0 + lc;
            *(float4*)&As[lr][lc]     = ((const float4*)ap)[0];
            *(float4*)&As[lr][lc + 4] = ((const float4*)ap)[1];
            const int wr = threadIdx.x >> 3, wc = (threadIdx.x & 7) * 4;
            *(float4*)&Ws[wr][wc] = *(const float4*)(Wr + (size_t)(f0 + wr) * 32 + wc);
        }
        __syncthreads();
        #pragma unroll
        for (int kk = 0; kk < 32; ++kk) {
            const float a = As[r][kk];
            #pragma unroll
            for (int c = 0; c < 8; ++c)
                acc[c] = fmaf(a, Ws[kk][cg * 8 + c], acc[c]);
        }
    }
    float* crow = C + (size_t)(m0 + r) * 32 + cg * 8;
    *(float4*)crow       = make_float4(acc[0], acc[1], acc[2], acc[3]);
    *(float4*)(crow + 4) = make_float4(acc[4], acc[5], acc[6], acc[7]);
}

// ---------------------------------------------------------------------------
// bf16 MFMA GEMM, templated tile, double-buffered LDS, 2-phase pipeline.
// QKV: merged qk+v output — n0<512 routes to per-head qkh (Cb); n0>=512
// routes to row-major vbh (Cf reinterpreted as u16*).
__device__ __forceinline__ float gelu1(float v) {
    return 0.5f * v * (1.0f + erff(v * 0.70710678118654752440f));
}
__device__ __forceinline__ int swz_row(int r, int BK) {
    return (BK == 32) ? ((r & 3) ^ ((r >> 2) & 3)) : (r & 7);
}

template<int BM, int BN, int BK, bool GELU, bool ADD, bool BIAS, bool OUTBF, bool QKV>
__global__ __launch_bounds__(256)
void gemm_bf16(const u16* __restrict__ A, const u16* __restrict__ WT,
               const float* __restrict__ bias, const float* __restrict__ addsrc,
               float* __restrict__ Cf, u16* __restrict__ Cb,
               int M, int N, int K)
{
    constexpr int NCH = BK / 8;
    constexpr int CPA = BM * NCH / 256;
    constexpr int CPB = BN * NCH / 256;
    constexpr int MR = BM / 32, NR = BN / 32, KR = BK / 32;
    __shared__ __align__(16) u16 Abuf[2][BM * BK];
    __shared__ __align__(16) u16 Bbuf[2][BN * BK];
    const int tid = threadIdx.x;
    const int m0 = blockIdx.x * BM, n0 = blockIdx.y * BN;

    const u16* aSrc[CPA]; const u16* bSrc[CPB];
    #pragma unroll
    for (int i = 0; i < CPA; ++i) {
        const int s = tid + i * 256, row = s / NCH, ch = s % NCH;
        aSrc[i] = A + (size_t)(m0 + row) * K + (ch ^ swz_row(row, BK)) * 8;
    }
    #pragma unroll
    for (int i = 0; i < CPB; ++i) {
        const int s = tid + i * 256, row = s / NCH, ch = s % NCH;
        bSrc[i] = WT + (size_t)(n0 + row) * K + (ch ^ swz_row(row, BK)) * 8;
    }

    auto STAGE = [&](int bufi, int koff) {
        #pragma unroll
        for (int i = 0; i < CPA; ++i)
            gload16(aSrc[i] + koff, &Abuf[bufi][(tid + i * 256) * 8]);
        #pragma unroll
        for (int i = 0; i < CPB; ++i)
            gload16(bSrc[i] + koff, &Bbuf[bufi][(tid + i * 256) * 8]);
    };

    const int l = tid & 63, wv_ = tid >> 6;
    const int wm = (wv_ >> 1) * (BM / 2);
    const int wn = (wv_ & 1) * (BN / 2);
    const int fr = l & 15, fc = l >> 4;

    f4x acc[MR][NR] = {};
    const int nK = K / BK;
    STAGE(0, 0);
    for (int ks = 0; ks < nK; ++ks) {
        __syncthreads();
        if (ks + 1 < nK) STAGE((ks + 1) & 1, (ks + 1) * BK);
        const u16* Ab = Abuf[ks & 1];
        const u16* Bb = Bbuf[ks & 1];
        FragU af[MR][KR], bf_[NR][KR];
        #pragma unroll
        for (int i = 0; i < MR; ++i)
            #pragma unroll
            for (int u = 0; u < KR; ++u) {
                const int r = wm + i * 16 + fr;
                af[i][u].v4 = *(const uint4*)((const char*)Ab +
                    (size_t)r * (2 * BK) + (((u * 4 + fc) ^ swz_row(r, BK)) << 4));
            }
        #pragma unroll
        for (int j = 0; j < NR; ++j)
            #pragma unroll
            for (int u = 0; u < KR; ++u) {
                const int r = wn + j * 16 + fr;
                bf_[j][u].v4 = *(const uint4*)((const char*)Bb +
                    (size_t)r * (2 * BK) + (((u * 4 + fc) ^ swz_row(r, BK)) << 4));
            }
        #pragma unroll
        for (int u = 0; u < KR; ++u)
            #pragma unroll
            for (int i = 0; i < MR; ++i)
                #pragma unroll
                for (int j = 0; j < NR; ++j)
                    acc[i][j] = __builtin_amdgcn_mfma_f32_16x16x32_bf16(
                        af[i][u].f, bf_[j][u].f, acc[i][j], 0, 0, 0);
    }

    #pragma unroll
    for (int i = 0; i < MR; ++i) {
        #pragma unroll
        for (int q = 0; q < 4; ++q) {
            const int row = m0 + wm + i * 16 + fc * 4 + q;
            #pragma unroll
            for (int j = 0; j < NR; ++j) {
                const int col = n0 + wn + j * 16 + fr;
                float vx = acc[i][j][q];
                if constexpr (BIAS) vx += bias[col];
                if constexpr (GELU) vx = gelu1(vx);
                if constexpr (ADD) vx += addsrc[(size_t)row * N + col];
                if constexpr (QKV) {
                    if (n0 < 512) {   // qk half -> per-head layout [(b*8+h)][t][d]
                        const int bq = row >> 9, tq = row & 511;
                        const int hq = col >> 6, dq = col & 63;
                        Cb[(((size_t)(bq * 8 + hq) * 512) + tq) * 64 + dq] = bf16_1(vx);
                    } else {          // v half -> row-major [row][512]
                        ((u16*)Cf)[(size_t)row * 512 + (col - 512)] = bf16_1(vx);
                    }
                } else if constexpr (OUTBF) {
                    Cb[(size_t)row * N + col] = bf16_1(vx);
                } else {
                    Cf[(size_t)row * N + col] = vx;
                }
            }
        }
    }
}

// ---------------------------------------------------------------------------
// K/Q pre-normalization from bf16 qkh: qkn = bf16(row/|row|), qnrm = |row|
__global__ __launch_bounds__(256)
void knorm_kernel(const u16* __restrict__ qkh, u16* __restrict__ qkn,
                  float* __restrict__ qnrm)
{
    const int g = blockIdx.x * 16 + (threadIdx.x >> 4);  // bh*T + t
    const int li = threadIdx.x & 15;
    const uint2 raw = *(const uint2*)(qkh + (size_t)g * 64 + li * 4);
    const float v0 = b2f((u16)(raw.x & 0xffff)), v1 = b2f((u16)(raw.x >> 16));
    const float v2 = b2f((u16)(raw.y & 0xffff)), v3 = b2f((u16)(raw.y >> 16));
    float ss = v0 * v0 + v1 * v1 + v2 * v2 + v3 * v3;
    ss += __shfl_xor(ss, 1); ss += __shfl_xor(ss, 2);
    ss += __shfl_xor(ss, 4); ss += __shfl_xor(ss, 8);
    const float qn = sqrtf(ss);
    const float rv = 1.0f / fmaxf(qn, 1e-12f);
    uint2 o;
    o.x = cvt_pk(v0 * rv, v1 * rv);
    o.y = cvt_pk(v2 * rv, v3 * rv);
    *(uint2*)(qkn + (size_t)g * 64 + li * 4) = o;
    if (li == 0) qnrm[g] = qn;
}

// ---------------------------------------------------------------------------
// Bucket assignment + stable partition from precomputed rotated (f32)
__global__ __launch_bounds__(512)
void bucket_sort_kernel(const float* __restrict__ rotated, int* __restrict__ st)
{
    const int h = blockIdx.x, bh = blockIdx.y;
    const int b = bh >> 3, head = bh & 7;
    const int t = threadIdx.x;
    __shared__ int zcnt[8];
    const float r = rotated[((size_t)(b * TT + t)) * 32 + head * 4 + h];
    const int bit = (r < 0.0f) ? 1 : 0;
    const int wid = t >> 6, lane = t & 63;
    const unsigned long long zm = __ballot(bit == 0);
    if (lane == 0) zcnt[wid] = __popcll(zm);
    __syncthreads();
    int zoff = 0, Z = 0;
    #pragma unroll
    for (int w = 0; w < 8; ++w) { const int cn = zcnt[w]; if (w < wid) zoff += cn; Z += cn; }
    const int zpre = __popcll(zm & ((1ull << lane) - 1ull));
    const int dst = (bit == 0) ? (zoff + zpre)
                               : (Z + (wid * 64 - zoff) + (lane - zpre));
    st[((size_t)bh * NHASH + h) * TT + dst] = t;
}

// ---------------------------------------------------------------------------
// MFMA LSH attention — 8 waves x 32 queries, double-buffered LDS (1 barrier
// per tile), bit-reversed V^T slot rotation (conflict-free V writes).
__global__ __launch_bounds__(512, 4)
void lsh_attn_mfma(const u16* __restrict__ qkn, const u16* __restrict__ v,
                   const float* __restrict__ qnrm, const int* __restrict__ st,
                   __half* __restrict__ o_hash, float* __restrict__ lse_hash)
{
    const int cc = blockIdx.x, bh = blockIdx.y;
    const int b = bh >> 3, head = bh & 7;
    const int h = cc >> 1, c = cc & 1;
    const int pcc = (cc + 7) & 7;
    const int hp = pcc >> 1, cp = pcc & 1;
    const int tid = threadIdx.x;
    const int w = tid >> 6;          // wave 0..7 -> queries w*32..+32
    const int lane = tid & 63;
    const int l31 = lane & 31;
    const int hi = lane >> 5;
    const int* stb = st + (size_t)bh * (NHASH * TT);
    const size_t vbase = ((size_t)b * TT) * DD + head * DHH;
    const u16* qknb = qkn + (size_t)bh * TT * DHH;

    __shared__ __align__(16) u16 Kbf[2][64 * 64];
    __shared__ __align__(16) u16 VTbf[2][64 * 64];
    __shared__ __align__(16) int ktl[2][64];

    // ---- Q fragment (one query per lane-column) ----
    const int q_t = stb[h * TT + c * CHUNKSZ + w * 32 + l31];
    const float qn = qnrm[(size_t)bh * TT + q_t];
    const float mnat = qn * 0.125f;
    const float aC = qn * 0.1803368801111137f;   // |q| * 0.125 * log2(e)
    uint4 QF4[4];
    {
        const u16* qrow = qknb + (size_t)q_t * DHH;
        #pragma unroll
        for (int ds = 0; ds < 4; ++ds)
            QF4[ds] = *(const uint4*)(qrow + ds * 16 + hi * 8);
    }

    f16x acc[2] = {};           // [dt] O^T tiles (32d x 32q)
    float lacc = 0.f;
    const int k8 = tid >> 3;    // key row 0..63 (8 lanes per 128B row)
    const int c8 = tid & 7;     // 16B chunk of the row
    // bit-reversed slot bases (constant per thread)
    const int brc = ((c8 & 1) << 2) | (c8 & 2) | ((c8 & 4) >> 2);   // bitrev3(c8)
    const int wSlot = ((k8 >> 3) + brc) & 7;                        // V write slot
    const int g2 = l31 >> 3;                                        // read row group
    const int brg = ((g2 & 1) << 2) | (g2 & 2);                     // bitrev3(g2), g2<4

    auto gather = [&](int t8, uint4& kc, uint4& vc, int& ktc) {
        const int kj = t8 * 64 + k8;
        const int k_t = (kj < CHUNKSZ) ? stb[h * TT + c * CHUNKSZ + kj]
                                       : stb[hp * TT + cp * CHUNKSZ + (kj - CHUNKSZ)];
        ktc = k_t;
        kc = *(const uint4*)(qknb + (size_t)k_t * DHH + c8 * 8);
        vc = *(const uint4*)(v + vbase + (size_t)k_t * DD + c8 * 8);
    };
    auto writeTile = [&](int bi, const uint4& kc, const uint4& vc, int ktc) {
        *(uint4*)((char*)Kbf[bi] + ((k8 * 128 + c8 * 16) ^ ((k8 & 7) << 4))) = kc;
        const unsigned vu[4] = {vc.x, vc.y, vc.z, vc.w};
        #pragma unroll
        for (int i = 0; i < 8; ++i) {
            const int d = c8 * 8 + i;
            const u16 hv = (u16)((i & 1) ? (vu[i >> 1] >> 16) : (vu[i >> 1] & 0xffff));
            *(u16*)((char*)VTbf[bi] + d * 128 + wSlot * 16 + (k8 & 7) * 2) = hv;
        }
        if (c8 == 0) ktl[bi][k8] = ktc;
    };

    uint4 kc, vc; int ktc;
    gather(0, kc, vc, ktc);
    writeTile(0, kc, vc, ktc);
    __syncthreads();

    for (int kt8 = 0; kt8 < 8; ++kt8) {
        const int cur = kt8 & 1;
        if (kt8 < 7) gather(kt8 + 1, kc, vc, ktc);
        const u16* Kb = Kbf[cur];
        const u16* Vb = VTbf[cur];
        const int* kl = ktl[cur];

        #pragma unroll
        for (int kt = 0; kt < 2; ++kt) {
            int4 kt4[4];
            #pragma unroll
            for (int j = 0; j < 4; ++j)
                kt4[j] = *(const int4*)&kl[kt * 32 + 8 * j + 4 * hi];
            const int* ktvp = (const int*)kt4;
            FragU KA[4];
            #pragma unroll
            for (int ds = 0; ds < 4; ++ds) {
                const int row = kt * 32 + l31;
                KA[ds].v4 = *(const uint4*)((const char*)Kb +
                    ((row * 128 + ds * 32 + hi * 16) ^ ((row & 7) << 4)));
            }
            FragU VA[2][2];
            #pragma unroll
            for (int dt = 0; dt < 2; ++dt)
                #pragma unroll
                for (int u = 0; u < 2; ++u) {
                    const int row = dt * 32 + l31;
                    const int cr = (kt * 2 + u) * 2 + hi;
                    const int slot = (cr + brg + dt) & 7;    // bitrev3(row>>3)=brg+dt
                    VA[dt][u].v4 = *(const uint4*)((const char*)Vb +
                        row * 128 + slot * 16);
                }
            f16x s = {0.f,0.f,0.f,0.f,0.f,0.f,0.f,0.f,
                      0.f,0.f,0.f,0.f,0.f,0.f,0.f,0.f};
            #pragma unroll
            for (int ds = 0; ds < 4; ++ds) {
                FragU qf; qf.v4 = QF4[ds];
                s = __builtin_amdgcn_mfma_f32_32x32x16_bf16(KA[ds].f, qf.f, s, 0, 0, 0);
            }
            float pv[16];
            #pragma unroll
            for (int i = 0; i < 16; ++i) {
                const float e = exp2f(fmaf(s[i], aC, -aC));   // exp(qn/8*(s-1))
                const float p = (q_t > ktvp[i]) ? e : 0.0f;
                pv[i] = p;
                lacc += p;
            }
            unsigned P2[8];
            #pragma unroll
            for (int g = 0; g < 4; ++g) {
                P2[2*g]   = cvt_pk(pv[4*g],   pv[4*g+1]);
                P2[2*g+1] = cvt_pk(pv[4*g+2], pv[4*g+3]);
            }
            #pragma unroll
            for (int u = 0; u < 2; ++u) {
                unsigned a0 = P2[4*u + 0], b0 = P2[4*u + 2];
                unsigned a1 = P2[4*u + 1], b1 = P2[4*u + 3];
                asm("v_permlane32_swap_b32 %0, %1" : "+v"(a0), "+v"(b0));
                asm("v_permlane32_swap_b32 %0, %1" : "+v"(a1), "+v"(b1));
                FragU bfv;
                bfv.u[0] = a0; bfv.u[1] = a1; bfv.u[2] = b0; bfv.u[3] = b1;
                #pragma unroll
                for (int dt = 0; dt < 2; ++dt)
                    acc[dt] = __builtin_amdgcn_mfma_f32_32x32x16_bf16(
                        VA[dt][u].f, bfv.f, acc[dt], 0, 0, 0);
            }
        }

        if (kt8 < 7) {
            writeTile(cur ^ 1, kc, vc, ktc);
            __syncthreads();
        }
    }

    // ---- finalize: l, lse, register-only epilogue ----
    const float lt = lacc + __shfl_xor(lacc, 32);
    const float invl = (lt > 0.f) ? 1.0f / lt : 0.0f;
    if (hi == 0) {
        const float lse = (lt > 0.f) ? (mnat + logf(lt)) : -5.0e4f;
        lse_hash[(size_t)(bh * NHASH + h) * TT + q_t] = lse;
    }
    unsigned wa[8], wb[8];
    #pragma unroll
    for (int m = 0; m < 8; ++m) {
        wa[m] = pkrtz(acc[0][2*m] * invl, acc[0][2*m+1] * invl);
        wb[m] = pkrtz(acc[1][2*m] * invl, acc[1][2*m+1] * invl);
    }
    #pragma unroll
    for (int m = 0; m < 8; ++m)
        asm("v_permlane32_swap_b32 %0, %1" : "+v"(wa[m]), "+v"(wb[m]));
    __half* orow = o_hash + ((size_t)(bh * NHASH + h) * TT + q_t) * DHH + hi * 32;
    if (lt > 0.f) {
        #pragma unroll
        for (int g = 0; g < 4; ++g) {
            uint4 o;
            o.x = wa[2*g]; o.y = wa[2*g+1];
            o.z = wb[2*g]; o.w = wb[2*g+1];
            ((uint4*)orow)[g] = o;
        }
    } else {
        const u16* vr = v + vbase + (size_t)q_t * DD + hi * 32;
        #pragma unroll
        for (int g = 0; g < 4; ++g) {
            uint4 o;
            o.x = pkrtz(b2f(vr[8*g+0]), b2f(vr[8*g+1]));
            o.y = pkrtz(b2f(vr[8*g+2]), b2f(vr[8*g+3]));
            o.z = pkrtz(b2f(vr[8*g+4]), b2f(vr[8*g+5]));
            o.w = pkrtz(b2f(vr[8*g+6]), b2f(vr[8*g+7]));
            ((uint4*)orow)[g] = o;
        }
    }
}

// ---------------------------------------------------------------------------
// Combine hash rounds: read o_hash f16, write merged bf16 (wo GEMM A-operand)
__global__ __launch_bounds__(256)
void combine_kernel(const __half* __restrict__ o_hash, const float* __restrict__ lse_hash,
                    u16* __restrict__ am)
{
    const int idx = blockIdx.x * 4 + (threadIdx.x >> 6);
    const int lane = threadIdx.x & 63;
    const int bh = idx >> 9, t = idx & 511;
    const int b = bh >> 3, head = bh & 7;
    const float ls0 = lse_hash[(size_t)(bh * NHASH + 0) * TT + t];
    const float ls1 = lse_hash[(size_t)(bh * NHASH + 1) * TT + t];
    const float ls2 = lse_hash[(size_t)(bh * NHASH + 2) * TT + t];
    const float ls3 = lse_hash[(size_t)(bh * NHASH + 3) * TT + t];
    const float M = fmaxf(fmaxf(ls0, ls1), fmaxf(ls2, ls3));
    const float e0 = __expf(ls0 - M), e1 = __expf(ls1 - M);
    const float e2 = __expf(ls2 - M), e3 = __expf(ls3 - M);
    const float inv = 1.0f / (e0 + e1 + e2 + e3);
    const float o =
        (e0 * __half2float(o_hash[((size_t)((bh * NHASH + 0) * TT + t)) * DHH + lane]) +
         e1 * __half2float(o_hash[((size_t)((bh * NHASH + 1) * TT + t)) * DHH + lane]) +
         e2 * __half2float(o_hash[((size_t)((bh * NHASH + 2) * TT + t)) * DHH + lane]) +
         e3 * __half2float(o_hash[((size_t)((bh * NHASH + 3) * TT + t)) * DHH + lane])) * inv;
    am[((size_t)(b * TT + t)) * DD + head * DHH + lane] = bf16_1(o);
}

// ---------------------------------------------------------------------------
// Final head
__device__ __forceinline__ float block_sum256(float v, volatile float* red)
{
    const int lane = threadIdx.x & 63, wid = threadIdx.x >> 6;
    #pragma unroll
    for (int o = 1; o < 64; o <<= 1) v += __shfl_xor(v, o);
    __syncthreads();
    if (lane == 0) red[wid] = v;
    __syncthreads();
    return red[0] + red[1] + red[2] + red[3];
}

__global__ __launch_bounds__(256)
void head_kernel(const float* __restrict__ x1, const float* __restrict__ x2,
                 const float* __restrict__ lnfg, const float* __restrict__ lnfb,
                 const float* __restrict__ hw1, const float* __restrict__ hb1,
                 const float* __restrict__ hlng, const float* __restrict__ hlnb,
                 const float* __restrict__ hw2, const float* __restrict__ hb2,
                 float* __restrict__ out)
{
    __shared__ float nrow[512];
    __shared__ float red[4];
    const int b = blockIdx.x, tid = threadIdx.x;
    const size_t roff = ((size_t)b * TT + (TT - 1)) * DD;
    const float v0 = 0.5f * (x1[roff + tid] + x2[roff + tid]);
    const float v1 = 0.5f * (x1[roff + 256 + tid] + x2[roff + 256 + tid]);
    const float mean = block_sum256(v0 + v1, red) * (1.0f / 512.0f);
    const float d0 = v0 - mean, d1 = v1 - mean;
    const float var = block_sum256(d0 * d0 + d1 * d1, red) * (1.0f / 512.0f);
    const float rstd = rsqrtf(var + 1e-5f);
    nrow[tid]       = d0 * rstd * lnfg[tid] + lnfb[tid];
    nrow[tid + 256] = d1 * rstd * lnfg[tid + 256] + lnfb[tid + 256];
    __syncthreads();
    float a = hb1[tid];
    for (int k = 0; k < 512; ++k) a = fmaf(nrow[k], hw1[(size_t)k * 256 + tid], a);
    const float m2 = block_sum256(a, red) * (1.0f / 256.0f);
    const float dd = a - m2;
    const float var2 = block_sum256(dd * dd, red) * (1.0f / 256.0f);
    float y = dd * rsqrtf(var2 + 1e-5f) * hlng[tid] + hlnb[tid];
    y = fmaxf(y, 0.0f);
    const float osum = block_sum256(y * hw2[tid], red);
    if (tid == 0) out[b] = osum + hb2[0];
}

// ---------------------------------------------------------------------------
extern "C" void kernel_launch(void* const* d_in, const int* in_sizes, int n_in,
                              void* d_out, int out_size, void* d_ws, size_t ws_size,
                              hipStream_t stream)
{
    (void)in_sizes; (void)n_in; (void)out_size; (void)ws_size;
    const float* x    = (const float*)d_in[0];
    const float* embw = (const float*)d_in[1];
    const float* embb = (const float*)d_in[2];
    const float* pos  = (const float*)d_in[3];
    const float* ln1g = (const float*)d_in[4];
    const float* ln1b = (const float*)d_in[5];
    const float* wqk  = (const float*)d_in[6];
    const float* wv   = (const float*)d_in[7];
    const float* wo   = (const float*)d_in[8];
    const float* wob  = (const float*)d_in[9];
    const float* ln2g = (const float*)d_in[10];
    const float* ln2b = (const float*)d_in[11];
    const float* ffw1 = (const float*)d_in[12];
    const float* ffb1 = (const float*)d_in[13];
    const float* ffw2 = (const float*)d_in[14];
    const float* ffb2 = (const float*)d_in[15];
    const float* rot  = (const float*)d_in[16];
    const float* lnfg = (const float*)d_in[17];
    const float* lnfb = (const float*)d_in[18];
    const float* hw1  = (const float*)d_in[19];
    const float* hb1  = (const float*)d_in[20];
    const float* hlng = (const float*)d_in[21];
    const float* hlnb = (const float*)d_in[22];
    const float* hw2  = (const float*)d_in[23];
    const float* hb2  = (const float*)d_in[24];
    float* out = (float*)d_out;

    const size_t SZ_BTD = (size_t)BB * TT * DD;            // 4,194,304
    const size_t SZ_OH  = (size_t)BHH * NHASH * TT * DHH;  // 16,777,216

    char* p = (char*)d_ws;
    float* x1b = (float*)p;  p += SZ_BTD * 4;
    float* x2b = (float*)p;  p += SZ_BTD * 4;
    float* xnb = (float*)p;  p += SZ_BTD * 4;              // also amb (bf16) late
    u16*   vbh = (u16*)p;    p += SZ_BTD * 2;
    u16*   xnbh = (u16*)p;   p += SZ_BTD * 2;
    u16*   qkh  = (u16*)p;   p += SZ_BTD * 2;              // bf16 qk, per-head layout
    u16*   qknb = (u16*)p;   p += (size_t)BHH * TT * DHH * 2;
    float* qnrm = (float*)p; p += (size_t)BHH * TT * 4;
    float* rotated = (float*)p; p += (size_t)BB * TT * 32 * 4;
    __half* ohash = (__half*)p;                  // 33.5MB region
    u16*    ffmid = (u16*)p;                     // temporal alias (disjoint life)
    p += SZ_OH * 2;
    float* lseb  = (float*)p; p += (size_t)BHH * NHASH * TT * 4;
    int*   stb   = (int*)p;   p += (size_t)BHH * NHASH * TT * 4;
    u16* wqkvT = (u16*)p; p += (size_t)NLAYER * 1024 * 512 * 2;
    u16* woT   = (u16*)p; p += (size_t)NLAYER * DD * DD * 2;
    u16* w1T   = (u16*)p; p += (size_t)NLAYER * DD * FFD * 2;
    u16* w2T   = (u16*)p; p += (size_t)NLAYER * FFD * DD * 2;
    float* wrotAll = (float*)p; p += (size_t)NLAYER * DD * 32 * 4;
    u16* amb = (u16*)xnb;                        // alias (xnb dead after GEMMs)

    // ---- one-time weight prep (all layers) ----
    prep_weights<<<11264, 256, 0, stream>>>(wqk, wv, wo, ffw1, ffw2,
                                            wqkvT, woT, w1T, w2T);
    wrot_kernel<<<dim3(32, NLAYER), 256, 0, stream>>>(wqk, rot, wrotAll);

    embed_kernel<<<BB * TT, 256, 0, stream>>>(x, embw, embb, pos, x1b, x2b);

    for (int L = 0; L < NLAYER; ++L) {
        const size_t w512 = (size_t)L * DD * DD;
        const size_t wff  = (size_t)L * DD * FFD;

        // x1 += attn(ln(x2))
        ln_kernel<<<2048, 256, 0, stream>>>(x2b, ln1g + L * DD, ln1b + L * DD, xnb, xnbh);
        rot_gemm<<<128, 256, 0, stream>>>(xnb, wrotAll + (size_t)L * DD * 32, rotated);
        gemm_bf16<128, 128, 32, false, false, false, false, true><<<dim3(64, 8), 256, 0, stream>>>(
            xnbh, wqkvT + (size_t)L * 1024 * 512, nullptr, nullptr,
            (float*)vbh, qkh, BB * TT, 1024, DD);
        bucket_sort_kernel<<<dim3(NHASH, BHH), 512, 0, stream>>>(rotated, stb);
        knorm_kernel<<<4096, 256, 0, stream>>>(qkh, qknb, qnrm);
        lsh_attn_mfma<<<dim3(NCHUNK, BHH), 512, 0, stream>>>(
            qknb, vbh, qnrm, stb, ohash, lseb);
        combine_kernel<<<16384, 256, 0, stream>>>(ohash, lseb, amb);
        gemm_bf16<64, 64, 64, false, true, true, false, false><<<dim3(128, 8), 256, 0, stream>>>(
            amb, woT + w512, wob + L * DD, x1b, x1b, nullptr, BB * TT, DD, DD);

        // x2 += ff(ln(x1))
        ln_kernel<<<2048, 256, 0, stream>>>(x1b, ln2g + L * DD, ln2b + L * DD, nullptr, xnbh);
        gemm_bf16<128, 128, 32, true, false, true, true, false><<<dim3(64, 16), 256, 0, stream>>>(
            xnbh, w1T + wff, ffb1 + L * FFD, nullptr, nullptr, ffmid, BB * TT, FFD, DD);
        gemm_bf16<64, 64, 64, false, true, true, false, false><<<dim3(128, 8), 256, 0, stream>>>(
            ffmid, w2T + wff, ffb2 + L * DD, x2b, x2b, nullptr, BB * TT, DD, FFD);
    }

    head_kernel<<<16, 256, 0, stream>>>(x1b, x2b, lnfg, lnfb, hw1, hb1,
                                        hlng, hlnb, hw2, hb2, out);
}